// Round 10
// baseline (256.224 us; speedup 1.0000x reference)
//
#include <hip/hip_runtime.h>
#include <math.h>

#define NODES 50000
#define NEDGE 800000
#define ETOT  (NEDGE + NODES)   // edges + self loops = 850000
#define NF    256
#define F1    128               // HEADS*NHID
#define NHEAD 8
#define NHID  16
#define NC    40
#define SCAN_BLK 196            // ceil((NODES+1)/256)

typedef __attribute__((ext_vector_type(8))) short bf16x8;
typedef __attribute__((ext_vector_type(4))) float f32x4;

__device__ __forceinline__ float bflo(unsigned u) { return __uint_as_float(u << 16); }
__device__ __forceinline__ float bfhi(unsigned u) { return __uint_as_float(u & 0xffff0000u); }
__device__ __forceinline__ unsigned short f2bf(float f) {
    unsigned u = __float_as_uint(f);
    unsigned r = u + 0x7fffu + ((u >> 16) & 1u);   // RNE
    return (unsigned short)(r >> 16);
}
__device__ __forceinline__ unsigned pk2(float a, float b) {
    return (unsigned)f2bf(a) | ((unsigned)f2bf(b) << 16);
}

// ---------- edge index dtype detect ----------
__global__ void detect_k(const unsigned* __restrict__ u, unsigned* __restrict__ flag) {
    int t = threadIdx.x;              // 256 threads
    if (u[2 * t + 1] != 0u) atomicOr(flag, 1u);   // nonzero hi-word pattern => int32 data
}

// ---------- CSR build (reads edge_index directly) ----------
__global__ void hist_k(const unsigned* __restrict__ u, const unsigned* __restrict__ flag,
                       int* __restrict__ cnt) {
    int e = blockIdx.x * 256 + threadIdx.x;
    if (e >= ETOT) return;
    int d;
    if (e < NEDGE) d = (*flag) ? (int)u[NEDGE + e] : (int)u[2 * NEDGE + 2 * e];
    else d = e - NEDGE;
    atomicAdd(&cnt[d], 1);
}

// ---------- multi-block exclusive scan of cnt[0..NODES] -> rowPtr ----------
__global__ __launch_bounds__(256) void scanA(const int* __restrict__ cnt,
                                             int* __restrict__ rowPtr,
                                             int* __restrict__ blockSum) {
    int idx = blockIdx.x * 256 + threadIdx.x;
    int lane = threadIdx.x & 63, w = threadIdx.x >> 6;
    int v = (idx < NODES) ? cnt[idx] : 0;
    int s = v;
#pragma unroll
    for (int off = 1; off < 64; off <<= 1) {
        int o = __shfl_up(s, off, 64);
        if (lane >= off) s += o;
    }
    __shared__ int wsum[4];
    if (lane == 63) wsum[w] = s;
    __syncthreads();
    int wadd = 0;
    for (int i = 0; i < w; ++i) wadd += wsum[i];
    int incl = s + wadd;
    if (idx <= NODES) rowPtr[idx] = incl - v;        // block-local exclusive
    if (threadIdx.x == 255) blockSum[blockIdx.x] = incl;
}

__global__ __launch_bounds__(256) void scanB(const int* __restrict__ blockSum,
                                             int* __restrict__ blockOff) {
    __shared__ int sh[256];
    int t = threadIdx.x;
    int v = (t < SCAN_BLK) ? blockSum[t] : 0;
    sh[t] = v;
    __syncthreads();
    for (int off = 1; off < 256; off <<= 1) {
        int o = (t >= off) ? sh[t - off] : 0;
        __syncthreads();
        sh[t] += o;
        __syncthreads();
    }
    if (t < SCAN_BLK) blockOff[t] = sh[t] - v;       // exclusive
}

__global__ __launch_bounds__(256) void scanC(int* __restrict__ rowPtr,
                                             const int* __restrict__ blockOff) {
    int idx = blockIdx.x * 256 + threadIdx.x;
    if (idx <= NODES) rowPtr[idx] += blockOff[blockIdx.x];
}

__global__ void scatter_k(const unsigned* __restrict__ u, const unsigned* __restrict__ flag,
                          const int* __restrict__ rowPtr, int* __restrict__ fill,
                          int* __restrict__ csrSrc) {
    int e = blockIdx.x * 256 + threadIdx.x;
    if (e >= ETOT) return;
    int s, d;
    if (e < NEDGE) {
        if (*flag) { s = (int)u[e]; d = (int)u[NEDGE + e]; }
        else       { s = (int)u[2 * e]; d = (int)u[2 * NEDGE + 2 * e]; }
    } else s = d = e - NEDGE;
    int pos = rowPtr[d] + atomicAdd(&fill[d], 1);
    csrSrc[pos] = s;
}

// ---------- prep: W1t144[144][256] bf16 = [W1^T ; W1.atts1 per head ; W1.attd1] ----------
__global__ void prepW1(const float* __restrict__ W1, const float* __restrict__ atts1,
                       const float* __restrict__ attd1, unsigned short* __restrict__ W1t) {
    int n = blockIdx.x;      // 0..143
    int k = threadIdx.x;     // 0..255
    float v;
    if (n < 128) {
        v = W1[(size_t)k * F1 + n];
    } else if (n < 136) {
        int h = n - 128; v = 0.f;
#pragma unroll
        for (int c = 0; c < 16; ++c) v += W1[(size_t)k * F1 + h * 16 + c] * atts1[h * 16 + c];
    } else {
        int h = n - 136; v = 0.f;
#pragma unroll
        for (int c = 0; c < 16; ++c) v += W1[(size_t)k * F1 + h * 16 + c] * attd1[h * 16 + c];
    }
    W1t[(size_t)n * NF + k] = f2bf(v);
}

// ---------- MFMA GEMM1: x[N,256] @ W1t144^T -> h1b[,128] bf16 + as1/ad1 ----------
// x loads issued up-front behind a sched_barrier (16-deep MLP), W1t staged in
// LDS (XOR-swizzled) so B-fragments come from ds_read_b128, not global.
__global__ __launch_bounds__(256) void gemm1m(const float* __restrict__ x,
                                              const unsigned short* __restrict__ W1t,
                                              unsigned short* __restrict__ h1b,
                                              float* __restrict__ as1,
                                              float* __restrict__ ad1) {
    __shared__ uint4 wlds[4608];         // 144 rows x 32 uint4 = 73728 B
    int t = threadIdx.x;
    int wave = t >> 6, lane = t & 63;
    int mbase = blockIdx.x * 64 + wave * 16;
    int row = mbase + (lane & 15);
    int rowc = min(row, NODES - 1);
    int kg = lane >> 4;              // 0..3
    const float4* xr = (const float4*)(x + (size_t)rowc * NF + kg * 8);

    // 1) issue the full K-strip loads (16 independent dwordx4 in flight)
    float4 xa[16];
#pragma unroll
    for (int ks = 0; ks < 8; ++ks) {
        xa[2 * ks]     = xr[ks * 8];
        xa[2 * ks + 1] = xr[ks * 8 + 1];
    }
    __builtin_amdgcn_sched_barrier(0);   // pin loads before the staging code

    // 2) stage W1t into LDS, swizzled: uint4 idx i -> i ^ (row&7), row = i>>5
#pragma unroll
    for (int it = 0; it < 18; ++it) {
        int i = it * 256 + t;
        wlds[i ^ ((i >> 5) & 7)] = ((const uint4*)W1t)[i];
    }
    __syncthreads();                     // also drains the x loads (all parallel)

    f32x4 acc[9];
#pragma unroll
    for (int f = 0; f < 9; ++f) acc[f] = (f32x4){0.f, 0.f, 0.f, 0.f};

    int r = lane & 15;
    int swz = r & 7;
    int rb = r * 32 + kg;                // uint4 index base within a frag row-block

#pragma unroll
    for (int ks = 0; ks < 8; ++ks) {
        union { uint4 u; bf16x8 v; } A;
        float4 a0 = xa[2 * ks], a1 = xa[2 * ks + 1];
        A.u.x = pk2(a0.x, a0.y); A.u.y = pk2(a0.z, a0.w);
        A.u.z = pk2(a1.x, a1.y); A.u.w = pk2(a1.z, a1.w);
#pragma unroll
        for (int f = 0; f < 9; ++f) {
            union { uint4 u; bf16x8 v; } B;
            B.u = wlds[(f * 512 + rb + ks * 4) ^ swz];
            acc[f] = __builtin_amdgcn_mfma_f32_16x16x32_bf16(A.v, B.v, acc[f], 0, 0, 0);
        }
    }

    // store: C/D layout col=lane&15, row=(lane>>4)*4+reg
    int col = lane & 15;
    int rbase = mbase + (lane >> 4) * 4;
#pragma unroll
    for (int f = 0; f < 8; ++f) {
#pragma unroll
        for (int i = 0; i < 4; ++i) {
            int rr = rbase + i;
            if (rr < NODES) h1b[(size_t)rr * F1 + f * 16 + col] = f2bf(acc[f][i]);
        }
    }
#pragma unroll
    for (int i = 0; i < 4; ++i) {
        int rr = rbase + i;
        if (rr < NODES) {
            float v = acc[8][i];
            if (col < 8) as1[(size_t)rr * NHEAD + col] = v;
            else ad1[(size_t)rr * NHEAD + (col - 8)] = v;
        }
    }
}

// no-max softmax step: 8 channels per lane
#define PROC8(AV, HV)                                    \
    {                                                    \
        float l = (AV) + adv;                            \
        l = l > 0.f ? l : 0.2f * l;                      \
        float p = __expf(l);                             \
        den += p;                                        \
        acc[0] += p * bflo(HV.x); acc[1] += p * bfhi(HV.x); \
        acc[2] += p * bflo(HV.y); acc[3] += p * bfhi(HV.y); \
        acc[4] += p * bflo(HV.z); acc[5] += p * bfhi(HV.z); \
        acc[6] += p * bflo(HV.w); acc[7] += p * bfhi(HV.w); \
    }

// ---------- L1 gather: wave per dst, depth-4 ring (16 edges in flight) ----------
__global__ __launch_bounds__(256) void msg1(const int* __restrict__ rowPtr,
                                            const int* __restrict__ csrSrc,
                                            const float* __restrict__ as1,
                                            const float* __restrict__ ad1,
                                            const unsigned short* __restrict__ h1b,
                                            const float* __restrict__ b1,
                                            unsigned short* __restrict__ out1b) {
    int t = threadIdx.x;
    int wid = t >> 6, lane = t & 63;
    int d = blockIdx.x * 4 + wid;        // grid exact (50000/4)
    int g = lane >> 4;                    // edge subgroup 0..3
    int cl = lane & 15;                   // channel lane: ch 8*cl..8*cl+7
    int h = cl >> 1;                      // head
    float adv = ad1[(size_t)d * NHEAD + h];
    int rs = rowPtr[d], re = rowPtr[d + 1];
    float den = 0.f;
    float acc[8];
#pragma unroll
    for (int k = 0; k < 8; ++k) acc[k] = 0.f;

    const char* as1c = (const char*)as1;
    const char* h1c = (const char*)h1b;
    unsigned hoff = (unsigned)(h << 2);
    unsigned coff = (unsigned)(cl << 4);

#define LD1(J0, AV, HV)                                               \
    {                                                                 \
        int j = (J0) + g;                                             \
        bool val = j < re;                                            \
        int jj = val ? j : re - 1;                                    \
        unsigned ss = (unsigned)csrSrc[jj];                           \
        AV = val ? *(const float*)(as1c + (ss << 5) + hoff) : -1e30f; \
        HV = *(const uint4*)(h1c + (ss << 8) + coff);                 \
    }

    float avA, avB, avC, avD;
    uint4 hvA, hvB, hvC, hvD;
    LD1(rs,      avA, hvA);
    LD1(rs + 4,  avB, hvB);
    LD1(rs + 8,  avC, hvC);
    LD1(rs + 12, avD, hvD);
    for (int j0 = rs; j0 < re; j0 += 16) {
        float tA, tB, tC, tD;
        uint4 uA, uB, uC, uD;
        LD1(j0 + 16, tA, uA);
        LD1(j0 + 20, tB, uB);
        LD1(j0 + 24, tC, uC);
        LD1(j0 + 28, tD, uD);
        PROC8(avA, hvA); PROC8(avB, hvB); PROC8(avC, hvC); PROC8(avD, hvD);
        avA = tA; avB = tB; avC = tC; avD = tD;
        hvA = uA; hvB = uB; hvC = uC; hvD = uD;
    }
#undef LD1

    // reduce across the 4 edge-groups
#pragma unroll
    for (int k = 0; k < 8; ++k) {
        acc[k] += __shfl_xor(acc[k], 16, 64);
        acc[k] += __shfl_xor(acc[k], 32, 64);
    }
    den += __shfl_xor(den, 16, 64);
    den += __shfl_xor(den, 32, 64);
    float invd = 1.f / (den + 1e-16f);

    if (g == 0) {
        const float4* bp = (const float4*)(b1 + cl * 8);
        float4 ba = bp[0], bb = bp[1];
        float v[8];
        v[0] = acc[0] * invd + ba.x; v[1] = acc[1] * invd + ba.y;
        v[2] = acc[2] * invd + ba.z; v[3] = acc[3] * invd + ba.w;
        v[4] = acc[4] * invd + bb.x; v[5] = acc[5] * invd + bb.y;
        v[6] = acc[6] * invd + bb.z; v[7] = acc[7] * invd + bb.w;
#pragma unroll
        for (int k = 0; k < 8; ++k) {
            float ev = __expf(v[k]) - 1.f;          // ELU negative branch
            v[k] = v[k] > 0.f ? v[k] : ev;
        }
        uint4 o;
        o.x = pk2(v[0], v[1]); o.y = pk2(v[2], v[3]);
        o.z = pk2(v[4], v[5]); o.w = pk2(v[6], v[7]);
        *(uint4*)(out1b + (size_t)d * F1 + cl * 8) = o;
    }
}

// ---------- GEMM2: out1b[N,128]bf16 @ W2[128,40] -> h2b (bf16) + fused a2k ----------
__global__ __launch_bounds__(320) void gemm2k(const unsigned short* __restrict__ a,
                                              const float* __restrict__ W,
                                              const float* __restrict__ atts2,
                                              const float* __restrict__ attd2,
                                              unsigned short* __restrict__ h2b,
                                              float* __restrict__ as2,
                                              float* __restrict__ ad2) {
    __shared__ float xs[8][132];
    __shared__ float red[2][320];
    int t = threadIdx.x;
    int base = blockIdx.x * 8;           // grid exact (50000/8)
    if (t < 256) {
        int row = t >> 5, q = t & 31;
        uint2 u = *(const uint2*)(a + (size_t)(base + row) * F1 + q * 4);
        float4 f;
        f.x = bflo(u.x); f.y = bfhi(u.x); f.z = bflo(u.y); f.w = bfhi(u.y);
        *(float4*)(&xs[row][q * 4]) = f;
    }
    __syncthreads();
    int n = t / 40, c = t % 40;
    float acc = 0.f;
    for (int k4 = 0; k4 < 32; ++k4) {
        float4 xv = *(const float4*)(&xs[n][k4 * 4]);
        const float* wp = W + (size_t)k4 * 4 * NC + c;
        acc += xv.x * wp[0];
        acc += xv.y * wp[NC];
        acc += xv.z * wp[2 * NC];
        acc += xv.w * wp[3 * NC];
    }
    int node = base + n;
    h2b[(size_t)node * NC + c] = f2bf(acc);
    red[0][n * 40 + c] = acc * atts2[c];
    red[1][n * 40 + c] = acc * attd2[c];
    __syncthreads();
    if (t < 16) {
        int which = t >> 3, nn = t & 7;
        const float* p = red[which] + nn * 40;
        float s = 0.f;
        for (int q = 0; q < 40; ++q) s += p[q];
        if (which) ad2[base + nn] = s; else as2[base + nn] = s;
    }
}

// ---------- L2 gather: wave per dst, depth-4 ring (32 edges in flight) ----------
__global__ __launch_bounds__(256) void msg2(const int* __restrict__ rowPtr,
                                            const int* __restrict__ csrSrc,
                                            const float* __restrict__ as2,
                                            const float* __restrict__ ad2,
                                            const unsigned short* __restrict__ h2b,
                                            const float* __restrict__ b2,
                                            float* __restrict__ out) {
    int t = threadIdx.x;
    int wid = t >> 6, lane = t & 63;
    int d = blockIdx.x * 4 + wid;        // grid exact
    int g = lane >> 3;                    // edge subgroup 0..7
    int cl = lane & 7;                    // channel lane; active cl<5 (8 ch each)
    int clc = cl < 5 ? cl : 4;
    bool act = cl < 5;
    float adv = ad2[d];
    int rs = rowPtr[d], re = rowPtr[d + 1];
    float den = 0.f;
    float acc[8];
#pragma unroll
    for (int k = 0; k < 8; ++k) acc[k] = 0.f;

    const char* as2c = (const char*)as2;
    const char* h2c = (const char*)h2b;
    unsigned coff = (unsigned)(clc << 4);

#define LD2(J0, AV, HV)                                               \
    {                                                                 \
        int j = (J0) + g;                                             \
        bool val = j < re;                                            \
        int jj = val ? j : re - 1;                                    \
        unsigned ss = (unsigned)csrSrc[jj];                           \
        AV = val ? *(const float*)(as2c + (ss << 2)) : -1e30f;        \
        HV = *(const uint4*)(h2c + ss * 80u + coff);                  \
    }

    float avA, avB, avC, avD;
    uint4 hvA, hvB, hvC, hvD;
    LD2(rs,      avA, hvA);
    LD2(rs + 8,  avB, hvB);
    LD2(rs + 16, avC, hvC);
    LD2(rs + 24, avD, hvD);
    for (int j0 = rs; j0 < re; j0 += 32) {
        float tA, tB, tC, tD;
        uint4 uA, uB, uC, uD;
        LD2(j0 + 32, tA, uA);
        LD2(j0 + 40, tB, uB);
        LD2(j0 + 48, tC, uC);
        LD2(j0 + 56, tD, uD);
        PROC8(avA, hvA); PROC8(avB, hvB); PROC8(avC, hvC); PROC8(avD, hvD);
        avA = tA; avB = tB; avC = tC; avD = tD;
        hvA = uA; hvB = uB; hvC = uC; hvD = uD;
    }
#undef LD2

    // reduce across the 8 edge-groups
#pragma unroll
    for (int k = 0; k < 8; ++k) {
        acc[k] += __shfl_xor(acc[k], 8, 64);
        acc[k] += __shfl_xor(acc[k], 16, 64);
        acc[k] += __shfl_xor(acc[k], 32, 64);
    }
    den += __shfl_xor(den, 8, 64);
    den += __shfl_xor(den, 16, 64);
    den += __shfl_xor(den, 32, 64);
    float invd = 1.f / (den + 1e-16f);

    float v[8];
    float mk = -1e30f;
    if (act) {
        const float4* bp = (const float4*)(b2 + cl * 8);
        float4 ba = bp[0], bb = bp[1];
        v[0] = acc[0] * invd + ba.x; v[1] = acc[1] * invd + ba.y;
        v[2] = acc[2] * invd + ba.z; v[3] = acc[3] * invd + ba.w;
        v[4] = acc[4] * invd + bb.x; v[5] = acc[5] * invd + bb.y;
        v[6] = acc[6] * invd + bb.z; v[7] = acc[7] * invd + bb.w;
#pragma unroll
        for (int k = 0; k < 8; ++k) mk = fmaxf(mk, v[k]);
    }
    mk = fmaxf(mk, __shfl_xor(mk, 1, 64));
    mk = fmaxf(mk, __shfl_xor(mk, 2, 64));
    mk = fmaxf(mk, __shfl_xor(mk, 4, 64));
    float e = 0.f;
    if (act) {
#pragma unroll
        for (int k = 0; k < 8; ++k) e += __expf(v[k] - mk);
    }
    e += __shfl_xor(e, 1, 64);
    e += __shfl_xor(e, 2, 64);
    e += __shfl_xor(e, 4, 64);
    float lse = mk + logf(e);
    if (lane < 5) {   // group 0, active channel lanes
        float4 o0 = make_float4(v[0] - lse, v[1] - lse, v[2] - lse, v[3] - lse);
        float4 o1 = make_float4(v[4] - lse, v[5] - lse, v[6] - lse, v[7] - lse);
        float* po = out + (size_t)d * NC + cl * 8;
        *(float4*)po = o0;
        *(float4*)(po + 4) = o1;
    }
}

extern "C" void kernel_launch(void* const* d_in, const int* in_sizes, int n_in,
                              void* d_out, int out_size, void* d_ws, size_t ws_size,
                              hipStream_t stream) {
    const float* x       = (const float*)d_in[0];
    const unsigned* eidx = (const unsigned*)d_in[1];
    const float* W1      = (const float*)d_in[2];
    const float* atts1   = (const float*)d_in[3];
    const float* attd1   = (const float*)d_in[4];
    const float* b1      = (const float*)d_in[5];
    const float* W2      = (const float*)d_in[6];
    const float* atts2   = (const float*)d_in[7];
    const float* attd2   = (const float*)d_in[8];
    const float* b2      = (const float*)d_in[9];
    float* out = (float*)d_out;

    char* base = (char*)d_ws;
    size_t off = 0;
    auto takeB = [&](size_t bytes) {
        void* p = base + off;
        off = (off + bytes + 255) & ~(size_t)255;
        return p;
    };
    unsigned* flag = (unsigned*)takeB(256);
    int* cnt       = (int*)takeB((size_t)NODES * 4);
    int* fill      = (int*)takeB((size_t)NODES * 4);
    int* rowPtr    = (int*)takeB((size_t)(NODES + 1) * 4);
    int* blockSum  = (int*)takeB(SCAN_BLK * 4);
    int* blockOff  = (int*)takeB(SCAN_BLK * 4);
    int* csrSrc    = (int*)takeB((size_t)ETOT * 4 + 256);
    unsigned short* W1t  = (unsigned short*)takeB((size_t)144 * NF * 2);
    unsigned short* h1b  = (unsigned short*)takeB((size_t)NODES * F1 * 2);
    float* as1     = (float*)takeB((size_t)NODES * NHEAD * 4);
    float* ad1     = (float*)takeB((size_t)NODES * NHEAD * 4);
    unsigned short* out1b = (unsigned short*)takeB((size_t)NODES * F1 * 2);
    unsigned short* h2b  = (unsigned short*)takeB((size_t)NODES * NC * 2 + 256);
    float* as2     = (float*)takeB((size_t)NODES * 4);
    float* ad2     = (float*)takeB((size_t)NODES * 4);

    hipMemsetAsync(flag, 0, 4, stream);
    hipMemsetAsync(cnt, 0, (size_t)NODES * 4, stream);
    hipMemsetAsync(fill, 0, (size_t)NODES * 4, stream);

    detect_k<<<1, 256, 0, stream>>>(eidx, flag);

    // CSR build (by destination), reading edge_index directly
    hist_k<<<(ETOT + 255) / 256, 256, 0, stream>>>(eidx, flag, cnt);
    scanA<<<SCAN_BLK, 256, 0, stream>>>(cnt, rowPtr, blockSum);
    scanB<<<1, 256, 0, stream>>>(blockSum, blockOff);
    scanC<<<SCAN_BLK, 256, 0, stream>>>(rowPtr, blockOff);
    scatter_k<<<(ETOT + 255) / 256, 256, 0, stream>>>(eidx, flag, rowPtr, fill, csrSrc);

    // Layer 1 (MFMA GEMM with fused a1k columns)
    prepW1<<<144, 256, 0, stream>>>(W1, atts1, attd1, W1t);
    gemm1m<<<(NODES + 63) / 64, 256, 0, stream>>>(x, W1t, h1b, as1, ad1);
    msg1<<<NODES / 4, 256, 0, stream>>>(rowPtr, csrSrc, as1, ad1, h1b, b1, out1b);

    // Layer 2
    gemm2k<<<NODES / 8, 320, 0, stream>>>(out1b, W2, atts2, attd2, h2b, as2, ad2);
    msg2<<<NODES / 4, 256, 0, stream>>>(rowPtr, csrSrc, as2, ad2, h2b, b2, out);
}

// Round 11
// 245.948 us; speedup vs baseline: 1.0418x; 1.0418x over previous
//
#include <hip/hip_runtime.h>
#include <math.h>

#define NODES 50000
#define NEDGE 800000
#define ETOT  (NEDGE + NODES)   // edges + self loops = 850000
#define NF    256
#define F1    128               // HEADS*NHID
#define NHEAD 8
#define NHID  16
#define NC    40
#define SCAN_BLK 196            // ceil((NODES+1)/256)

typedef __attribute__((ext_vector_type(8))) short bf16x8;
typedef __attribute__((ext_vector_type(4))) float f32x4;

__device__ __forceinline__ float bflo(unsigned u) { return __uint_as_float(u << 16); }
__device__ __forceinline__ float bfhi(unsigned u) { return __uint_as_float(u & 0xffff0000u); }
__device__ __forceinline__ unsigned short f2bf(float f) {
    unsigned u = __float_as_uint(f);
    unsigned r = u + 0x7fffu + ((u >> 16) & 1u);   // RNE
    return (unsigned short)(r >> 16);
}
__device__ __forceinline__ unsigned pk2(float a, float b) {
    return (unsigned)f2bf(a) | ((unsigned)f2bf(b) << 16);
}

// ---------- edge index dtype detect ----------
__global__ void detect_k(const unsigned* __restrict__ u, unsigned* __restrict__ flag) {
    int t = threadIdx.x;              // 256 threads
    if (u[2 * t + 1] != 0u) atomicOr(flag, 1u);   // nonzero hi-word pattern => int32 data
}

// ---------- CSR build (reads edge_index directly) ----------
__global__ void hist_k(const unsigned* __restrict__ u, const unsigned* __restrict__ flag,
                       int* __restrict__ cnt) {
    int e = blockIdx.x * 256 + threadIdx.x;
    if (e >= ETOT) return;
    int d;
    if (e < NEDGE) d = (*flag) ? (int)u[NEDGE + e] : (int)u[2 * NEDGE + 2 * e];
    else d = e - NEDGE;
    atomicAdd(&cnt[d], 1);
}

// ---------- multi-block exclusive scan of cnt[0..NODES] -> rowPtr ----------
__global__ __launch_bounds__(256) void scanA(const int* __restrict__ cnt,
                                             int* __restrict__ rowPtr,
                                             int* __restrict__ blockSum) {
    int idx = blockIdx.x * 256 + threadIdx.x;
    int lane = threadIdx.x & 63, w = threadIdx.x >> 6;
    int v = (idx < NODES) ? cnt[idx] : 0;
    int s = v;
#pragma unroll
    for (int off = 1; off < 64; off <<= 1) {
        int o = __shfl_up(s, off, 64);
        if (lane >= off) s += o;
    }
    __shared__ int wsum[4];
    if (lane == 63) wsum[w] = s;
    __syncthreads();
    int wadd = 0;
    for (int i = 0; i < w; ++i) wadd += wsum[i];
    int incl = s + wadd;
    if (idx <= NODES) rowPtr[idx] = incl - v;        // block-local exclusive
    if (threadIdx.x == 255) blockSum[blockIdx.x] = incl;
}

__global__ __launch_bounds__(256) void scanB(const int* __restrict__ blockSum,
                                             int* __restrict__ blockOff) {
    __shared__ int sh[256];
    int t = threadIdx.x;
    int v = (t < SCAN_BLK) ? blockSum[t] : 0;
    sh[t] = v;
    __syncthreads();
    for (int off = 1; off < 256; off <<= 1) {
        int o = (t >= off) ? sh[t - off] : 0;
        __syncthreads();
        sh[t] += o;
        __syncthreads();
    }
    if (t < SCAN_BLK) blockOff[t] = sh[t] - v;       // exclusive
}

__global__ __launch_bounds__(256) void scanC(int* __restrict__ rowPtr,
                                             const int* __restrict__ blockOff) {
    int idx = blockIdx.x * 256 + threadIdx.x;
    if (idx <= NODES) rowPtr[idx] += blockOff[blockIdx.x];
}

__global__ void scatter_k(const unsigned* __restrict__ u, const unsigned* __restrict__ flag,
                          const int* __restrict__ rowPtr, int* __restrict__ fill,
                          int* __restrict__ csrSrc) {
    int e = blockIdx.x * 256 + threadIdx.x;
    if (e >= ETOT) return;
    int s, d;
    if (e < NEDGE) {
        if (*flag) { s = (int)u[e]; d = (int)u[NEDGE + e]; }
        else       { s = (int)u[2 * e]; d = (int)u[2 * NEDGE + 2 * e]; }
    } else s = d = e - NEDGE;
    int pos = rowPtr[d] + atomicAdd(&fill[d], 1);
    csrSrc[pos] = s;
}

// ---------- prep: W1t144[144][256] bf16 = [W1^T ; W1.atts1 per head ; W1.attd1] ----------
__global__ void prepW1(const float* __restrict__ W1, const float* __restrict__ atts1,
                       const float* __restrict__ attd1, unsigned short* __restrict__ W1t) {
    int n = blockIdx.x;      // 0..143
    int k = threadIdx.x;     // 0..255
    float v;
    if (n < 128) {
        v = W1[(size_t)k * F1 + n];
    } else if (n < 136) {
        int h = n - 128; v = 0.f;
#pragma unroll
        for (int c = 0; c < 16; ++c) v += W1[(size_t)k * F1 + h * 16 + c] * atts1[h * 16 + c];
    } else {
        int h = n - 136; v = 0.f;
#pragma unroll
        for (int c = 0; c < 16; ++c) v += W1[(size_t)k * F1 + h * 16 + c] * attd1[h * 16 + c];
    }
    W1t[(size_t)n * NF + k] = f2bf(v);
}

// ---------- MFMA GEMM1: x[N,256] @ W1t144^T -> h1b[,128] bf16 + as1/ad1 ----------
// x loads issued up-front behind a sched_barrier (16-deep MLP), W1t staged in
// LDS (XOR-swizzled) so B-fragments come from ds_read_b128, not global.
__global__ __launch_bounds__(256) void gemm1m(const float* __restrict__ x,
                                              const unsigned short* __restrict__ W1t,
                                              unsigned short* __restrict__ h1b,
                                              float* __restrict__ as1,
                                              float* __restrict__ ad1) {
    __shared__ uint4 wlds[4608];         // 144 rows x 32 uint4 = 73728 B
    int t = threadIdx.x;
    int wave = t >> 6, lane = t & 63;
    int mbase = blockIdx.x * 64 + wave * 16;
    int row = mbase + (lane & 15);
    int rowc = min(row, NODES - 1);
    int kg = lane >> 4;              // 0..3
    const float4* xr = (const float4*)(x + (size_t)rowc * NF + kg * 8);

    // 1) issue the full K-strip loads (16 independent dwordx4 in flight)
    float4 xa[16];
#pragma unroll
    for (int ks = 0; ks < 8; ++ks) {
        xa[2 * ks]     = xr[ks * 8];
        xa[2 * ks + 1] = xr[ks * 8 + 1];
    }
    __builtin_amdgcn_sched_barrier(0);   // pin loads before the staging code

    // 2) stage W1t into LDS, swizzled: uint4 idx i -> i ^ (row&7), row = i>>5
#pragma unroll
    for (int it = 0; it < 18; ++it) {
        int i = it * 256 + t;
        wlds[i ^ ((i >> 5) & 7)] = ((const uint4*)W1t)[i];
    }
    __syncthreads();                     // also drains the x loads (all parallel)

    f32x4 acc[9];
#pragma unroll
    for (int f = 0; f < 9; ++f) acc[f] = (f32x4){0.f, 0.f, 0.f, 0.f};

    int r = lane & 15;
    int swz = r & 7;
    int rb = r * 32 + kg;                // uint4 index base within a frag row-block

#pragma unroll
    for (int ks = 0; ks < 8; ++ks) {
        union { uint4 u; bf16x8 v; } A;
        float4 a0 = xa[2 * ks], a1 = xa[2 * ks + 1];
        A.u.x = pk2(a0.x, a0.y); A.u.y = pk2(a0.z, a0.w);
        A.u.z = pk2(a1.x, a1.y); A.u.w = pk2(a1.z, a1.w);
#pragma unroll
        for (int f = 0; f < 9; ++f) {
            union { uint4 u; bf16x8 v; } B;
            B.u = wlds[(f * 512 + rb + ks * 4) ^ swz];
            acc[f] = __builtin_amdgcn_mfma_f32_16x16x32_bf16(A.v, B.v, acc[f], 0, 0, 0);
        }
    }

    // store: C/D layout col=lane&15, row=(lane>>4)*4+reg
    int col = lane & 15;
    int rbase = mbase + (lane >> 4) * 4;
#pragma unroll
    for (int f = 0; f < 8; ++f) {
#pragma unroll
        for (int i = 0; i < 4; ++i) {
            int rr = rbase + i;
            if (rr < NODES) h1b[(size_t)rr * F1 + f * 16 + col] = f2bf(acc[f][i]);
        }
    }
#pragma unroll
    for (int i = 0; i < 4; ++i) {
        int rr = rbase + i;
        if (rr < NODES) {
            float v = acc[8][i];
            if (col < 8) as1[(size_t)rr * NHEAD + col] = v;
            else ad1[(size_t)rr * NHEAD + (col - 8)] = v;
        }
    }
}

// no-max softmax step: 8 channels per lane
#define PROC8(AV, HV)                                    \
    {                                                    \
        float l = (AV) + adv;                            \
        l = l > 0.f ? l : 0.2f * l;                      \
        float p = __expf(l);                             \
        den += p;                                        \
        acc[0] += p * bflo(HV.x); acc[1] += p * bfhi(HV.x); \
        acc[2] += p * bflo(HV.y); acc[3] += p * bfhi(HV.y); \
        acc[4] += p * bflo(HV.z); acc[5] += p * bfhi(HV.z); \
        acc[6] += p * bflo(HV.w); acc[7] += p * bfhi(HV.w); \
    }

// ---------- L1 gather: wave per dst, 3-stage pipeline (idx -> gather -> use),
//            predicated gathers (masked lanes issue no memory requests) ----------
__global__ __launch_bounds__(256) void msg1(const int* __restrict__ rowPtr,
                                            const int* __restrict__ csrSrc,
                                            const float* __restrict__ as1,
                                            const float* __restrict__ ad1,
                                            const unsigned short* __restrict__ h1b,
                                            const float* __restrict__ b1,
                                            unsigned short* __restrict__ out1b) {
    int t = threadIdx.x;
    int wid = t >> 6, lane = t & 63;
    int d = blockIdx.x * 4 + wid;        // grid exact (50000/4)
    int g = lane >> 4;                    // edge subgroup 0..3
    int cl = lane & 15;                   // channel lane: ch 8*cl..8*cl+7
    int h = cl >> 1;                      // head
    float adv = ad1[(size_t)d * NHEAD + h];
    int rs = rowPtr[d], re = rowPtr[d + 1];   // re > rs (self-loops)
    float den = 0.f;
    float acc[8];
#pragma unroll
    for (int k = 0; k < 8; ++k) acc[k] = 0.f;

    const char* as1c = (const char*)as1;
    const char* h1c = (const char*)h1b;
    unsigned hoff = (unsigned)(h << 2);
    unsigned coff = (unsigned)(cl << 4);

#define IDX1(J0, SS) { int j = (J0) + g; SS = csrSrc[j < re ? j : re - 1]; }
#define GTH1(J0, SS, AV, HV)                                          \
    {                                                                 \
        AV = -1e30f; HV = make_uint4(0u, 0u, 0u, 0u);                 \
        if ((J0) + g < re) {                                          \
            unsigned ss = (unsigned)(SS);                             \
            AV = *(const float*)(as1c + (ss << 5) + hoff);            \
            HV = *(const uint4*)(h1c + (ss << 8) + coff);             \
        }                                                             \
    }

    int sA, sB, sC, sD, sE, sF;
    float avA, avB, avC, avD;
    uint4 hvA, hvB, hvC, hvD;
    IDX1(rs, sA); IDX1(rs + 4, sB);
    GTH1(rs, sA, avA, hvA); GTH1(rs + 4, sB, avB, hvB);
    IDX1(rs + 8, sC); IDX1(rs + 12, sD);
    GTH1(rs + 8, sC, avC, hvC); GTH1(rs + 12, sD, avD, hvD);
    IDX1(rs + 16, sE); IDX1(rs + 20, sF);

    for (int j0 = rs; j0 < re; j0 += 8) {
        int sG, sH;
        IDX1(j0 + 24, sG); IDX1(j0 + 28, sH);
        float avE, avF; uint4 hvE, hvF;
        GTH1(j0 + 16, sE, avE, hvE); GTH1(j0 + 20, sF, avF, hvF);
        PROC8(avA, hvA); PROC8(avB, hvB);
        avA = avC; hvA = hvC; avB = avD; hvB = hvD;
        avC = avE; hvC = hvE; avD = avF; hvD = hvF;
        sE = sG; sF = sH;
    }
#undef IDX1
#undef GTH1

    // reduce across the 4 edge-groups
#pragma unroll
    for (int k = 0; k < 8; ++k) {
        acc[k] += __shfl_xor(acc[k], 16, 64);
        acc[k] += __shfl_xor(acc[k], 32, 64);
    }
    den += __shfl_xor(den, 16, 64);
    den += __shfl_xor(den, 32, 64);
    float invd = 1.f / (den + 1e-16f);

    if (g == 0) {
        const float4* bp = (const float4*)(b1 + cl * 8);
        float4 ba = bp[0], bb = bp[1];
        float v[8];
        v[0] = acc[0] * invd + ba.x; v[1] = acc[1] * invd + ba.y;
        v[2] = acc[2] * invd + ba.z; v[3] = acc[3] * invd + ba.w;
        v[4] = acc[4] * invd + bb.x; v[5] = acc[5] * invd + bb.y;
        v[6] = acc[6] * invd + bb.z; v[7] = acc[7] * invd + bb.w;
#pragma unroll
        for (int k = 0; k < 8; ++k) {
            float ev = __expf(v[k]) - 1.f;          // ELU negative branch
            v[k] = v[k] > 0.f ? v[k] : ev;
        }
        uint4 o;
        o.x = pk2(v[0], v[1]); o.y = pk2(v[2], v[3]);
        o.z = pk2(v[4], v[5]); o.w = pk2(v[6], v[7]);
        *(uint4*)(out1b + (size_t)d * F1 + cl * 8) = o;
    }
}

// ---------- GEMM2: out1b[N,128]bf16 @ W2[128,40] -> h2b (bf16) + fused a2k ----------
__global__ __launch_bounds__(320) void gemm2k(const unsigned short* __restrict__ a,
                                              const float* __restrict__ W,
                                              const float* __restrict__ atts2,
                                              const float* __restrict__ attd2,
                                              unsigned short* __restrict__ h2b,
                                              float* __restrict__ as2,
                                              float* __restrict__ ad2) {
    __shared__ float xs[8][132];
    __shared__ float red[2][320];
    int t = threadIdx.x;
    int base = blockIdx.x * 8;           // grid exact (50000/8)
    if (t < 256) {
        int row = t >> 5, q = t & 31;
        uint2 u = *(const uint2*)(a + (size_t)(base + row) * F1 + q * 4);
        float4 f;
        f.x = bflo(u.x); f.y = bfhi(u.x); f.z = bflo(u.y); f.w = bfhi(u.y);
        *(float4*)(&xs[row][q * 4]) = f;
    }
    __syncthreads();
    int n = t / 40, c = t % 40;
    float acc = 0.f;
    for (int k4 = 0; k4 < 32; ++k4) {
        float4 xv = *(const float4*)(&xs[n][k4 * 4]);
        const float* wp = W + (size_t)k4 * 4 * NC + c;
        acc += xv.x * wp[0];
        acc += xv.y * wp[NC];
        acc += xv.z * wp[2 * NC];
        acc += xv.w * wp[3 * NC];
    }
    int node = base + n;
    h2b[(size_t)node * NC + c] = f2bf(acc);
    red[0][n * 40 + c] = acc * atts2[c];
    red[1][n * 40 + c] = acc * attd2[c];
    __syncthreads();
    if (t < 16) {
        int which = t >> 3, nn = t & 7;
        const float* p = red[which] + nn * 40;
        float s = 0.f;
        for (int q = 0; q < 40; ++q) s += p[q];
        if (which) ad2[base + nn] = s; else as2[base + nn] = s;
    }
}

// ---------- L2 gather: wave per dst, 3-stage pipeline, predicated gathers ----------
__global__ __launch_bounds__(256) void msg2(const int* __restrict__ rowPtr,
                                            const int* __restrict__ csrSrc,
                                            const float* __restrict__ as2,
                                            const float* __restrict__ ad2,
                                            const unsigned short* __restrict__ h2b,
                                            const float* __restrict__ b2,
                                            float* __restrict__ out) {
    int t = threadIdx.x;
    int wid = t >> 6, lane = t & 63;
    int d = blockIdx.x * 4 + wid;        // grid exact
    int g = lane >> 3;                    // edge subgroup 0..7
    int cl = lane & 7;                    // channel lane; active cl<5 (8 ch each)
    int clc = cl < 5 ? cl : 4;
    bool act = cl < 5;
    float adv = ad2[d];
    int rs = rowPtr[d], re = rowPtr[d + 1];
    float den = 0.f;
    float acc[8];
#pragma unroll
    for (int k = 0; k < 8; ++k) acc[k] = 0.f;

    const char* as2c = (const char*)as2;
    const char* h2c = (const char*)h2b;
    unsigned coff = (unsigned)(clc << 4);

#define IDX2(J0, SS) { int j = (J0) + g; SS = csrSrc[j < re ? j : re - 1]; }
#define GTH2(J0, SS, AV, HV)                                          \
    {                                                                 \
        AV = -1e30f; HV = make_uint4(0u, 0u, 0u, 0u);                 \
        if ((J0) + g < re) {                                          \
            unsigned ss = (unsigned)(SS);                             \
            AV = *(const float*)(as2c + (ss << 2));                   \
            HV = *(const uint4*)(h2c + ss * 80u + coff);              \
        }                                                             \
    }

    int sA, sB, sC, sD, sE, sF;
    float avA, avB, avC, avD;
    uint4 hvA, hvB, hvC, hvD;
    IDX2(rs, sA); IDX2(rs + 8, sB);
    GTH2(rs, sA, avA, hvA); GTH2(rs + 8, sB, avB, hvB);
    IDX2(rs + 16, sC); IDX2(rs + 24, sD);
    GTH2(rs + 16, sC, avC, hvC); GTH2(rs + 24, sD, avD, hvD);
    IDX2(rs + 32, sE); IDX2(rs + 40, sF);

    for (int j0 = rs; j0 < re; j0 += 16) {
        int sG, sH;
        IDX2(j0 + 48, sG); IDX2(j0 + 56, sH);
        float avE, avF; uint4 hvE, hvF;
        GTH2(j0 + 32, sE, avE, hvE); GTH2(j0 + 40, sF, avF, hvF);
        PROC8(avA, hvA); PROC8(avB, hvB);
        avA = avC; hvA = hvC; avB = avD; hvB = hvD;
        avC = avE; hvC = hvE; avD = avF; hvD = hvF;
        sE = sG; sF = sH;
    }
#undef IDX2
#undef GTH2

    // reduce across the 8 edge-groups
#pragma unroll
    for (int k = 0; k < 8; ++k) {
        acc[k] += __shfl_xor(acc[k], 8, 64);
        acc[k] += __shfl_xor(acc[k], 16, 64);
        acc[k] += __shfl_xor(acc[k], 32, 64);
    }
    den += __shfl_xor(den, 8, 64);
    den += __shfl_xor(den, 16, 64);
    den += __shfl_xor(den, 32, 64);
    float invd = 1.f / (den + 1e-16f);

    float v[8];
    float mk = -1e30f;
    if (act) {
        const float4* bp = (const float4*)(b2 + cl * 8);
        float4 ba = bp[0], bb = bp[1];
        v[0] = acc[0] * invd + ba.x; v[1] = acc[1] * invd + ba.y;
        v[2] = acc[2] * invd + ba.z; v[3] = acc[3] * invd + ba.w;
        v[4] = acc[4] * invd + bb.x; v[5] = acc[5] * invd + bb.y;
        v[6] = acc[6] * invd + bb.z; v[7] = acc[7] * invd + bb.w;
#pragma unroll
        for (int k = 0; k < 8; ++k) mk = fmaxf(mk, v[k]);
    }
    mk = fmaxf(mk, __shfl_xor(mk, 1, 64));
    mk = fmaxf(mk, __shfl_xor(mk, 2, 64));
    mk = fmaxf(mk, __shfl_xor(mk, 4, 64));
    float e = 0.f;
    if (act) {
#pragma unroll
        for (int k = 0; k < 8; ++k) e += __expf(v[k] - mk);
    }
    e += __shfl_xor(e, 1, 64);
    e += __shfl_xor(e, 2, 64);
    e += __shfl_xor(e, 4, 64);
    float lse = mk + logf(e);
    if (lane < 5) {   // group 0, active channel lanes
        float4 o0 = make_float4(v[0] - lse, v[1] - lse, v[2] - lse, v[3] - lse);
        float4 o1 = make_float4(v[4] - lse, v[5] - lse, v[6] - lse, v[7] - lse);
        float* po = out + (size_t)d * NC + cl * 8;
        *(float4*)po = o0;
        *(float4*)(po + 4) = o1;
    }
}

extern "C" void kernel_launch(void* const* d_in, const int* in_sizes, int n_in,
                              void* d_out, int out_size, void* d_ws, size_t ws_size,
                              hipStream_t stream) {
    const float* x       = (const float*)d_in[0];
    const unsigned* eidx = (const unsigned*)d_in[1];
    const float* W1      = (const float*)d_in[2];
    const float* atts1   = (const float*)d_in[3];
    const float* attd1   = (const float*)d_in[4];
    const float* b1      = (const float*)d_in[5];
    const float* W2      = (const float*)d_in[6];
    const float* atts2   = (const float*)d_in[7];
    const float* attd2   = (const float*)d_in[8];
    const float* b2      = (const float*)d_in[9];
    float* out = (float*)d_out;

    char* base = (char*)d_ws;
    size_t off = 0;
    auto takeB = [&](size_t bytes) {
        void* p = base + off;
        off = (off + bytes + 255) & ~(size_t)255;
        return p;
    };
    unsigned* flag = (unsigned*)takeB(256);
    int* cnt       = (int*)takeB((size_t)NODES * 4);
    int* fill      = (int*)takeB((size_t)NODES * 4);
    int* rowPtr    = (int*)takeB((size_t)(NODES + 1) * 4);
    int* blockSum  = (int*)takeB(SCAN_BLK * 4);
    int* blockOff  = (int*)takeB(SCAN_BLK * 4);
    int* csrSrc    = (int*)takeB((size_t)ETOT * 4 + 256);
    unsigned short* W1t  = (unsigned short*)takeB((size_t)144 * NF * 2);
    unsigned short* h1b  = (unsigned short*)takeB((size_t)NODES * F1 * 2);
    float* as1     = (float*)takeB((size_t)NODES * NHEAD * 4);
    float* ad1     = (float*)takeB((size_t)NODES * NHEAD * 4);
    unsigned short* out1b = (unsigned short*)takeB((size_t)NODES * F1 * 2);
    unsigned short* h2b  = (unsigned short*)takeB((size_t)NODES * NC * 2 + 256);
    float* as2     = (float*)takeB((size_t)NODES * 4);
    float* ad2     = (float*)takeB((size_t)NODES * 4);

    hipMemsetAsync(flag, 0, 4, stream);
    hipMemsetAsync(cnt, 0, (size_t)NODES * 4, stream);
    hipMemsetAsync(fill, 0, (size_t)NODES * 4, stream);

    detect_k<<<1, 256, 0, stream>>>(eidx, flag);

    // CSR build (by destination), reading edge_index directly
    hist_k<<<(ETOT + 255) / 256, 256, 0, stream>>>(eidx, flag, cnt);
    scanA<<<SCAN_BLK, 256, 0, stream>>>(cnt, rowPtr, blockSum);
    scanB<<<1, 256, 0, stream>>>(blockSum, blockOff);
    scanC<<<SCAN_BLK, 256, 0, stream>>>(rowPtr, blockOff);
    scatter_k<<<(ETOT + 255) / 256, 256, 0, stream>>>(eidx, flag, rowPtr, fill, csrSrc);

    // Layer 1 (MFMA GEMM with fused a1k columns)
    prepW1<<<144, 256, 0, stream>>>(W1, atts1, attd1, W1t);
    gemm1m<<<(NODES + 63) / 64, 256, 0, stream>>>(x, W1t, h1b, as1, ad1);
    msg1<<<NODES / 4, 256, 0, stream>>>(rowPtr, csrSrc, as1, ad1, h1b, b1, out1b);

    // Layer 2
    gemm2k<<<NODES / 8, 320, 0, stream>>>(out1b, W2, atts2, attd2, h2b, as2, ad2);
    msg2<<<NODES / 4, 256, 0, stream>>>(rowPtr, csrSrc, as2, ad2, h2b, b2, out);
}

// Round 13
// 226.472 us; speedup vs baseline: 1.1314x; 1.0860x over previous
//
#include <hip/hip_runtime.h>
#include <math.h>

#define NODES 50000
#define NEDGE 800000
#define ETOT  (NEDGE + NODES)   // edges + self loops = 850000
#define NF    256
#define F1    128               // HEADS*NHID
#define NHEAD 8
#define NHID  16
#define NC    40
#define SCAN_BLK 196            // ceil((NODES+1)/256)

typedef __attribute__((ext_vector_type(8))) short bf16x8;
typedef __attribute__((ext_vector_type(4))) float f32x4;

__device__ __forceinline__ float bflo(unsigned u) { return __uint_as_float(u << 16); }
__device__ __forceinline__ float bfhi(unsigned u) { return __uint_as_float(u & 0xffff0000u); }
__device__ __forceinline__ unsigned short f2bf(float f) {
    unsigned u = __float_as_uint(f);
    unsigned r = u + 0x7fffu + ((u >> 16) & 1u);   // RNE
    return (unsigned short)(r >> 16);
}
__device__ __forceinline__ unsigned pk2(float a, float b) {
    return (unsigned)f2bf(a) | ((unsigned)f2bf(b) << 16);
}

// ---------- edge index dtype detect ----------
__global__ void detect_k(const unsigned* __restrict__ u, unsigned* __restrict__ flag) {
    int t = threadIdx.x;              // 256 threads
    if (u[2 * t + 1] != 0u) atomicOr(flag, 1u);   // nonzero hi-word pattern => int32 data
}

// ---------- CSR build (reads edge_index directly) ----------
__global__ void hist_k(const unsigned* __restrict__ u, const unsigned* __restrict__ flag,
                       int* __restrict__ cnt) {
    int e = blockIdx.x * 256 + threadIdx.x;
    if (e >= ETOT) return;
    int d;
    if (e < NEDGE) d = (*flag) ? (int)u[NEDGE + e] : (int)u[2 * NEDGE + 2 * e];
    else d = e - NEDGE;
    atomicAdd(&cnt[d], 1);
}

// ---------- multi-block exclusive scan of cnt[0..NODES] -> rowPtr ----------
__global__ __launch_bounds__(256) void scanA(const int* __restrict__ cnt,
                                             int* __restrict__ rowPtr,
                                             int* __restrict__ blockSum) {
    int idx = blockIdx.x * 256 + threadIdx.x;
    int lane = threadIdx.x & 63, w = threadIdx.x >> 6;
    int v = (idx < NODES) ? cnt[idx] : 0;
    int s = v;
#pragma unroll
    for (int off = 1; off < 64; off <<= 1) {
        int o = __shfl_up(s, off, 64);
        if (lane >= off) s += o;
    }
    __shared__ int wsum[4];
    if (lane == 63) wsum[w] = s;
    __syncthreads();
    int wadd = 0;
    for (int i = 0; i < w; ++i) wadd += wsum[i];
    int incl = s + wadd;
    if (idx <= NODES) rowPtr[idx] = incl - v;        // block-local exclusive
    if (threadIdx.x == 255) blockSum[blockIdx.x] = incl;
}

__global__ __launch_bounds__(256) void scanB(const int* __restrict__ blockSum,
                                             int* __restrict__ blockOff) {
    __shared__ int sh[256];
    int t = threadIdx.x;
    int v = (t < SCAN_BLK) ? blockSum[t] : 0;
    sh[t] = v;
    __syncthreads();
    for (int off = 1; off < 256; off <<= 1) {
        int o = (t >= off) ? sh[t - off] : 0;
        __syncthreads();
        sh[t] += o;
        __syncthreads();
    }
    if (t < SCAN_BLK) blockOff[t] = sh[t] - v;       // exclusive
}

__global__ __launch_bounds__(256) void scanC(int* __restrict__ rowPtr,
                                             const int* __restrict__ blockOff) {
    int idx = blockIdx.x * 256 + threadIdx.x;
    if (idx <= NODES) rowPtr[idx] += blockOff[blockIdx.x];
}

__global__ void scatter_k(const unsigned* __restrict__ u, const unsigned* __restrict__ flag,
                          const int* __restrict__ rowPtr, int* __restrict__ fill,
                          int* __restrict__ csrSrc) {
    int e = blockIdx.x * 256 + threadIdx.x;
    if (e >= ETOT) return;
    int s, d;
    if (e < NEDGE) {
        if (*flag) { s = (int)u[e]; d = (int)u[NEDGE + e]; }
        else       { s = (int)u[2 * e]; d = (int)u[2 * NEDGE + 2 * e]; }
    } else s = d = e - NEDGE;
    int pos = rowPtr[d] + atomicAdd(&fill[d], 1);
    csrSrc[pos] = s;
}

// ---------- prep: W1t144[144][256] bf16 = [W1^T ; W1.atts1 per head ; W1.attd1] ----------
__global__ void prepW1(const float* __restrict__ W1, const float* __restrict__ atts1,
                       const float* __restrict__ attd1, unsigned short* __restrict__ W1t) {
    int n = blockIdx.x;      // 0..143
    int k = threadIdx.x;     // 0..255
    float v;
    if (n < 128) {
        v = W1[(size_t)k * F1 + n];
    } else if (n < 136) {
        int h = n - 128; v = 0.f;
#pragma unroll
        for (int c = 0; c < 16; ++c) v += W1[(size_t)k * F1 + h * 16 + c] * atts1[h * 16 + c];
    } else {
        int h = n - 136; v = 0.f;
#pragma unroll
        for (int c = 0; c < 16; ++c) v += W1[(size_t)k * F1 + h * 16 + c] * attd1[h * 16 + c];
    }
    W1t[(size_t)n * NF + k] = f2bf(v);
}

// ---------- MFMA GEMM1: x[N,256] @ W1t144^T -> h1b[,128] bf16 + as1/ad1 ----------
__global__ __launch_bounds__(256) void gemm1m(const float* __restrict__ x,
                                              const unsigned short* __restrict__ W1t,
                                              unsigned short* __restrict__ h1b,
                                              float* __restrict__ as1,
                                              float* __restrict__ ad1) {
    __shared__ uint4 wlds[4608];         // 144 rows x 32 uint4 = 73728 B
    int t = threadIdx.x;
    int wave = t >> 6, lane = t & 63;
    int mbase = blockIdx.x * 64 + wave * 16;
    int row = mbase + (lane & 15);
    int rowc = min(row, NODES - 1);
    int kg = lane >> 4;              // 0..3
    const float4* xr = (const float4*)(x + (size_t)rowc * NF + kg * 8);

    // 1) issue the full K-strip loads (16 independent dwordx4 in flight)
    float4 xa[16];
#pragma unroll
    for (int ks = 0; ks < 8; ++ks) {
        xa[2 * ks]     = xr[ks * 8];
        xa[2 * ks + 1] = xr[ks * 8 + 1];
    }
    __builtin_amdgcn_sched_barrier(0);   // pin loads before the staging code

    // 2) stage W1t into LDS, swizzled: uint4 idx i -> i ^ (row&7), row = i>>5
#pragma unroll
    for (int it = 0; it < 18; ++it) {
        int i = it * 256 + t;
        wlds[i ^ ((i >> 5) & 7)] = ((const uint4*)W1t)[i];
    }
    __syncthreads();                     // also drains the x loads (all parallel)

    f32x4 acc[9];
#pragma unroll
    for (int f = 0; f < 9; ++f) acc[f] = (f32x4){0.f, 0.f, 0.f, 0.f};

    int r = lane & 15;
    int swz = r & 7;
    int rb = r * 32 + kg;                // uint4 index base within a frag row-block

#pragma unroll
    for (int ks = 0; ks < 8; ++ks) {
        union { uint4 u; bf16x8 v; } A;
        float4 a0 = xa[2 * ks], a1 = xa[2 * ks + 1];
        A.u.x = pk2(a0.x, a0.y); A.u.y = pk2(a0.z, a0.w);
        A.u.z = pk2(a1.x, a1.y); A.u.w = pk2(a1.z, a1.w);
#pragma unroll
        for (int f = 0; f < 9; ++f) {
            union { uint4 u; bf16x8 v; } B;
            B.u = wlds[(f * 512 + rb + ks * 4) ^ swz];
            acc[f] = __builtin_amdgcn_mfma_f32_16x16x32_bf16(A.v, B.v, acc[f], 0, 0, 0);
        }
    }

    // store: C/D layout col=lane&15, row=(lane>>4)*4+reg
    int col = lane & 15;
    int rbase = mbase + (lane >> 4) * 4;
#pragma unroll
    for (int f = 0; f < 8; ++f) {
#pragma unroll
        for (int i = 0; i < 4; ++i) {
            int rr = rbase + i;
            if (rr < NODES) h1b[(size_t)rr * F1 + f * 16 + col] = f2bf(acc[f][i]);
        }
    }
#pragma unroll
    for (int i = 0; i < 4; ++i) {
        int rr = rbase + i;
        if (rr < NODES) {
            float v = acc[8][i];
            if (col < 8) as1[(size_t)rr * NHEAD + col] = v;
            else ad1[(size_t)rr * NHEAD + (col - 8)] = v;
        }
    }
}

// no-max softmax step: 8 channels per lane
#define PROC8(AV, HV)                                    \
    {                                                    \
        float l = (AV) + adv;                            \
        l = l > 0.f ? l : 0.2f * l;                      \
        float p = __expf(l);                             \
        den += p;                                        \
        acc[0] += p * bflo(HV.x); acc[1] += p * bfhi(HV.x); \
        acc[2] += p * bflo(HV.y); acc[3] += p * bfhi(HV.y); \
        acc[4] += p * bflo(HV.z); acc[5] += p * bfhi(HV.z); \
        acc[6] += p * bflo(HV.w); acc[7] += p * bfhi(HV.w); \
    }

// ---------- L1 gather: 16-lane group per dst (4 dst/wave), depth-2, no shuffles ----------
__global__ __launch_bounds__(256) void msg1(const int* __restrict__ rowPtr,
                                            const int* __restrict__ csrSrc,
                                            const float* __restrict__ as1,
                                            const float* __restrict__ ad1,
                                            const unsigned short* __restrict__ h1b,
                                            const float* __restrict__ b1,
                                            unsigned short* __restrict__ out1b) {
    int t = threadIdx.x;
    int wid = t >> 6, lane = t & 63;
    int g = lane >> 4;                    // group 0..3 -> own dst
    int cl = lane & 15;                   // channel lane: ch 8*cl..8*cl+7
    int h = cl >> 1;                      // head
    int d = blockIdx.x * 16 + wid * 4 + g;   // grid exact: 3125*16 = 50000
    float adv = ad1[(size_t)d * NHEAD + h];
    int rs = rowPtr[d], re = rowPtr[d + 1];  // re > rs (self-loops)
    float den = 0.f;
    float acc[8];
#pragma unroll
    for (int k = 0; k < 8; ++k) acc[k] = 0.f;

    const char* as1c = (const char*)as1;
    const char* h1c = (const char*)h1b;
    unsigned hoff = (unsigned)(h << 2);
    unsigned coff = (unsigned)(cl << 4);

// NOTE: internal index named j_ to avoid shadowing the caller's loop variable
// (int j = (j+2) self-initialization UB was the R11 correctness bug).
#define LD1(J, AV, HV)                                                \
    {                                                                 \
        int j_ = (J);                                                 \
        AV = -1e30f; HV = make_uint4(0u, 0u, 0u, 0u);                 \
        if (j_ < re) {                                                \
            unsigned ss = (unsigned)csrSrc[j_];                       \
            AV = *(const float*)(as1c + (ss << 5) + hoff);            \
            HV = *(const uint4*)(h1c + (ss << 8) + coff);             \
        }                                                             \
    }

    float av0, av1; uint4 hv0, hv1;
    LD1(rs, av0, hv0);
    LD1(rs + 1, av1, hv1);
    for (int j = rs; j < re; j += 2) {
        float ta, tb; uint4 ua, ub;
        LD1(j + 2, ta, ua);
        LD1(j + 3, tb, ub);
        PROC8(av0, hv0);
        PROC8(av1, hv1);
        av0 = ta; hv0 = ua; av1 = tb; hv1 = ub;
    }
#undef LD1

    float invd = 1.f / (den + 1e-16f);
    const float4* bp = (const float4*)(b1 + cl * 8);
    float4 ba = bp[0], bb = bp[1];
    float v[8];
    v[0] = acc[0] * invd + ba.x; v[1] = acc[1] * invd + ba.y;
    v[2] = acc[2] * invd + ba.z; v[3] = acc[3] * invd + ba.w;
    v[4] = acc[4] * invd + bb.x; v[5] = acc[5] * invd + bb.y;
    v[6] = acc[6] * invd + bb.z; v[7] = acc[7] * invd + bb.w;
#pragma unroll
    for (int k = 0; k < 8; ++k) {
        float ev = __expf(v[k]) - 1.f;          // ELU negative branch
        v[k] = v[k] > 0.f ? v[k] : ev;
    }
    uint4 o;
    o.x = pk2(v[0], v[1]); o.y = pk2(v[2], v[3]);
    o.z = pk2(v[4], v[5]); o.w = pk2(v[6], v[7]);
    *(uint4*)(out1b + (size_t)d * F1 + cl * 8) = o;
}

// ---------- GEMM2: out1b[N,128]bf16 @ W2[128,40] -> h2b (bf16) + fused a2k ----------
__global__ __launch_bounds__(320) void gemm2k(const unsigned short* __restrict__ a,
                                              const float* __restrict__ W,
                                              const float* __restrict__ atts2,
                                              const float* __restrict__ attd2,
                                              unsigned short* __restrict__ h2b,
                                              float* __restrict__ as2,
                                              float* __restrict__ ad2) {
    __shared__ float xs[8][132];
    __shared__ float red[2][320];
    int t = threadIdx.x;
    int base = blockIdx.x * 8;           // grid exact (50000/8)
    if (t < 256) {
        int row = t >> 5, q = t & 31;
        uint2 u = *(const uint2*)(a + (size_t)(base + row) * F1 + q * 4);
        float4 f;
        f.x = bflo(u.x); f.y = bfhi(u.x); f.z = bflo(u.y); f.w = bfhi(u.y);
        *(float4*)(&xs[row][q * 4]) = f;
    }
    __syncthreads();
    int n = t / 40, c = t % 40;
    float acc = 0.f;
    for (int k4 = 0; k4 < 32; ++k4) {
        float4 xv = *(const float4*)(&xs[n][k4 * 4]);
        const float* wp = W + (size_t)k4 * 4 * NC + c;
        acc += xv.x * wp[0];
        acc += xv.y * wp[NC];
        acc += xv.z * wp[2 * NC];
        acc += xv.w * wp[3 * NC];
    }
    int node = base + n;
    h2b[(size_t)node * NC + c] = f2bf(acc);
    red[0][n * 40 + c] = acc * atts2[c];
    red[1][n * 40 + c] = acc * attd2[c];
    __syncthreads();
    if (t < 16) {
        int which = t >> 3, nn = t & 7;
        const float* p = red[which] + nn * 40;
        float s = 0.f;
        for (int q = 0; q < 40; ++q) s += p[q];
        if (which) ad2[base + nn] = s; else as2[base + nn] = s;
    }
}

// ---------- L2 gather: 8-lane group per dst (8 dst/wave), depth-2 ----------
__global__ __launch_bounds__(256) void msg2(const int* __restrict__ rowPtr,
                                            const int* __restrict__ csrSrc,
                                            const float* __restrict__ as2,
                                            const float* __restrict__ ad2,
                                            const unsigned short* __restrict__ h2b,
                                            const float* __restrict__ b2,
                                            float* __restrict__ out) {
    int t = threadIdx.x;
    int wid = t >> 6, lane = t & 63;
    int g = lane >> 3;                    // group 0..7 -> own dst
    int cl = lane & 7;                    // channel lane; active cl<5 (8 ch each)
    int clc = cl < 5 ? cl : 4;
    bool act = cl < 5;
    int d0 = blockIdx.x * 32 + wid * 8 + g;
    int d = min(d0, NODES - 1);
    float adv = ad2[d];
    int rs = rowPtr[d], re = rowPtr[d + 1];
    if (!act) { rs = 0; re = 0; }         // inactive lanes: no loads, no loop
    float den = 0.f;
    float acc[8];
#pragma unroll
    for (int k = 0; k < 8; ++k) acc[k] = 0.f;

    const char* as2c = (const char*)as2;
    const char* h2c = (const char*)h2b;
    unsigned coff = (unsigned)(clc << 4);

#define LD2(J, AV, HV)                                                \
    {                                                                 \
        int j_ = (J);                                                 \
        AV = -1e30f; HV = make_uint4(0u, 0u, 0u, 0u);                 \
        if (j_ < re) {                                                \
            unsigned ss = (unsigned)csrSrc[j_];                       \
            AV = *(const float*)(as2c + (ss << 2));                   \
            HV = *(const uint4*)(h2c + ss * 80u + coff);              \
        }                                                             \
    }

    float av0, av1; uint4 hv0, hv1;
    LD2(rs, av0, hv0);
    LD2(rs + 1, av1, hv1);
    for (int j = rs; j < re; j += 2) {
        float ta, tb; uint4 ua, ub;
        LD2(j + 2, ta, ua);
        LD2(j + 3, tb, ub);
        PROC8(av0, hv0);
        PROC8(av1, hv1);
        av0 = ta; hv0 = ua; av1 = tb; hv1 = ub;
    }
#undef LD2

    float invd = 1.f / (den + 1e-16f);
    float v[8];
    float mk = -1e30f;
    if (act) {
        const float4* bp = (const float4*)(b2 + cl * 8);
        float4 ba = bp[0], bb = bp[1];
        v[0] = acc[0] * invd + ba.x; v[1] = acc[1] * invd + ba.y;
        v[2] = acc[2] * invd + ba.z; v[3] = acc[3] * invd + ba.w;
        v[4] = acc[4] * invd + bb.x; v[5] = acc[5] * invd + bb.y;
        v[6] = acc[6] * invd + bb.z; v[7] = acc[7] * invd + bb.w;
#pragma unroll
        for (int k = 0; k < 8; ++k) mk = fmaxf(mk, v[k]);
    }
    // reduce within the 8-lane group
    mk = fmaxf(mk, __shfl_xor(mk, 1, 64));
    mk = fmaxf(mk, __shfl_xor(mk, 2, 64));
    mk = fmaxf(mk, __shfl_xor(mk, 4, 64));
    float e = 0.f;
    if (act) {
#pragma unroll
        for (int k = 0; k < 8; ++k) e += __expf(v[k] - mk);
    }
    e += __shfl_xor(e, 1, 64);
    e += __shfl_xor(e, 2, 64);
    e += __shfl_xor(e, 4, 64);
    float lse = mk + logf(e);
    if (act && d0 < NODES) {
        float4 o0 = make_float4(v[0] - lse, v[1] - lse, v[2] - lse, v[3] - lse);
        float4 o1 = make_float4(v[4] - lse, v[5] - lse, v[6] - lse, v[7] - lse);
        float* po = out + (size_t)d0 * NC + cl * 8;
        *(float4*)po = o0;
        *(float4*)(po + 4) = o1;
    }
}

extern "C" void kernel_launch(void* const* d_in, const int* in_sizes, int n_in,
                              void* d_out, int out_size, void* d_ws, size_t ws_size,
                              hipStream_t stream) {
    const float* x       = (const float*)d_in[0];
    const unsigned* eidx = (const unsigned*)d_in[1];
    const float* W1      = (const float*)d_in[2];
    const float* atts1   = (const float*)d_in[3];
    const float* attd1   = (const float*)d_in[4];
    const float* b1      = (const float*)d_in[5];
    const float* W2      = (const float*)d_in[6];
    const float* atts2   = (const float*)d_in[7];
    const float* attd2   = (const float*)d_in[8];
    const float* b2      = (const float*)d_in[9];
    float* out = (float*)d_out;

    char* base = (char*)d_ws;
    size_t off = 0;
    auto takeB = [&](size_t bytes) {
        void* p = base + off;
        off = (off + bytes + 255) & ~(size_t)255;
        return p;
    };
    unsigned* flag = (unsigned*)takeB(256);
    int* cnt       = (int*)takeB((size_t)NODES * 4);
    int* fill      = (int*)takeB((size_t)NODES * 4);
    int* rowPtr    = (int*)takeB((size_t)(NODES + 64) * 4);
    int* blockSum  = (int*)takeB(SCAN_BLK * 4);
    int* blockOff  = (int*)takeB(SCAN_BLK * 4);
    int* csrSrc    = (int*)takeB((size_t)ETOT * 4 + 256);
    unsigned short* W1t  = (unsigned short*)takeB((size_t)144 * NF * 2);
    unsigned short* h1b  = (unsigned short*)takeB((size_t)NODES * F1 * 2);
    float* as1     = (float*)takeB((size_t)NODES * NHEAD * 4);
    float* ad1     = (float*)takeB((size_t)NODES * NHEAD * 4);
    unsigned short* out1b = (unsigned short*)takeB((size_t)NODES * F1 * 2);
    unsigned short* h2b  = (unsigned short*)takeB((size_t)NODES * NC * 2 + 256);
    float* as2     = (float*)takeB((size_t)NODES * 4);
    float* ad2     = (float*)takeB((size_t)NODES * 4);

    hipMemsetAsync(flag, 0, 4, stream);
    hipMemsetAsync(cnt, 0, (size_t)NODES * 4, stream);
    hipMemsetAsync(fill, 0, (size_t)NODES * 4, stream);

    detect_k<<<1, 256, 0, stream>>>(eidx, flag);

    // CSR build (by destination), reading edge_index directly
    hist_k<<<(ETOT + 255) / 256, 256, 0, stream>>>(eidx, flag, cnt);
    scanA<<<SCAN_BLK, 256, 0, stream>>>(cnt, rowPtr, blockSum);
    scanB<<<1, 256, 0, stream>>>(blockSum, blockOff);
    scanC<<<SCAN_BLK, 256, 0, stream>>>(rowPtr, blockOff);
    scatter_k<<<(ETOT + 255) / 256, 256, 0, stream>>>(eidx, flag, rowPtr, fill, csrSrc);

    // Layer 1 (MFMA GEMM with fused a1k columns)
    prepW1<<<144, 256, 0, stream>>>(W1, atts1, attd1, W1t);
    gemm1m<<<(NODES + 63) / 64, 256, 0, stream>>>(x, W1t, h1b, as1, ad1);
    msg1<<<NODES / 16, 256, 0, stream>>>(rowPtr, csrSrc, as1, ad1, h1b, b1, out1b);

    // Layer 2
    gemm2k<<<NODES / 8, 320, 0, stream>>>(out1b, W2, atts2, attd2, h2b, as2, ad2);
    msg2<<<(NODES + 31) / 32, 256, 0, stream>>>(rowPtr, csrSrc, as2, ad2, h2b, b2, out);
}

// Round 14
// 203.116 us; speedup vs baseline: 1.2615x; 1.1150x over previous
//
#include <hip/hip_runtime.h>
#include <math.h>

#define NODES 50000
#define NEDGE 800000
#define ETOT  (NEDGE + NODES)   // edges + self loops = 850000
#define NF    256
#define F1    128               // HEADS*NHID
#define NHEAD 8
#define NHID  16
#define NC    40
#define SCAN_BLK 196            // ceil((NODES+1)/256)

typedef __attribute__((ext_vector_type(8))) short bf16x8;
typedef __attribute__((ext_vector_type(4))) float f32x4;

__device__ __forceinline__ float bflo(unsigned u) { return __uint_as_float(u << 16); }
__device__ __forceinline__ float bfhi(unsigned u) { return __uint_as_float(u & 0xffff0000u); }
__device__ __forceinline__ unsigned short f2bf(float f) {
    unsigned u = __float_as_uint(f);
    unsigned r = u + 0x7fffu + ((u >> 16) & 1u);   // RNE
    return (unsigned short)(r >> 16);
}
__device__ __forceinline__ unsigned pk2(float a, float b) {
    return (unsigned)f2bf(a) | ((unsigned)f2bf(b) << 16);
}

// ---------- edge index dtype detect ----------
__global__ void detect_k(const unsigned* __restrict__ u, unsigned* __restrict__ flag) {
    int t = threadIdx.x;              // 256 threads
    if (u[2 * t + 1] != 0u) atomicOr(flag, 1u);   // nonzero hi-word pattern => int32 data
}

// ---------- CSR build (reads edge_index directly) ----------
__global__ void hist_k(const unsigned* __restrict__ u, const unsigned* __restrict__ flag,
                       int* __restrict__ cnt) {
    int e = blockIdx.x * 256 + threadIdx.x;
    if (e >= ETOT) return;
    int d;
    if (e < NEDGE) d = (*flag) ? (int)u[NEDGE + e] : (int)u[2 * NEDGE + 2 * e];
    else d = e - NEDGE;
    atomicAdd(&cnt[d], 1);
}

// ---------- multi-block exclusive scan of cnt[0..NODES] -> rowPtr ----------
__global__ __launch_bounds__(256) void scanA(const int* __restrict__ cnt,
                                             int* __restrict__ rowPtr,
                                             int* __restrict__ blockSum) {
    int idx = blockIdx.x * 256 + threadIdx.x;
    int lane = threadIdx.x & 63, w = threadIdx.x >> 6;
    int v = (idx < NODES) ? cnt[idx] : 0;
    int s = v;
#pragma unroll
    for (int off = 1; off < 64; off <<= 1) {
        int o = __shfl_up(s, off, 64);
        if (lane >= off) s += o;
    }
    __shared__ int wsum[4];
    if (lane == 63) wsum[w] = s;
    __syncthreads();
    int wadd = 0;
    for (int i = 0; i < w; ++i) wadd += wsum[i];
    int incl = s + wadd;
    if (idx <= NODES) rowPtr[idx] = incl - v;        // block-local exclusive
    if (threadIdx.x == 255) blockSum[blockIdx.x] = incl;
}

__global__ __launch_bounds__(256) void scanB(const int* __restrict__ blockSum,
                                             int* __restrict__ blockOff) {
    __shared__ int sh[256];
    int t = threadIdx.x;
    int v = (t < SCAN_BLK) ? blockSum[t] : 0;
    sh[t] = v;
    __syncthreads();
    for (int off = 1; off < 256; off <<= 1) {
        int o = (t >= off) ? sh[t - off] : 0;
        __syncthreads();
        sh[t] += o;
        __syncthreads();
    }
    if (t < SCAN_BLK) blockOff[t] = sh[t] - v;       // exclusive
}

__global__ __launch_bounds__(256) void scanC(int* __restrict__ rowPtr,
                                             const int* __restrict__ blockOff) {
    int idx = blockIdx.x * 256 + threadIdx.x;
    if (idx <= NODES) rowPtr[idx] += blockOff[blockIdx.x];
}

// 4 edges per thread: independent atomic chains overlap in the VMEM queue
__global__ void scatter_k(const unsigned* __restrict__ u, const unsigned* __restrict__ flag,
                          const int* __restrict__ rowPtr, int* __restrict__ fill,
                          int* __restrict__ csrSrc) {
    int base = (blockIdx.x * 256 + threadIdx.x) * 4;
    bool isi32 = (*flag) != 0;
    int s[4], d[4];
#pragma unroll
    for (int q = 0; q < 4; ++q) {
        int e = base + q;
        d[q] = -1;
        if (e < ETOT) {
            if (e < NEDGE) {
                if (isi32) { s[q] = (int)u[e]; d[q] = (int)u[NEDGE + e]; }
                else       { s[q] = (int)u[2 * e]; d[q] = (int)u[2 * NEDGE + 2 * e]; }
            } else { s[q] = d[q] = e - NEDGE; }
        }
    }
    int pos[4];
#pragma unroll
    for (int q = 0; q < 4; ++q)
        if (d[q] >= 0) pos[q] = atomicAdd(&fill[d[q]], 1);
#pragma unroll
    for (int q = 0; q < 4; ++q)
        if (d[q] >= 0) csrSrc[rowPtr[d[q]] + pos[q]] = s[q];
}

// ---------- prep: W1t144[144][256] bf16 = [W1^T ; W1.atts1 per head ; W1.attd1] ----------
__global__ void prepW1(const float* __restrict__ W1, const float* __restrict__ atts1,
                       const float* __restrict__ attd1, unsigned short* __restrict__ W1t) {
    int n = blockIdx.x;      // 0..143
    int k = threadIdx.x;     // 0..255
    float v;
    if (n < 128) {
        v = W1[(size_t)k * F1 + n];
    } else if (n < 136) {
        int h = n - 128; v = 0.f;
#pragma unroll
        for (int c = 0; c < 16; ++c) v += W1[(size_t)k * F1 + h * 16 + c] * atts1[h * 16 + c];
    } else {
        int h = n - 136; v = 0.f;
#pragma unroll
        for (int c = 0; c < 16; ++c) v += W1[(size_t)k * F1 + h * 16 + c] * attd1[h * 16 + c];
    }
    W1t[(size_t)n * NF + k] = f2bf(v);
}

// ---------- prep: W2e[48][128] bf16 = [W2^T ; W2.atts2 ; W2.attd2 ; pad] ----------
__global__ void prepW2(const float* __restrict__ W2, const float* __restrict__ atts2,
                       const float* __restrict__ attd2, unsigned short* __restrict__ W2e) {
    int n = blockIdx.x;      // 0..47
    int k = threadIdx.x;     // 0..127
    float v = 0.f;
    if (n < NC) {
        v = W2[(size_t)k * NC + n];
    } else if (n == NC) {
#pragma unroll
        for (int c = 0; c < NC; ++c) v += W2[(size_t)k * NC + c] * atts2[c];
    } else if (n == NC + 1) {
#pragma unroll
        for (int c = 0; c < NC; ++c) v += W2[(size_t)k * NC + c] * attd2[c];
    }
    W2e[(size_t)n * F1 + k] = f2bf(v);
}

// ---------- MFMA GEMM1: x[N,256] @ W1t144^T -> h1b[,128] bf16 + as1/ad1 ----------
__global__ __launch_bounds__(256) void gemm1m(const float* __restrict__ x,
                                              const unsigned short* __restrict__ W1t,
                                              unsigned short* __restrict__ h1b,
                                              float* __restrict__ as1,
                                              float* __restrict__ ad1) {
    __shared__ uint4 wlds[4608];         // 144 rows x 32 uint4 = 73728 B
    int t = threadIdx.x;
    int wave = t >> 6, lane = t & 63;
    int mbase = blockIdx.x * 64 + wave * 16;
    int row = mbase + (lane & 15);
    int rowc = min(row, NODES - 1);
    int kg = lane >> 4;              // 0..3
    const float4* xr = (const float4*)(x + (size_t)rowc * NF + kg * 8);

    // 1) issue the full K-strip loads (16 independent dwordx4 in flight)
    float4 xa[16];
#pragma unroll
    for (int ks = 0; ks < 8; ++ks) {
        xa[2 * ks]     = xr[ks * 8];
        xa[2 * ks + 1] = xr[ks * 8 + 1];
    }
    __builtin_amdgcn_sched_barrier(0);   // pin loads before the staging code

    // 2) stage W1t into LDS, swizzled: uint4 idx i -> i ^ (row&7), row = i>>5
#pragma unroll
    for (int it = 0; it < 18; ++it) {
        int i = it * 256 + t;
        wlds[i ^ ((i >> 5) & 7)] = ((const uint4*)W1t)[i];
    }
    __syncthreads();                     // also drains the x loads (all parallel)

    f32x4 acc[9];
#pragma unroll
    for (int f = 0; f < 9; ++f) acc[f] = (f32x4){0.f, 0.f, 0.f, 0.f};

    int r = lane & 15;
    int swz = r & 7;
    int rb = r * 32 + kg;                // uint4 index base within a frag row-block

#pragma unroll
    for (int ks = 0; ks < 8; ++ks) {
        union { uint4 u; bf16x8 v; } A;
        float4 a0 = xa[2 * ks], a1 = xa[2 * ks + 1];
        A.u.x = pk2(a0.x, a0.y); A.u.y = pk2(a0.z, a0.w);
        A.u.z = pk2(a1.x, a1.y); A.u.w = pk2(a1.z, a1.w);
#pragma unroll
        for (int f = 0; f < 9; ++f) {
            union { uint4 u; bf16x8 v; } B;
            B.u = wlds[(f * 512 + rb + ks * 4) ^ swz];
            acc[f] = __builtin_amdgcn_mfma_f32_16x16x32_bf16(A.v, B.v, acc[f], 0, 0, 0);
        }
    }

    // store: C/D layout col=lane&15, row=(lane>>4)*4+reg
    int col = lane & 15;
    int rbase = mbase + (lane >> 4) * 4;
#pragma unroll
    for (int f = 0; f < 8; ++f) {
#pragma unroll
        for (int i = 0; i < 4; ++i) {
            int rr = rbase + i;
            if (rr < NODES) h1b[(size_t)rr * F1 + f * 16 + col] = f2bf(acc[f][i]);
        }
    }
#pragma unroll
    for (int i = 0; i < 4; ++i) {
        int rr = rbase + i;
        if (rr < NODES) {
            float v = acc[8][i];
            if (col < 8) as1[(size_t)rr * NHEAD + col] = v;
            else ad1[(size_t)rr * NHEAD + (col - 8)] = v;
        }
    }
}

// ---------- MFMA GEMM2: out1b[N,128]bf16 @ W2e^T -> h2b bf16 + as2/ad2 ----------
__global__ __launch_bounds__(256) void gemm2m(const unsigned short* __restrict__ a,
                                              const unsigned short* __restrict__ W2e,
                                              unsigned short* __restrict__ h2b,
                                              float* __restrict__ as2,
                                              float* __restrict__ ad2) {
    __shared__ uint4 wlds[768];          // 48 rows x 16 uint4 = 12288 B
    int t = threadIdx.x;
    int wave = t >> 6, lane = t & 63;
    int mbase = blockIdx.x * 64 + wave * 16;
    int row = mbase + (lane & 15);
    int rowc = min(row, NODES - 1);
    int kg = lane >> 4;              // 0..3
    const uint4* ar = (const uint4*)(a + (size_t)rowc * F1 + kg * 8);

    // preload all 4 A fragments (K=128)
    uint4 xa[4];
#pragma unroll
    for (int ks = 0; ks < 4; ++ks) xa[ks] = ar[ks * 4];
    __builtin_amdgcn_sched_barrier(0);

    // stage W2e, swizzled: uint4 idx i -> i ^ ((i>>4)&7)
#pragma unroll
    for (int it = 0; it < 3; ++it) {
        int i = it * 256 + t;
        wlds[i ^ ((i >> 4) & 7)] = ((const uint4*)W2e)[i];
    }
    __syncthreads();

    f32x4 acc[3];
#pragma unroll
    for (int f = 0; f < 3; ++f) acc[f] = (f32x4){0.f, 0.f, 0.f, 0.f};

    int r = lane & 15;
    int swz = r & 7;
    int rb = r * 16 + kg;                // uint4 idx within frag row-block (16/row)

#pragma unroll
    for (int ks = 0; ks < 4; ++ks) {
        union { uint4 u; bf16x8 v; } A;
        A.u = xa[ks];
#pragma unroll
        for (int f = 0; f < 3; ++f) {
            union { uint4 u; bf16x8 v; } B;
            B.u = wlds[(f * 256 + rb + ks * 4) ^ swz];
            acc[f] = __builtin_amdgcn_mfma_f32_16x16x32_bf16(A.v, B.v, acc[f], 0, 0, 0);
        }
    }

    int col = lane & 15;
    int rbase = mbase + (lane >> 4) * 4;
#pragma unroll
    for (int f = 0; f < 2; ++f) {
#pragma unroll
        for (int i = 0; i < 4; ++i) {
            int rr = rbase + i;
            if (rr < NODES) h2b[(size_t)rr * NC + f * 16 + col] = f2bf(acc[f][i]);
        }
    }
#pragma unroll
    for (int i = 0; i < 4; ++i) {
        int rr = rbase + i;
        if (rr < NODES) {
            float v = acc[2][i];
            int c = 32 + col;
            if (c < NC) h2b[(size_t)rr * NC + c] = f2bf(v);
            else if (c == NC) as2[rr] = v;
            else if (c == NC + 1) ad2[rr] = v;
        }
    }
}

// no-max softmax step: 8 channels per lane
#define PROC8(AV, HV)                                    \
    {                                                    \
        float l = (AV) + adv;                            \
        l = l > 0.f ? l : 0.2f * l;                      \
        float p = __expf(l);                             \
        den += p;                                        \
        acc[0] += p * bflo(HV.x); acc[1] += p * bfhi(HV.x); \
        acc[2] += p * bflo(HV.y); acc[3] += p * bfhi(HV.y); \
        acc[4] += p * bflo(HV.z); acc[5] += p * bfhi(HV.z); \
        acc[6] += p * bflo(HV.w); acc[7] += p * bfhi(HV.w); \
    }

// ---------- L1 gather: 16-lane group per dst (4 dst/wave), depth-2, no shuffles ----------
__global__ __launch_bounds__(256) void msg1(const int* __restrict__ rowPtr,
                                            const int* __restrict__ csrSrc,
                                            const float* __restrict__ as1,
                                            const float* __restrict__ ad1,
                                            const unsigned short* __restrict__ h1b,
                                            const float* __restrict__ b1,
                                            unsigned short* __restrict__ out1b) {
    int t = threadIdx.x;
    int wid = t >> 6, lane = t & 63;
    int g = lane >> 4;                    // group 0..3 -> own dst
    int cl = lane & 15;                   // channel lane: ch 8*cl..8*cl+7
    int h = cl >> 1;                      // head
    int d = blockIdx.x * 16 + wid * 4 + g;   // grid exact: 3125*16 = 50000
    float adv = ad1[(size_t)d * NHEAD + h];
    int rs = rowPtr[d], re = rowPtr[d + 1];  // re > rs (self-loops)
    float den = 0.f;
    float acc[8];
#pragma unroll
    for (int k = 0; k < 8; ++k) acc[k] = 0.f;

    const char* as1c = (const char*)as1;
    const char* h1c = (const char*)h1b;
    unsigned hoff = (unsigned)(h << 2);
    unsigned coff = (unsigned)(cl << 4);

// internal index j_ avoids shadowing the caller's loop variable (R11 bug)
#define LD1(J, AV, HV)                                                \
    {                                                                 \
        int j_ = (J);                                                 \
        AV = -1e30f; HV = make_uint4(0u, 0u, 0u, 0u);                 \
        if (j_ < re) {                                                \
            unsigned ss = (unsigned)csrSrc[j_];                       \
            AV = *(const float*)(as1c + (ss << 5) + hoff);            \
            HV = *(const uint4*)(h1c + (ss << 8) + coff);             \
        }                                                             \
    }

    float av0, av1; uint4 hv0, hv1;
    LD1(rs, av0, hv0);
    LD1(rs + 1, av1, hv1);
    for (int j = rs; j < re; j += 2) {
        float ta, tb; uint4 ua, ub;
        LD1(j + 2, ta, ua);
        LD1(j + 3, tb, ub);
        PROC8(av0, hv0);
        PROC8(av1, hv1);
        av0 = ta; hv0 = ua; av1 = tb; hv1 = ub;
    }
#undef LD1

    float invd = 1.f / (den + 1e-16f);
    const float4* bp = (const float4*)(b1 + cl * 8);
    float4 ba = bp[0], bb = bp[1];
    float v[8];
    v[0] = acc[0] * invd + ba.x; v[1] = acc[1] * invd + ba.y;
    v[2] = acc[2] * invd + ba.z; v[3] = acc[3] * invd + ba.w;
    v[4] = acc[4] * invd + bb.x; v[5] = acc[5] * invd + bb.y;
    v[6] = acc[6] * invd + bb.z; v[7] = acc[7] * invd + bb.w;
#pragma unroll
    for (int k = 0; k < 8; ++k) {
        float ev = __expf(v[k]) - 1.f;          // ELU negative branch
        v[k] = v[k] > 0.f ? v[k] : ev;
    }
    uint4 o;
    o.x = pk2(v[0], v[1]); o.y = pk2(v[2], v[3]);
    o.z = pk2(v[4], v[5]); o.w = pk2(v[6], v[7]);
    *(uint4*)(out1b + (size_t)d * F1 + cl * 8) = o;
}

// ---------- L2 gather: 8-lane group per dst (8 dst/wave), depth-2 ----------
__global__ __launch_bounds__(256) void msg2(const int* __restrict__ rowPtr,
                                            const int* __restrict__ csrSrc,
                                            const float* __restrict__ as2,
                                            const float* __restrict__ ad2,
                                            const unsigned short* __restrict__ h2b,
                                            const float* __restrict__ b2,
                                            float* __restrict__ out) {
    int t = threadIdx.x;
    int wid = t >> 6, lane = t & 63;
    int g = lane >> 3;                    // group 0..7 -> own dst
    int cl = lane & 7;                    // channel lane; active cl<5 (8 ch each)
    int clc = cl < 5 ? cl : 4;
    bool act = cl < 5;
    int d0 = blockIdx.x * 32 + wid * 8 + g;
    int d = min(d0, NODES - 1);
    float adv = ad2[d];
    int rs = rowPtr[d], re = rowPtr[d + 1];
    if (!act) { rs = 0; re = 0; }         // inactive lanes: no loads, no loop
    float den = 0.f;
    float acc[8];
#pragma unroll
    for (int k = 0; k < 8; ++k) acc[k] = 0.f;

    const char* as2c = (const char*)as2;
    const char* h2c = (const char*)h2b;
    unsigned coff = (unsigned)(clc << 4);

#define LD2(J, AV, HV)                                                \
    {                                                                 \
        int j_ = (J);                                                 \
        AV = -1e30f; HV = make_uint4(0u, 0u, 0u, 0u);                 \
        if (j_ < re) {                                                \
            unsigned ss = (unsigned)csrSrc[j_];                       \
            AV = *(const float*)(as2c + (ss << 2));                   \
            HV = *(const uint4*)(h2c + ss * 80u + coff);              \
        }                                                             \
    }

    float av0, av1; uint4 hv0, hv1;
    LD2(rs, av0, hv0);
    LD2(rs + 1, av1, hv1);
    for (int j = rs; j < re; j += 2) {
        float ta, tb; uint4 ua, ub;
        LD2(j + 2, ta, ua);
        LD2(j + 3, tb, ub);
        PROC8(av0, hv0);
        PROC8(av1, hv1);
        av0 = ta; hv0 = ua; av1 = tb; hv1 = ub;
    }
#undef LD2

    float invd = 1.f / (den + 1e-16f);
    float v[8];
    float mk = -1e30f;
    if (act) {
        const float4* bp = (const float4*)(b2 + cl * 8);
        float4 ba = bp[0], bb = bp[1];
        v[0] = acc[0] * invd + ba.x; v[1] = acc[1] * invd + ba.y;
        v[2] = acc[2] * invd + ba.z; v[3] = acc[3] * invd + ba.w;
        v[4] = acc[4] * invd + bb.x; v[5] = acc[5] * invd + bb.y;
        v[6] = acc[6] * invd + bb.z; v[7] = acc[7] * invd + bb.w;
#pragma unroll
        for (int k = 0; k < 8; ++k) mk = fmaxf(mk, v[k]);
    }
    // reduce within the 8-lane group
    mk = fmaxf(mk, __shfl_xor(mk, 1, 64));
    mk = fmaxf(mk, __shfl_xor(mk, 2, 64));
    mk = fmaxf(mk, __shfl_xor(mk, 4, 64));
    float e = 0.f;
    if (act) {
#pragma unroll
        for (int k = 0; k < 8; ++k) e += __expf(v[k] - mk);
    }
    e += __shfl_xor(e, 1, 64);
    e += __shfl_xor(e, 2, 64);
    e += __shfl_xor(e, 4, 64);
    float lse = mk + logf(e);
    if (act && d0 < NODES) {
        float4 o0 = make_float4(v[0] - lse, v[1] - lse, v[2] - lse, v[3] - lse);
        float4 o1 = make_float4(v[4] - lse, v[5] - lse, v[6] - lse, v[7] - lse);
        float* po = out + (size_t)d0 * NC + cl * 8;
        *(float4*)po = o0;
        *(float4*)(po + 4) = o1;
    }
}

extern "C" void kernel_launch(void* const* d_in, const int* in_sizes, int n_in,
                              void* d_out, int out_size, void* d_ws, size_t ws_size,
                              hipStream_t stream) {
    const float* x       = (const float*)d_in[0];
    const unsigned* eidx = (const unsigned*)d_in[1];
    const float* W1      = (const float*)d_in[2];
    const float* atts1   = (const float*)d_in[3];
    const float* attd1   = (const float*)d_in[4];
    const float* b1      = (const float*)d_in[5];
    const float* W2      = (const float*)d_in[6];
    const float* atts2   = (const float*)d_in[7];
    const float* attd2   = (const float*)d_in[8];
    const float* b2      = (const float*)d_in[9];
    float* out = (float*)d_out;

    char* base = (char*)d_ws;
    size_t off = 0;
    auto takeB = [&](size_t bytes) {
        void* p = base + off;
        off = (off + bytes + 255) & ~(size_t)255;
        return p;
    };
    unsigned* flag = (unsigned*)takeB(256);
    int* cnt       = (int*)takeB((size_t)NODES * 4);
    int* fill      = (int*)takeB((size_t)NODES * 4);
    int* rowPtr    = (int*)takeB((size_t)(NODES + 64) * 4);
    int* blockSum  = (int*)takeB(SCAN_BLK * 4);
    int* blockOff  = (int*)takeB(SCAN_BLK * 4);
    int* csrSrc    = (int*)takeB((size_t)ETOT * 4 + 256);
    unsigned short* W1t  = (unsigned short*)takeB((size_t)144 * NF * 2);
    unsigned short* W2e  = (unsigned short*)takeB((size_t)48 * F1 * 2);
    unsigned short* h1b  = (unsigned short*)takeB((size_t)NODES * F1 * 2);
    float* as1     = (float*)takeB((size_t)NODES * NHEAD * 4);
    float* ad1     = (float*)takeB((size_t)NODES * NHEAD * 4);
    unsigned short* out1b = (unsigned short*)takeB((size_t)(NODES + 64) * F1 * 2);
    unsigned short* h2b  = (unsigned short*)takeB((size_t)NODES * NC * 2 + 256);
    float* as2     = (float*)takeB((size_t)NODES * 4);
    float* ad2     = (float*)takeB((size_t)NODES * 4);

    hipMemsetAsync(flag, 0, 4, stream);
    hipMemsetAsync(cnt, 0, (size_t)NODES * 4, stream);
    hipMemsetAsync(fill, 0, (size_t)NODES * 4, stream);

    detect_k<<<1, 256, 0, stream>>>(eidx, flag);

    // CSR build (by destination), reading edge_index directly
    hist_k<<<(ETOT + 255) / 256, 256, 0, stream>>>(eidx, flag, cnt);
    scanA<<<SCAN_BLK, 256, 0, stream>>>(cnt, rowPtr, blockSum);
    scanB<<<1, 256, 0, stream>>>(blockSum, blockOff);
    scanC<<<SCAN_BLK, 256, 0, stream>>>(rowPtr, blockOff);
    scatter_k<<<(ETOT + 1023) / 1024, 256, 0, stream>>>(eidx, flag, rowPtr, fill, csrSrc);

    // Layer 1 (MFMA GEMM with fused a1k columns)
    prepW1<<<144, 256, 0, stream>>>(W1, atts1, attd1, W1t);
    gemm1m<<<(NODES + 63) / 64, 256, 0, stream>>>(x, W1t, h1b, as1, ad1);
    msg1<<<NODES / 16, 256, 0, stream>>>(rowPtr, csrSrc, as1, ad1, h1b, b1, out1b);

    // Layer 2 (MFMA GEMM with fused a2k columns)
    prepW2<<<48, 128, 0, stream>>>(W2, atts2, attd2, W2e);
    gemm2m<<<(NODES + 63) / 64, 256, 0, stream>>>(out1b, W2e, h2b, as2, ad2);
    msg2<<<(NODES + 31) / 32, 256, 0, stream>>>(rowPtr, csrSrc, as2, ad2, h2b, b2, out);
}

// Round 15
// 198.804 us; speedup vs baseline: 1.2888x; 1.0217x over previous
//
#include <hip/hip_runtime.h>
#include <math.h>

#define NODES 50000
#define NEDGE 800000
#define ETOT  (NEDGE + NODES)   // edges + self loops = 850000
#define NF    256
#define F1    128               // HEADS*NHID
#define NHEAD 8
#define NHID  16
#define NC    40
#define SCAN_BLK 196            // ceil((NODES+1)/256)
// fused scatter+gemm1 grid: 3321 scatter blocks + 782 gemm blocks, 4:1 interleave
#define SG_BLOCKS 4103
#define SG_GEMMCUT 3910         // 782*5; gemm role at bid%5==4 below this

typedef __attribute__((ext_vector_type(8))) short bf16x8;
typedef __attribute__((ext_vector_type(4))) float f32x4;

__device__ __forceinline__ float bflo(unsigned u) { return __uint_as_float(u << 16); }
__device__ __forceinline__ float bfhi(unsigned u) { return __uint_as_float(u & 0xffff0000u); }
__device__ __forceinline__ unsigned short f2bf(float f) {
    unsigned u = __float_as_uint(f);
    unsigned r = u + 0x7fffu + ((u >> 16) & 1u);   // RNE
    return (unsigned short)(r >> 16);
}
__device__ __forceinline__ unsigned pk2(float a, float b) {
    return (unsigned)f2bf(a) | ((unsigned)f2bf(b) << 16);
}

// ---------- edge index dtype detect ----------
__global__ void detect_k(const unsigned* __restrict__ u, unsigned* __restrict__ flag) {
    int t = threadIdx.x;              // 256 threads
    if (u[2 * t + 1] != 0u) atomicOr(flag, 1u);   // nonzero hi-word pattern => int32 data
}

// ---------- CSR build (reads edge_index directly) ----------
__global__ void hist_k(const unsigned* __restrict__ u, const unsigned* __restrict__ flag,
                       int* __restrict__ cnt) {
    int e = blockIdx.x * 256 + threadIdx.x;
    if (e >= ETOT) return;
    int d;
    if (e < NEDGE) d = (*flag) ? (int)u[NEDGE + e] : (int)u[2 * NEDGE + 2 * e];
    else d = e - NEDGE;
    atomicAdd(&cnt[d], 1);
}

// ---------- multi-block exclusive scan of cnt[0..NODES] -> rowPtr ----------
__global__ __launch_bounds__(256) void scanA(const int* __restrict__ cnt,
                                             int* __restrict__ rowPtr,
                                             int* __restrict__ blockSum) {
    int idx = blockIdx.x * 256 + threadIdx.x;
    int lane = threadIdx.x & 63, w = threadIdx.x >> 6;
    int v = (idx < NODES) ? cnt[idx] : 0;
    int s = v;
#pragma unroll
    for (int off = 1; off < 64; off <<= 1) {
        int o = __shfl_up(s, off, 64);
        if (lane >= off) s += o;
    }
    __shared__ int wsum[4];
    if (lane == 63) wsum[w] = s;
    __syncthreads();
    int wadd = 0;
    for (int i = 0; i < w; ++i) wadd += wsum[i];
    int incl = s + wadd;
    if (idx <= NODES) rowPtr[idx] = incl - v;        // block-local exclusive
    if (threadIdx.x == 255) blockSum[blockIdx.x] = incl;
}

__global__ __launch_bounds__(256) void scanB(const int* __restrict__ blockSum,
                                             int* __restrict__ blockOff) {
    __shared__ int sh[256];
    int t = threadIdx.x;
    int v = (t < SCAN_BLK) ? blockSum[t] : 0;
    sh[t] = v;
    __syncthreads();
    for (int off = 1; off < 256; off <<= 1) {
        int o = (t >= off) ? sh[t - off] : 0;
        __syncthreads();
        sh[t] += o;
        __syncthreads();
    }
    if (t < SCAN_BLK) blockOff[t] = sh[t] - v;       // exclusive
}

__global__ __launch_bounds__(256) void scanC(int* __restrict__ rowPtr,
                                             const int* __restrict__ blockOff) {
    int idx = blockIdx.x * 256 + threadIdx.x;
    if (idx <= NODES) rowPtr[idx] += blockOff[blockIdx.x];
}

// ---------- prep (merged): W1t144[144][256] + W2e[48][128], both bf16 ----------
__global__ void prepW12(const float* __restrict__ W1, const float* __restrict__ atts1,
                        const float* __restrict__ attd1,
                        const float* __restrict__ W2, const float* __restrict__ atts2,
                        const float* __restrict__ attd2,
                        unsigned short* __restrict__ W1t, unsigned short* __restrict__ W2e) {
    int b = blockIdx.x;
    int k = threadIdx.x;
    if (b < 144) {
        int n = b;            // 0..143, k 0..255
        float v;
        if (n < 128) {
            v = W1[(size_t)k * F1 + n];
        } else if (n < 136) {
            int h = n - 128; v = 0.f;
#pragma unroll
            for (int c = 0; c < 16; ++c) v += W1[(size_t)k * F1 + h * 16 + c] * atts1[h * 16 + c];
        } else {
            int h = n - 136; v = 0.f;
#pragma unroll
            for (int c = 0; c < 16; ++c) v += W1[(size_t)k * F1 + h * 16 + c] * attd1[h * 16 + c];
        }
        W1t[(size_t)n * NF + k] = f2bf(v);
    } else {
        int n = b - 144;      // 0..47, k valid 0..127
        if (k >= F1) return;
        float v = 0.f;
        if (n < NC) {
            v = W2[(size_t)k * NC + n];
        } else if (n == NC) {
#pragma unroll
            for (int c = 0; c < NC; ++c) v += W2[(size_t)k * NC + c] * atts2[c];
        } else if (n == NC + 1) {
#pragma unroll
            for (int c = 0; c < NC; ++c) v += W2[(size_t)k * NC + c] * attd2[c];
        }
        W2e[(size_t)n * F1 + k] = f2bf(v);
    }
}

// ---------- FUSED: scatter (3321 blocks) + MFMA GEMM1 no-LDS (782 blocks) ----------
// Roles interleaved 4:1 so CUs co-schedule memory-bound scatter with the
// compute-bound GEMM. Gemm role reads B-fragments from L2 (no LDS so scatter
// blocks aren't LDS-capped).
__global__ __launch_bounds__(256) void scatter_gemm1(
        const unsigned* __restrict__ u, const unsigned* __restrict__ flag,
        const int* __restrict__ rowPtr, int* __restrict__ fill,
        int* __restrict__ csrSrc,
        const float* __restrict__ x, const unsigned short* __restrict__ W1t,
        unsigned short* __restrict__ h1b, float* __restrict__ as1,
        float* __restrict__ ad1) {
    int bid = blockIdx.x;
    int t = threadIdx.x;
    bool isGemm = (bid < SG_GEMMCUT) && ((bid % 5) == 4);
    if (!isGemm) {
        // ---- scatter role: 1 edge per thread ----
        int si = bid - min(bid, SG_GEMMCUT) / 5;   // gemm blocks before bid
        int e = si * 256 + t;
        if (e >= ETOT) return;
        int s, d;
        if (e < NEDGE) {
            if (*flag) { s = (int)u[e]; d = (int)u[NEDGE + e]; }
            else       { s = (int)u[2 * e]; d = (int)u[2 * NEDGE + 2 * e]; }
        } else s = d = e - NEDGE;
        int pos = rowPtr[d] + atomicAdd(&fill[d], 1);
        csrSrc[pos] = s;
        return;
    }
    // ---- gemm role ----
    int gi = bid / 5;
    int wave = t >> 6, lane = t & 63;
    int mbase = gi * 64 + wave * 16;
    int rowc = min(mbase + (lane & 15), NODES - 1);
    int kg = lane >> 4;              // 0..3
    const float4* xr = (const float4*)(x + (size_t)rowc * NF + kg * 8);

    // issue the full K-strip loads (16 independent dwordx4 in flight)
    float4 xa[16];
#pragma unroll
    for (int ks = 0; ks < 8; ++ks) {
        xa[2 * ks]     = xr[ks * 8];
        xa[2 * ks + 1] = xr[ks * 8 + 1];
    }
    __builtin_amdgcn_sched_barrier(0);   // pin x loads before the MFMA loop

    f32x4 acc[9];
#pragma unroll
    for (int f = 0; f < 9; ++f) acc[f] = (f32x4){0.f, 0.f, 0.f, 0.f};

    const unsigned short* wb = W1t + (size_t)(lane & 15) * NF + kg * 8;

#pragma unroll
    for (int ks = 0; ks < 8; ++ks) {
        union { uint4 u4; bf16x8 v; } A;
        float4 a0 = xa[2 * ks], a1 = xa[2 * ks + 1];
        A.u4.x = pk2(a0.x, a0.y); A.u4.y = pk2(a0.z, a0.w);
        A.u4.z = pk2(a1.x, a1.y); A.u4.w = pk2(a1.z, a1.w);
        const unsigned short* wk = wb + ks * 32;
#pragma unroll
        for (int f = 0; f < 9; ++f) {
            union { uint4 u4; bf16x8 v; } B;
            B.u4 = *(const uint4*)(wk + (size_t)f * 16 * NF);
            acc[f] = __builtin_amdgcn_mfma_f32_16x16x32_bf16(A.v, B.v, acc[f], 0, 0, 0);
        }
    }

    // store: C/D layout col=lane&15, row=(lane>>4)*4+reg
    int col = lane & 15;
    int rbase = mbase + (lane >> 4) * 4;
#pragma unroll
    for (int f = 0; f < 8; ++f) {
#pragma unroll
        for (int i = 0; i < 4; ++i) {
            int rr = rbase + i;
            if (rr < NODES) h1b[(size_t)rr * F1 + f * 16 + col] = f2bf(acc[f][i]);
        }
    }
#pragma unroll
    for (int i = 0; i < 4; ++i) {
        int rr = rbase + i;
        if (rr < NODES) {
            float v = acc[8][i];
            if (col < 8) as1[(size_t)rr * NHEAD + col] = v;
            else ad1[(size_t)rr * NHEAD + (col - 8)] = v;
        }
    }
}

// ---------- MFMA GEMM2: out1b[N,128]bf16 @ W2e^T -> h2b bf16 + as2/ad2 ----------
__global__ __launch_bounds__(256) void gemm2m(const unsigned short* __restrict__ a,
                                              const unsigned short* __restrict__ W2e,
                                              unsigned short* __restrict__ h2b,
                                              float* __restrict__ as2,
                                              float* __restrict__ ad2) {
    __shared__ uint4 wlds[768];          // 48 rows x 16 uint4 = 12288 B
    int t = threadIdx.x;
    int wave = t >> 6, lane = t & 63;
    int mbase = blockIdx.x * 64 + wave * 16;
    int rowc = min(mbase + (lane & 15), NODES - 1);
    int kg = lane >> 4;              // 0..3
    const uint4* ar = (const uint4*)(a + (size_t)rowc * F1 + kg * 8);

    // preload all 4 A fragments (K=128)
    uint4 xa[4];
#pragma unroll
    for (int ks = 0; ks < 4; ++ks) xa[ks] = ar[ks * 4];
    __builtin_amdgcn_sched_barrier(0);

    // stage W2e, swizzled: uint4 idx i -> i ^ ((i>>4)&7)
#pragma unroll
    for (int it = 0; it < 3; ++it) {
        int i = it * 256 + t;
        wlds[i ^ ((i >> 4) & 7)] = ((const uint4*)W2e)[i];
    }
    __syncthreads();

    f32x4 acc[3];
#pragma unroll
    for (int f = 0; f < 3; ++f) acc[f] = (f32x4){0.f, 0.f, 0.f, 0.f};

    int r = lane & 15;
    int swz = r & 7;
    int rb = r * 16 + kg;                // uint4 idx within frag row-block (16/row)

#pragma unroll
    for (int ks = 0; ks < 4; ++ks) {
        union { uint4 u; bf16x8 v; } A;
        A.u = xa[ks];
#pragma unroll
        for (int f = 0; f < 3; ++f) {
            union { uint4 u; bf16x8 v; } B;
            B.u = wlds[(f * 256 + rb + ks * 4) ^ swz];
            acc[f] = __builtin_amdgcn_mfma_f32_16x16x32_bf16(A.v, B.v, acc[f], 0, 0, 0);
        }
    }

    int col = lane & 15;
    int rbase = mbase + (lane >> 4) * 4;
#pragma unroll
    for (int f = 0; f < 2; ++f) {
#pragma unroll
        for (int i = 0; i < 4; ++i) {
            int rr = rbase + i;
            if (rr < NODES) h2b[(size_t)rr * NC + f * 16 + col] = f2bf(acc[f][i]);
        }
    }
#pragma unroll
    for (int i = 0; i < 4; ++i) {
        int rr = rbase + i;
        if (rr < NODES) {
            float v = acc[2][i];
            int c = 32 + col;
            if (c < NC) h2b[(size_t)rr * NC + c] = f2bf(v);
            else if (c == NC) as2[rr] = v;
            else if (c == NC + 1) ad2[rr] = v;
        }
    }
}

// no-max softmax step: 8 channels per lane
#define PROC8(AV, HV)                                    \
    {                                                    \
        float l = (AV) + adv;                            \
        l = l > 0.f ? l : 0.2f * l;                      \
        float p = __expf(l);                             \
        den += p;                                        \
        acc[0] += p * bflo(HV.x); acc[1] += p * bfhi(HV.x); \
        acc[2] += p * bflo(HV.y); acc[3] += p * bfhi(HV.y); \
        acc[4] += p * bflo(HV.z); acc[5] += p * bfhi(HV.z); \
        acc[6] += p * bflo(HV.w); acc[7] += p * bfhi(HV.w); \
    }

// ---------- L1 gather: 16-lane group per dst (4 dst/wave), depth-2, no shuffles ----------
__global__ __launch_bounds__(256) void msg1(const int* __restrict__ rowPtr,
                                            const int* __restrict__ csrSrc,
                                            const float* __restrict__ as1,
                                            const float* __restrict__ ad1,
                                            const unsigned short* __restrict__ h1b,
                                            const float* __restrict__ b1,
                                            unsigned short* __restrict__ out1b) {
    int t = threadIdx.x;
    int wid = t >> 6, lane = t & 63;
    int g = lane >> 4;                    // group 0..3 -> own dst
    int cl = lane & 15;                   // channel lane: ch 8*cl..8*cl+7
    int h = cl >> 1;                      // head
    int d = blockIdx.x * 16 + wid * 4 + g;   // grid exact: 3125*16 = 50000
    float adv = ad1[(size_t)d * NHEAD + h];
    int rs = rowPtr[d], re = rowPtr[d + 1];  // re > rs (self-loops)
    float den = 0.f;
    float acc[8];
#pragma unroll
    for (int k = 0; k < 8; ++k) acc[k] = 0.f;

    const char* as1c = (const char*)as1;
    const char* h1c = (const char*)h1b;
    unsigned hoff = (unsigned)(h << 2);
    unsigned coff = (unsigned)(cl << 4);

// internal index j_ avoids shadowing the caller's loop variable (R11 bug)
#define LD1(J, AV, HV)                                                \
    {                                                                 \
        int j_ = (J);                                                 \
        AV = -1e30f; HV = make_uint4(0u, 0u, 0u, 0u);                 \
        if (j_ < re) {                                                \
            unsigned ss = (unsigned)csrSrc[j_];                       \
            AV = *(const float*)(as1c + (ss << 5) + hoff);            \
            HV = *(const uint4*)(h1c + (ss << 8) + coff);             \
        }                                                             \
    }

    float av0, av1; uint4 hv0, hv1;
    LD1(rs, av0, hv0);
    LD1(rs + 1, av1, hv1);
    for (int j = rs; j < re; j += 2) {
        float ta, tb; uint4 ua, ub;
        LD1(j + 2, ta, ua);
        LD1(j + 3, tb, ub);
        PROC8(av0, hv0);
        PROC8(av1, hv1);
        av0 = ta; hv0 = ua; av1 = tb; hv1 = ub;
    }
#undef LD1

    float invd = 1.f / (den + 1e-16f);
    const float4* bp = (const float4*)(b1 + cl * 8);
    float4 ba = bp[0], bb = bp[1];
    float v[8];
    v[0] = acc[0] * invd + ba.x; v[1] = acc[1] * invd + ba.y;
    v[2] = acc[2] * invd + ba.z; v[3] = acc[3] * invd + ba.w;
    v[4] = acc[4] * invd + bb.x; v[5] = acc[5] * invd + bb.y;
    v[6] = acc[6] * invd + bb.z; v[7] = acc[7] * invd + bb.w;
#pragma unroll
    for (int k = 0; k < 8; ++k) {
        float ev = __expf(v[k]) - 1.f;          // ELU negative branch
        v[k] = v[k] > 0.f ? v[k] : ev;
    }
    uint4 o;
    o.x = pk2(v[0], v[1]); o.y = pk2(v[2], v[3]);
    o.z = pk2(v[4], v[5]); o.w = pk2(v[6], v[7]);
    *(uint4*)(out1b + (size_t)d * F1 + cl * 8) = o;
}

// ---------- L2 gather: 8-lane group per dst (8 dst/wave), depth-2 ----------
__global__ __launch_bounds__(256) void msg2(const int* __restrict__ rowPtr,
                                            const int* __restrict__ csrSrc,
                                            const float* __restrict__ as2,
                                            const float* __restrict__ ad2,
                                            const unsigned short* __restrict__ h2b,
                                            const float* __restrict__ b2,
                                            float* __restrict__ out) {
    int t = threadIdx.x;
    int wid = t >> 6, lane = t & 63;
    int g = lane >> 3;                    // group 0..7 -> own dst
    int cl = lane & 7;                    // channel lane; active cl<5 (8 ch each)
    int clc = cl < 5 ? cl : 4;
    bool act = cl < 5;
    int d0 = blockIdx.x * 32 + wid * 8 + g;
    int d = min(d0, NODES - 1);
    float adv = ad2[d];
    int rs = rowPtr[d], re = rowPtr[d + 1];
    if (!act) { rs = 0; re = 0; }         // inactive lanes: no loads, no loop
    float den = 0.f;
    float acc[8];
#pragma unroll
    for (int k = 0; k < 8; ++k) acc[k] = 0.f;

    const char* as2c = (const char*)as2;
    const char* h2c = (const char*)h2b;
    unsigned coff = (unsigned)(clc << 4);

#define LD2(J, AV, HV)                                                \
    {                                                                 \
        int j_ = (J);                                                 \
        AV = -1e30f; HV = make_uint4(0u, 0u, 0u, 0u);                 \
        if (j_ < re) {                                                \
            unsigned ss = (unsigned)csrSrc[j_];                       \
            AV = *(const float*)(as2c + (ss << 2));                   \
            HV = *(const uint4*)(h2c + ss * 80u + coff);              \
        }                                                             \
    }

    float av0, av1; uint4 hv0, hv1;
    LD2(rs, av0, hv0);
    LD2(rs + 1, av1, hv1);
    for (int j = rs; j < re; j += 2) {
        float ta, tb; uint4 ua, ub;
        LD2(j + 2, ta, ua);
        LD2(j + 3, tb, ub);
        PROC8(av0, hv0);
        PROC8(av1, hv1);
        av0 = ta; hv0 = ua; av1 = tb; hv1 = ub;
    }
#undef LD2

    float invd = 1.f / (den + 1e-16f);
    float v[8];
    float mk = -1e30f;
    if (act) {
        const float4* bp = (const float4*)(b2 + cl * 8);
        float4 ba = bp[0], bb = bp[1];
        v[0] = acc[0] * invd + ba.x; v[1] = acc[1] * invd + ba.y;
        v[2] = acc[2] * invd + ba.z; v[3] = acc[3] * invd + ba.w;
        v[4] = acc[4] * invd + bb.x; v[5] = acc[5] * invd + bb.y;
        v[6] = acc[6] * invd + bb.z; v[7] = acc[7] * invd + bb.w;
#pragma unroll
        for (int k = 0; k < 8; ++k) mk = fmaxf(mk, v[k]);
    }
    // reduce within the 8-lane group
    mk = fmaxf(mk, __shfl_xor(mk, 1, 64));
    mk = fmaxf(mk, __shfl_xor(mk, 2, 64));
    mk = fmaxf(mk, __shfl_xor(mk, 4, 64));
    float e = 0.f;
    if (act) {
#pragma unroll
        for (int k = 0; k < 8; ++k) e += __expf(v[k] - mk);
    }
    e += __shfl_xor(e, 1, 64);
    e += __shfl_xor(e, 2, 64);
    e += __shfl_xor(e, 4, 64);
    float lse = mk + logf(e);
    if (act && d0 < NODES) {
        float4 o0 = make_float4(v[0] - lse, v[1] - lse, v[2] - lse, v[3] - lse);
        float4 o1 = make_float4(v[4] - lse, v[5] - lse, v[6] - lse, v[7] - lse);
        float* po = out + (size_t)d0 * NC + cl * 8;
        *(float4*)po = o0;
        *(float4*)(po + 4) = o1;
    }
}

extern "C" void kernel_launch(void* const* d_in, const int* in_sizes, int n_in,
                              void* d_out, int out_size, void* d_ws, size_t ws_size,
                              hipStream_t stream) {
    const float* x       = (const float*)d_in[0];
    const unsigned* eidx = (const unsigned*)d_in[1];
    const float* W1      = (const float*)d_in[2];
    const float* atts1   = (const float*)d_in[3];
    const float* attd1   = (const float*)d_in[4];
    const float* b1      = (const float*)d_in[5];
    const float* W2      = (const float*)d_in[6];
    const float* atts2   = (const float*)d_in[7];
    const float* attd2   = (const float*)d_in[8];
    const float* b2      = (const float*)d_in[9];
    float* out = (float*)d_out;

    char* base = (char*)d_ws;
    size_t off = 0;
    auto takeB = [&](size_t bytes) {
        void* p = base + off;
        off = (off + bytes + 255) & ~(size_t)255;
        return p;
    };
    unsigned* flag = (unsigned*)takeB(256);
    int* cnt       = (int*)takeB((size_t)NODES * 4);
    int* fill      = (int*)takeB((size_t)NODES * 4);
    int* rowPtr    = (int*)takeB((size_t)(NODES + 64) * 4);
    int* blockSum  = (int*)takeB(SCAN_BLK * 4);
    int* blockOff  = (int*)takeB(SCAN_BLK * 4);
    int* csrSrc    = (int*)takeB((size_t)ETOT * 4 + 256);
    unsigned short* W1t  = (unsigned short*)takeB((size_t)144 * NF * 2);
    unsigned short* W2e  = (unsigned short*)takeB((size_t)48 * F1 * 2);
    unsigned short* h1b  = (unsigned short*)takeB((size_t)NODES * F1 * 2);
    float* as1     = (float*)takeB((size_t)NODES * NHEAD * 4);
    float* ad1     = (float*)takeB((size_t)NODES * NHEAD * 4);
    unsigned short* out1b = (unsigned short*)takeB((size_t)(NODES + 64) * F1 * 2);
    unsigned short* h2b  = (unsigned short*)takeB((size_t)NODES * NC * 2 + 256);
    float* as2     = (float*)takeB((size_t)NODES * 4);
    float* ad2     = (float*)takeB((size_t)NODES * 4);

    hipMemsetAsync(flag, 0, 4, stream);
    hipMemsetAsync(cnt, 0, (size_t)NODES * 4, stream);
    hipMemsetAsync(fill, 0, (size_t)NODES * 4, stream);

    detect_k<<<1, 256, 0, stream>>>(eidx, flag);

    // CSR histogram + scan
    hist_k<<<(ETOT + 255) / 256, 256, 0, stream>>>(eidx, flag, cnt);
    scanA<<<SCAN_BLK, 256, 0, stream>>>(cnt, rowPtr, blockSum);
    scanB<<<1, 256, 0, stream>>>(blockSum, blockOff);
    scanC<<<SCAN_BLK, 256, 0, stream>>>(rowPtr, blockOff);

    // weight prep (both layers, one dispatch)
    prepW12<<<192, 256, 0, stream>>>(W1, atts1, attd1, W2, atts2, attd2, W1t, W2e);

    // fused: CSR scatter + layer-1 MFMA GEMM (independent, co-scheduled)
    scatter_gemm1<<<SG_BLOCKS, 256, 0, stream>>>(eidx, flag, rowPtr, fill, csrSrc,
                                                 x, W1t, h1b, as1, ad1);

    // Layer-1 gather
    msg1<<<NODES / 16, 256, 0, stream>>>(rowPtr, csrSrc, as1, ad1, h1b, b1, out1b);

    // Layer 2
    gemm2m<<<(NODES + 63) / 64, 256, 0, stream>>>(out1b, W2e, h2b, as2, ad2);
    msg2<<<(NODES + 31) / 32, 256, 0, stream>>>(rowPtr, csrSrc, as2, ad2, h2b, b2, out);
}

// Round 16
// 177.249 us; speedup vs baseline: 1.4456x; 1.1216x over previous
//
#include <hip/hip_runtime.h>
#include <math.h>

#define NODES 50000
#define NEDGE 800000
#define ETOT  (NEDGE + NODES)   // edges + self loops = 850000
#define NF    256
#define F1    128               // HEADS*NHID
#define NHEAD 8
#define NHID  16
#define NC    40
#define SCAN_BLK 196            // ceil((NODES+1)/256)
// fused scatter+gemm1 grid: 3321 scatter blocks + 782 gemm blocks, 4:1 interleave
#define SG_BLOCKS 4103
#define SG_GEMMCUT 3910         // 782*5; gemm role at bid%5==4 below this

typedef __attribute__((ext_vector_type(8))) short bf16x8;
typedef __attribute__((ext_vector_type(4))) float f32x4;

__device__ __forceinline__ float bflo(unsigned u) { return __uint_as_float(u << 16); }
__device__ __forceinline__ float bfhi(unsigned u) { return __uint_as_float(u & 0xffff0000u); }
__device__ __forceinline__ unsigned short f2bf(float f) {
    unsigned u = __float_as_uint(f);
    unsigned r = u + 0x7fffu + ((u >> 16) & 1u);   // RNE
    return (unsigned short)(r >> 16);
}
__device__ __forceinline__ unsigned pk2(float a, float b) {
    return (unsigned)f2bf(a) | ((unsigned)f2bf(b) << 16);
}

// ---------- edge index dtype detect ----------
__global__ void detect_k(const unsigned* __restrict__ u, unsigned* __restrict__ flag) {
    int t = threadIdx.x;              // 256 threads
    if (u[2 * t + 1] != 0u) atomicOr(flag, 1u);   // nonzero hi-word pattern => int32 data
}

// ---------- CSR build (reads edge_index directly) ----------
__global__ void hist_k(const unsigned* __restrict__ u, const unsigned* __restrict__ flag,
                       int* __restrict__ cnt) {
    int e = blockIdx.x * 256 + threadIdx.x;
    if (e >= ETOT) return;
    int d;
    if (e < NEDGE) d = (*flag) ? (int)u[NEDGE + e] : (int)u[2 * NEDGE + 2 * e];
    else d = e - NEDGE;
    atomicAdd(&cnt[d], 1);
}

// ---------- multi-block exclusive scan of cnt[0..NODES] -> rowPtr ----------
__global__ __launch_bounds__(256) void scanA(const int* __restrict__ cnt,
                                             int* __restrict__ rowPtr,
                                             int* __restrict__ blockSum) {
    int idx = blockIdx.x * 256 + threadIdx.x;
    int lane = threadIdx.x & 63, w = threadIdx.x >> 6;
    int v = (idx < NODES) ? cnt[idx] : 0;
    int s = v;
#pragma unroll
    for (int off = 1; off < 64; off <<= 1) {
        int o = __shfl_up(s, off, 64);
        if (lane >= off) s += o;
    }
    __shared__ int wsum[4];
    if (lane == 63) wsum[w] = s;
    __syncthreads();
    int wadd = 0;
    for (int i = 0; i < w; ++i) wadd += wsum[i];
    int incl = s + wadd;
    if (idx <= NODES) rowPtr[idx] = incl - v;        // block-local exclusive
    if (threadIdx.x == 255) blockSum[blockIdx.x] = incl;
}

__global__ __launch_bounds__(256) void scanB(const int* __restrict__ blockSum,
                                             int* __restrict__ blockOff) {
    __shared__ int sh[256];
    int t = threadIdx.x;
    int v = (t < SCAN_BLK) ? blockSum[t] : 0;
    sh[t] = v;
    __syncthreads();
    for (int off = 1; off < 256; off <<= 1) {
        int o = (t >= off) ? sh[t - off] : 0;
        __syncthreads();
        sh[t] += o;
        __syncthreads();
    }
    if (t < SCAN_BLK) blockOff[t] = sh[t] - v;       // exclusive
}

__global__ __launch_bounds__(256) void scanC(int* __restrict__ rowPtr,
                                             const int* __restrict__ blockOff) {
    int idx = blockIdx.x * 256 + threadIdx.x;
    if (idx <= NODES) rowPtr[idx] += blockOff[blockIdx.x];
}

// ---------- prep (merged): W1t144[144][256] + W2e[48][128], both bf16 ----------
__global__ void prepW12(const float* __restrict__ W1, const float* __restrict__ atts1,
                        const float* __restrict__ attd1,
                        const float* __restrict__ W2, const float* __restrict__ atts2,
                        const float* __restrict__ attd2,
                        unsigned short* __restrict__ W1t, unsigned short* __restrict__ W2e) {
    int b = blockIdx.x;
    int k = threadIdx.x;
    if (b < 144) {
        int n = b;            // 0..143, k 0..255
        float v;
        if (n < 128) {
            v = W1[(size_t)k * F1 + n];
        } else if (n < 136) {
            int h = n - 128; v = 0.f;
#pragma unroll
            for (int c = 0; c < 16; ++c) v += W1[(size_t)k * F1 + h * 16 + c] * atts1[h * 16 + c];
        } else {
            int h = n - 136; v = 0.f;
#pragma unroll
            for (int c = 0; c < 16; ++c) v += W1[(size_t)k * F1 + h * 16 + c] * attd1[h * 16 + c];
        }
        W1t[(size_t)n * NF + k] = f2bf(v);
    } else {
        int n = b - 144;      // 0..47, k valid 0..127
        if (k >= F1) return;
        float v = 0.f;
        if (n < NC) {
            v = W2[(size_t)k * NC + n];
        } else if (n == NC) {
#pragma unroll
            for (int c = 0; c < NC; ++c) v += W2[(size_t)k * NC + c] * atts2[c];
        } else if (n == NC + 1) {
#pragma unroll
            for (int c = 0; c < NC; ++c) v += W2[(size_t)k * NC + c] * attd2[c];
        }
        W2e[(size_t)n * F1 + k] = f2bf(v);
    }
}

// ---------- FUSED: scatter (3321 blocks) + MFMA GEMM1 split-K LDS (782 blocks) ----------
// Roles interleaved 4:1. Gemm role stages W1t in TWO 36KB K-halves
// ([144][16] uint4, XOR-swizzled) so B-fragments are ds_read_b128 while
// keeping LDS small enough for 4 blocks/CU (scatter occupancy stays ~50%).
__global__ __launch_bounds__(256) void scatter_gemm1(
        const unsigned* __restrict__ u, const unsigned* __restrict__ flag,
        const int* __restrict__ rowPtr, int* __restrict__ fill,
        int* __restrict__ csrSrc,
        const float* __restrict__ x, const unsigned short* __restrict__ W1t,
        unsigned short* __restrict__ h1b, float* __restrict__ as1,
        float* __restrict__ ad1) {
    __shared__ uint4 wlds[2304];         // 144 rows x 16 uint4 = 36864 B
    int bid = blockIdx.x;
    int t = threadIdx.x;
    bool isGemm = (bid < SG_GEMMCUT) && ((bid % 5) == 4);
    if (!isGemm) {
        // ---- scatter role: 1 edge per thread (block-uniform branch; no syncthreads) ----
        int si = bid - min(bid, SG_GEMMCUT) / 5;   // gemm blocks before bid
        int e = si * 256 + t;
        if (e >= ETOT) return;
        int s, d;
        if (e < NEDGE) {
            if (*flag) { s = (int)u[e]; d = (int)u[NEDGE + e]; }
            else       { s = (int)u[2 * e]; d = (int)u[2 * NEDGE + 2 * e]; }
        } else s = d = e - NEDGE;
        int pos = rowPtr[d] + atomicAdd(&fill[d], 1);
        csrSrc[pos] = s;
        return;
    }
    // ---- gemm role ----
    int gi = bid / 5;
    int wave = t >> 6, lane = t & 63;
    int mbase = gi * 64 + wave * 16;
    int rowc = min(mbase + (lane & 15), NODES - 1);
    int kg = lane >> 4;              // 0..3
    const float4* xr = (const float4*)(x + (size_t)rowc * NF + kg * 8);

    // issue the full K-strip loads (16 independent dwordx4 in flight)
    float4 xa[16];
#pragma unroll
    for (int ks = 0; ks < 8; ++ks) {
        xa[2 * ks]     = xr[ks * 8];
        xa[2 * ks + 1] = xr[ks * 8 + 1];
    }
    __builtin_amdgcn_sched_barrier(0);   // pin x loads before staging

    f32x4 acc[9];
#pragma unroll
    for (int f = 0; f < 9; ++f) acc[f] = (f32x4){0.f, 0.f, 0.f, 0.f};

    int r = lane & 15;
    int swz = r & 7;
    int rb = r * 16 + kg;                // uint4 idx base in [row][16] half-layout

    // two K-halves: stage 36KB, run 4 MFMA steps, repeat
#pragma unroll
    for (int half = 0; half < 2; ++half) {
        if (half) __syncthreads();       // all reads of previous half done
#pragma unroll
        for (int it = 0; it < 9; ++it) {
            int i = it * 256 + t;        // 0..2303
            wlds[i ^ ((i >> 4) & 7)] = ((const uint4*)W1t)[(i >> 4) * 32 + half * 16 + (i & 15)];
        }
        __syncthreads();
#pragma unroll
        for (int ks = 0; ks < 4; ++ks) {
            union { uint4 u4; bf16x8 v; } A;
            float4 a0 = xa[2 * (half * 4 + ks)], a1 = xa[2 * (half * 4 + ks) + 1];
            A.u4.x = pk2(a0.x, a0.y); A.u4.y = pk2(a0.z, a0.w);
            A.u4.z = pk2(a1.x, a1.y); A.u4.w = pk2(a1.z, a1.w);
#pragma unroll
            for (int f = 0; f < 9; ++f) {
                union { uint4 u4; bf16x8 v; } B;
                B.u4 = wlds[(f * 256 + rb + ks * 4) ^ swz];
                acc[f] = __builtin_amdgcn_mfma_f32_16x16x32_bf16(A.v, B.v, acc[f], 0, 0, 0);
            }
        }
    }

    // store: C/D layout col=lane&15, row=(lane>>4)*4+reg
    int col = lane & 15;
    int rbase = mbase + (lane >> 4) * 4;
#pragma unroll
    for (int f = 0; f < 8; ++f) {
#pragma unroll
        for (int i = 0; i < 4; ++i) {
            int rr = rbase + i;
            if (rr < NODES) h1b[(size_t)rr * F1 + f * 16 + col] = f2bf(acc[f][i]);
        }
    }
#pragma unroll
    for (int i = 0; i < 4; ++i) {
        int rr = rbase + i;
        if (rr < NODES) {
            float v = acc[8][i];
            if (col < 8) as1[(size_t)rr * NHEAD + col] = v;
            else ad1[(size_t)rr * NHEAD + (col - 8)] = v;
        }
    }
}

// ---------- MFMA GEMM2: out1b[N,128]bf16 @ W2e^T -> h2b bf16 + as2/ad2 ----------
__global__ __launch_bounds__(256) void gemm2m(const unsigned short* __restrict__ a,
                                              const unsigned short* __restrict__ W2e,
                                              unsigned short* __restrict__ h2b,
                                              float* __restrict__ as2,
                                              float* __restrict__ ad2) {
    __shared__ uint4 wlds[768];          // 48 rows x 16 uint4 = 12288 B
    int t = threadIdx.x;
    int wave = t >> 6, lane = t & 63;
    int mbase = blockIdx.x * 64 + wave * 16;
    int rowc = min(mbase + (lane & 15), NODES - 1);
    int kg = lane >> 4;              // 0..3
    const uint4* ar = (const uint4*)(a + (size_t)rowc * F1 + kg * 8);

    // preload all 4 A fragments (K=128)
    uint4 xa[4];
#pragma unroll
    for (int ks = 0; ks < 4; ++ks) xa[ks] = ar[ks * 4];
    __builtin_amdgcn_sched_barrier(0);

    // stage W2e, swizzled: uint4 idx i -> i ^ ((i>>4)&7)
#pragma unroll
    for (int it = 0; it < 3; ++it) {
        int i = it * 256 + t;
        wlds[i ^ ((i >> 4) & 7)] = ((const uint4*)W2e)[i];
    }
    __syncthreads();

    f32x4 acc[3];
#pragma unroll
    for (int f = 0; f < 3; ++f) acc[f] = (f32x4){0.f, 0.f, 0.f, 0.f};

    int r = lane & 15;
    int swz = r & 7;
    int rb = r * 16 + kg;                // uint4 idx within frag row-block (16/row)

#pragma unroll
    for (int ks = 0; ks < 4; ++ks) {
        union { uint4 u; bf16x8 v; } A;
        A.u = xa[ks];
#pragma unroll
        for (int f = 0; f < 3; ++f) {
            union { uint4 u; bf16x8 v; } B;
            B.u = wlds[(f * 256 + rb + ks * 4) ^ swz];
            acc[f] = __builtin_amdgcn_mfma_f32_16x16x32_bf16(A.v, B.v, acc[f], 0, 0, 0);
        }
    }

    int col = lane & 15;
    int rbase = mbase + (lane >> 4) * 4;
#pragma unroll
    for (int f = 0; f < 2; ++f) {
#pragma unroll
        for (int i = 0; i < 4; ++i) {
            int rr = rbase + i;
            if (rr < NODES) h2b[(size_t)rr * NC + f * 16 + col] = f2bf(acc[f][i]);
        }
    }
#pragma unroll
    for (int i = 0; i < 4; ++i) {
        int rr = rbase + i;
        if (rr < NODES) {
            float v = acc[2][i];
            int c = 32 + col;
            if (c < NC) h2b[(size_t)rr * NC + c] = f2bf(v);
            else if (c == NC) as2[rr] = v;
            else if (c == NC + 1) ad2[rr] = v;
        }
    }
}

// no-max softmax step: 8 channels per lane
#define PROC8(AV, HV)                                    \
    {                                                    \
        float l = (AV) + adv;                            \
        l = l > 0.f ? l : 0.2f * l;                      \
        float p = __expf(l);                             \
        den += p;                                        \
        acc[0] += p * bflo(HV.x); acc[1] += p * bfhi(HV.x); \
        acc[2] += p * bflo(HV.y); acc[3] += p * bfhi(HV.y); \
        acc[4] += p * bflo(HV.z); acc[5] += p * bfhi(HV.z); \
        acc[6] += p * bflo(HV.w); acc[7] += p * bfhi(HV.w); \
    }

// ---------- L1 gather: 16-lane group per dst (4 dst/wave), depth-2, no shuffles ----------
__global__ __launch_bounds__(256) void msg1(const int* __restrict__ rowPtr,
                                            const int* __restrict__ csrSrc,
                                            const float* __restrict__ as1,
                                            const float* __restrict__ ad1,
                                            const unsigned short* __restrict__ h1b,
                                            const float* __restrict__ b1,
                                            unsigned short* __restrict__ out1b) {
    int t = threadIdx.x;
    int wid = t >> 6, lane = t & 63;
    int g = lane >> 4;                    // group 0..3 -> own dst
    int cl = lane & 15;                   // channel lane: ch 8*cl..8*cl+7
    int h = cl >> 1;                      // head
    int d = blockIdx.x * 16 + wid * 4 + g;   // grid exact: 3125*16 = 50000
    float adv = ad1[(size_t)d * NHEAD + h];
    int rs = rowPtr[d], re = rowPtr[d + 1];  // re > rs (self-loops)
    float den = 0.f;
    float acc[8];
#pragma unroll
    for (int k = 0; k < 8; ++k) acc[k] = 0.f;

    const char* as1c = (const char*)as1;
    const char* h1c = (const char*)h1b;
    unsigned hoff = (unsigned)(h << 2);
    unsigned coff = (unsigned)(cl << 4);

// internal index j_ avoids shadowing the caller's loop variable (R11 bug)
#define LD1(J, AV, HV)                                                \
    {                                                                 \
        int j_ = (J);                                                 \
        AV = -1e30f; HV = make_uint4(0u, 0u, 0u, 0u);                 \
        if (j_ < re) {                                                \
            unsigned ss = (unsigned)csrSrc[j_];                       \
            AV = *(const float*)(as1c + (ss << 5) + hoff);            \
            HV = *(const uint4*)(h1c + (ss << 8) + coff);             \
        }                                                             \
    }

    float av0, av1; uint4 hv0, hv1;
    LD1(rs, av0, hv0);
    LD1(rs + 1, av1, hv1);
    for (int j = rs; j < re; j += 2) {
        float ta, tb; uint4 ua, ub;
        LD1(j + 2, ta, ua);
        LD1(j + 3, tb, ub);
        PROC8(av0, hv0);
        PROC8(av1, hv1);
        av0 = ta; hv0 = ua; av1 = tb; hv1 = ub;
    }
#undef LD1

    float invd = 1.f / (den + 1e-16f);
    const float4* bp = (const float4*)(b1 + cl * 8);
    float4 ba = bp[0], bb = bp[1];
    float v[8];
    v[0] = acc[0] * invd + ba.x; v[1] = acc[1] * invd + ba.y;
    v[2] = acc[2] * invd + ba.z; v[3] = acc[3] * invd + ba.w;
    v[4] = acc[4] * invd + bb.x; v[5] = acc[5] * invd + bb.y;
    v[6] = acc[6] * invd + bb.z; v[7] = acc[7] * invd + bb.w;
#pragma unroll
    for (int k = 0; k < 8; ++k) {
        float ev = __expf(v[k]) - 1.f;          // ELU negative branch
        v[k] = v[k] > 0.f ? v[k] : ev;
    }
    uint4 o;
    o.x = pk2(v[0], v[1]); o.y = pk2(v[2], v[3]);
    o.z = pk2(v[4], v[5]); o.w = pk2(v[6], v[7]);
    *(uint4*)(out1b + (size_t)d * F1 + cl * 8) = o;
}

// ---------- L2 gather: 8-lane group per dst (8 dst/wave), depth-2 ----------
__global__ __launch_bounds__(256) void msg2(const int* __restrict__ rowPtr,
                                            const int* __restrict__ csrSrc,
                                            const float* __restrict__ as2,
                                            const float* __restrict__ ad2,
                                            const unsigned short* __restrict__ h2b,
                                            const float* __restrict__ b2,
                                            float* __restrict__ out) {
    int t = threadIdx.x;
    int wid = t >> 6, lane = t & 63;
    int g = lane >> 3;                    // group 0..7 -> own dst
    int cl = lane & 7;                    // channel lane; active cl<5 (8 ch each)
    int clc = cl < 5 ? cl : 4;
    bool act = cl < 5;
    int d0 = blockIdx.x * 32 + wid * 8 + g;
    int d = min(d0, NODES - 1);
    float adv = ad2[d];
    int rs = rowPtr[d], re = rowPtr[d + 1];
    if (!act) { rs = 0; re = 0; }         // inactive lanes: no loads, no loop
    float den = 0.f;
    float acc[8];
#pragma unroll
    for (int k = 0; k < 8; ++k) acc[k] = 0.f;

    const char* as2c = (const char*)as2;
    const char* h2c = (const char*)h2b;
    unsigned coff = (unsigned)(clc << 4);

#define LD2(J, AV, HV)                                                \
    {                                                                 \
        int j_ = (J);                                                 \
        AV = -1e30f; HV = make_uint4(0u, 0u, 0u, 0u);                 \
        if (j_ < re) {                                                \
            unsigned ss = (unsigned)csrSrc[j_];                       \
            AV = *(const float*)(as2c + (ss << 2));                   \
            HV = *(const uint4*)(h2c + ss * 80u + coff);              \
        }                                                             \
    }

    float av0, av1; uint4 hv0, hv1;
    LD2(rs, av0, hv0);
    LD2(rs + 1, av1, hv1);
    for (int j = rs; j < re; j += 2) {
        float ta, tb; uint4 ua, ub;
        LD2(j + 2, ta, ua);
        LD2(j + 3, tb, ub);
        PROC8(av0, hv0);
        PROC8(av1, hv1);
        av0 = ta; hv0 = ua; av1 = tb; hv1 = ub;
    }
#undef LD2

    float invd = 1.f / (den + 1e-16f);
    float v[8];
    float mk = -1e30f;
    if (act) {
        const float4* bp = (const float4*)(b2 + cl * 8);
        float4 ba = bp[0], bb = bp[1];
        v[0] = acc[0] * invd + ba.x; v[1] = acc[1] * invd + ba.y;
        v[2] = acc[2] * invd + ba.z; v[3] = acc[3] * invd + ba.w;
        v[4] = acc[4] * invd + bb.x; v[5] = acc[5] * invd + bb.y;
        v[6] = acc[6] * invd + bb.z; v[7] = acc[7] * invd + bb.w;
#pragma unroll
        for (int k = 0; k < 8; ++k) mk = fmaxf(mk, v[k]);
    }
    // reduce within the 8-lane group
    mk = fmaxf(mk, __shfl_xor(mk, 1, 64));
    mk = fmaxf(mk, __shfl_xor(mk, 2, 64));
    mk = fmaxf(mk, __shfl_xor(mk, 4, 64));
    float e = 0.f;
    if (act) {
#pragma unroll
        for (int k = 0; k < 8; ++k) e += __expf(v[k] - mk);
    }
    e += __shfl_xor(e, 1, 64);
    e += __shfl_xor(e, 2, 64);
    e += __shfl_xor(e, 4, 64);
    float lse = mk + logf(e);
    if (act && d0 < NODES) {
        float4 o0 = make_float4(v[0] - lse, v[1] - lse, v[2] - lse, v[3] - lse);
        float4 o1 = make_float4(v[4] - lse, v[5] - lse, v[6] - lse, v[7] - lse);
        float* po = out + (size_t)d0 * NC + cl * 8;
        *(float4*)po = o0;
        *(float4*)(po + 4) = o1;
    }
}

extern "C" void kernel_launch(void* const* d_in, const int* in_sizes, int n_in,
                              void* d_out, int out_size, void* d_ws, size_t ws_size,
                              hipStream_t stream) {
    const float* x       = (const float*)d_in[0];
    const unsigned* eidx = (const unsigned*)d_in[1];
    const float* W1      = (const float*)d_in[2];
    const float* atts1   = (const float*)d_in[3];
    const float* attd1   = (const float*)d_in[4];
    const float* b1      = (const float*)d_in[5];
    const float* W2      = (const float*)d_in[6];
    const float* atts2   = (const float*)d_in[7];
    const float* attd2   = (const float*)d_in[8];
    const float* b2      = (const float*)d_in[9];
    float* out = (float*)d_out;

    char* base = (char*)d_ws;
    size_t off = 0;
    auto takeB = [&](size_t bytes) {
        void* p = base + off;
        off = (off + bytes + 255) & ~(size_t)255;
        return p;
    };
    unsigned* flag = (unsigned*)takeB(256);
    int* cnt       = (int*)takeB((size_t)NODES * 4);
    int* fill      = (int*)takeB((size_t)NODES * 4);
    int* rowPtr    = (int*)takeB((size_t)(NODES + 64) * 4);
    int* blockSum  = (int*)takeB(SCAN_BLK * 4);
    int* blockOff  = (int*)takeB(SCAN_BLK * 4);
    int* csrSrc    = (int*)takeB((size_t)ETOT * 4 + 256);
    unsigned short* W1t  = (unsigned short*)takeB((size_t)144 * NF * 2);
    unsigned short* W2e  = (unsigned short*)takeB((size_t)48 * F1 * 2);
    unsigned short* h1b  = (unsigned short*)takeB((size_t)NODES * F1 * 2);
    float* as1     = (float*)takeB((size_t)NODES * NHEAD * 4);
    float* ad1     = (float*)takeB((size_t)NODES * NHEAD * 4);
    unsigned short* out1b = (unsigned short*)takeB((size_t)(NODES + 64) * F1 * 2);
    unsigned short* h2b  = (unsigned short*)takeB((size_t)NODES * NC * 2 + 256);
    float* as2     = (float*)takeB((size_t)NODES * 4);
    float* ad2     = (float*)takeB((size_t)NODES * 4);

    hipMemsetAsync(flag, 0, 4, stream);
    hipMemsetAsync(cnt, 0, (size_t)NODES * 4, stream);
    hipMemsetAsync(fill, 0, (size_t)NODES * 4, stream);

    detect_k<<<1, 256, 0, stream>>>(eidx, flag);

    // CSR histogram + scan
    hist_k<<<(ETOT + 255) / 256, 256, 0, stream>>>(eidx, flag, cnt);
    scanA<<<SCAN_BLK, 256, 0, stream>>>(cnt, rowPtr, blockSum);
    scanB<<<1, 256, 0, stream>>>(blockSum, blockOff);
    scanC<<<SCAN_BLK, 256, 0, stream>>>(rowPtr, blockOff);

    // weight prep (both layers, one dispatch)
    prepW12<<<192, 256, 0, stream>>>(W1, atts1, attd1, W2, atts2, attd2, W1t, W2e);

    // fused: CSR scatter + layer-1 MFMA GEMM (independent, co-scheduled)
    scatter_gemm1<<<SG_BLOCKS, 256, 0, stream>>>(eidx, flag, rowPtr, fill, csrSrc,
                                                 x, W1t, h1b, as1, ad1);

    // Layer-1 gather
    msg1<<<NODES / 16, 256, 0, stream>>>(rowPtr, csrSrc, as1, ad1, h1b, b1, out1b);

    // Layer 2
    gemm2m<<<(NODES + 63) / 64, 256, 0, stream>>>(out1b, W2e, h2b, as2, ad2);
    msg2<<<(NODES + 31) / 32, 256, 0, stream>>>(rowPtr, csrSrc, as2, ad2, h2b, b2, out);
}

// Round 17
// 167.845 us; speedup vs baseline: 1.5265x; 1.0560x over previous
//
#include <hip/hip_runtime.h>
#include <math.h>

#define NODES 50000
#define NEDGE 800000
#define ETOT  (NEDGE + NODES)   // edges + self loops = 850000
#define NF    256
#define F1    128               // HEADS*NHID
#define NHEAD 8
#define NHID  16
#define NC    40
#define SCAN_BLK 196            // ceil((NODES+1)/256)
// fused scatter+gemm1 grid: 3321 scatter blocks + 782 gemm blocks, 4:1 interleave
#define SG_BLOCKS 4103
#define SG_GEMMCUT 3910         // 782*5; gemm role at bid%5==4 below this

typedef __attribute__((ext_vector_type(8))) short bf16x8;
typedef __attribute__((ext_vector_type(4))) float f32x4;
typedef __attribute__((ext_vector_type(2))) float f32x2;

__device__ __forceinline__ float bflo(unsigned u) { return __uint_as_float(u << 16); }
__device__ __forceinline__ float bfhi(unsigned u) { return __uint_as_float(u & 0xffff0000u); }
__device__ __forceinline__ unsigned short f2bf(float f) {
    unsigned u = __float_as_uint(f);
    unsigned r = u + 0x7fffu + ((u >> 16) & 1u);   // RNE
    return (unsigned short)(r >> 16);
}
__device__ __forceinline__ unsigned pk2(float a, float b) {
    return (unsigned)f2bf(a) | ((unsigned)f2bf(b) << 16);
}

// ---------- edge index dtype detect ----------
__global__ void detect_k(const unsigned* __restrict__ u, unsigned* __restrict__ flag) {
    int t = threadIdx.x;              // 256 threads
    if (u[2 * t + 1] != 0u) atomicOr(flag, 1u);   // nonzero hi-word pattern => int32 data
}

// ---------- CSR build (reads edge_index directly) ----------
__global__ void hist_k(const unsigned* __restrict__ u, const unsigned* __restrict__ flag,
                       int* __restrict__ cnt) {
    int e = blockIdx.x * 256 + threadIdx.x;
    if (e >= ETOT) return;
    int d;
    if (e < NEDGE) d = (*flag) ? (int)u[NEDGE + e] : (int)u[2 * NEDGE + 2 * e];
    else d = e - NEDGE;
    atomicAdd(&cnt[d], 1);
}

// ---------- multi-block exclusive scan of cnt[0..NODES] -> rowPtr ----------
__global__ __launch_bounds__(256) void scanA(const int* __restrict__ cnt,
                                             int* __restrict__ rowPtr,
                                             int* __restrict__ blockSum) {
    int idx = blockIdx.x * 256 + threadIdx.x;
    int lane = threadIdx.x & 63, w = threadIdx.x >> 6;
    int v = (idx < NODES) ? cnt[idx] : 0;
    int s = v;
#pragma unroll
    for (int off = 1; off < 64; off <<= 1) {
        int o = __shfl_up(s, off, 64);
        if (lane >= off) s += o;
    }
    __shared__ int wsum[4];
    if (lane == 63) wsum[w] = s;
    __syncthreads();
    int wadd = 0;
    for (int i = 0; i < w; ++i) wadd += wsum[i];
    int incl = s + wadd;
    if (idx <= NODES) rowPtr[idx] = incl - v;        // block-local exclusive
    if (threadIdx.x == 255) blockSum[blockIdx.x] = incl;
}

__global__ __launch_bounds__(256) void scanB(const int* __restrict__ blockSum,
                                             int* __restrict__ blockOff) {
    __shared__ int sh[256];
    int t = threadIdx.x;
    int v = (t < SCAN_BLK) ? blockSum[t] : 0;
    sh[t] = v;
    __syncthreads();
    for (int off = 1; off < 256; off <<= 1) {
        int o = (t >= off) ? sh[t - off] : 0;
        __syncthreads();
        sh[t] += o;
        __syncthreads();
    }
    if (t < SCAN_BLK) blockOff[t] = sh[t] - v;       // exclusive
}

__global__ __launch_bounds__(256) void scanC(int* __restrict__ rowPtr,
                                             const int* __restrict__ blockOff) {
    int idx = blockIdx.x * 256 + threadIdx.x;
    if (idx <= NODES) rowPtr[idx] += blockOff[blockIdx.x];
}

// ---------- prep (merged): W1t144[144][256] + W2e[48][128], both bf16 ----------
__global__ void prepW12(const float* __restrict__ W1, const float* __restrict__ atts1,
                        const float* __restrict__ attd1,
                        const float* __restrict__ W2, const float* __restrict__ atts2,
                        const float* __restrict__ attd2,
                        unsigned short* __restrict__ W1t, unsigned short* __restrict__ W2e) {
    int b = blockIdx.x;
    int k = threadIdx.x;
    if (b < 144) {
        int n = b;            // 0..143, k 0..255
        float v;
        if (n < 128) {
            v = W1[(size_t)k * F1 + n];
        } else if (n < 136) {
            int h = n - 128; v = 0.f;
#pragma unroll
            for (int c = 0; c < 16; ++c) v += W1[(size_t)k * F1 + h * 16 + c] * atts1[h * 16 + c];
        } else {
            int h = n - 136; v = 0.f;
#pragma unroll
            for (int c = 0; c < 16; ++c) v += W1[(size_t)k * F1 + h * 16 + c] * attd1[h * 16 + c];
        }
        W1t[(size_t)n * NF + k] = f2bf(v);
    } else {
        int n = b - 144;      // 0..47, k valid 0..127
        if (k >= F1) return;
        float v = 0.f;
        if (n < NC) {
            v = W2[(size_t)k * NC + n];
        } else if (n == NC) {
#pragma unroll
            for (int c = 0; c < NC; ++c) v += W2[(size_t)k * NC + c] * atts2[c];
        } else if (n == NC + 1) {
#pragma unroll
            for (int c = 0; c < NC; ++c) v += W2[(size_t)k * NC + c] * attd2[c];
        }
        W2e[(size_t)n * F1 + k] = f2bf(v);
    }
}

// ---------- FUSED: scatter (ushort csrSrc) + MFMA GEMM1 split-K LDS (fp8 h1) ----------
__global__ __launch_bounds__(256) void scatter_gemm1(
        const unsigned* __restrict__ u, const unsigned* __restrict__ flag,
        const int* __restrict__ rowPtr, int* __restrict__ fill,
        unsigned short* __restrict__ csr16,
        const float* __restrict__ x, const unsigned short* __restrict__ W1t,
        unsigned char* __restrict__ h1f8, float* __restrict__ as1,
        float* __restrict__ ad1) {
    __shared__ uint4 wlds[2304];         // 144 rows x 16 uint4 = 36864 B
    int bid = blockIdx.x;
    int t = threadIdx.x;
    bool isGemm = (bid < SG_GEMMCUT) && ((bid % 5) == 4);
    if (!isGemm) {
        // ---- scatter role: 1 edge per thread, 2B stores ----
        int si = bid - min(bid, SG_GEMMCUT) / 5;   // gemm blocks before bid
        int e = si * 256 + t;
        if (e >= ETOT) return;
        int s, d;
        if (e < NEDGE) {
            if (*flag) { s = (int)u[e]; d = (int)u[NEDGE + e]; }
            else       { s = (int)u[2 * e]; d = (int)u[2 * NEDGE + 2 * e]; }
        } else s = d = e - NEDGE;
        int pos = rowPtr[d] + atomicAdd(&fill[d], 1);
        csr16[pos] = (unsigned short)s;
        return;
    }
    // ---- gemm role ----
    int gi = bid / 5;
    int wave = t >> 6, lane = t & 63;
    int mbase = gi * 64 + wave * 16;
    int rowc = min(mbase + (lane & 15), NODES - 1);
    int kg = lane >> 4;              // 0..3
    const float4* xr = (const float4*)(x + (size_t)rowc * NF + kg * 8);

    // issue the full K-strip loads (16 independent dwordx4 in flight)
    float4 xa[16];
#pragma unroll
    for (int ks = 0; ks < 8; ++ks) {
        xa[2 * ks]     = xr[ks * 8];
        xa[2 * ks + 1] = xr[ks * 8 + 1];
    }
    __builtin_amdgcn_sched_barrier(0);   // pin x loads before staging

    f32x4 acc[9];
#pragma unroll
    for (int f = 0; f < 9; ++f) acc[f] = (f32x4){0.f, 0.f, 0.f, 0.f};

    int r = lane & 15;
    int swz = r & 7;
    int rb = r * 16 + kg;                // uint4 idx base in [row][16] half-layout

    // two K-halves: stage 36KB, run 4 MFMA steps, repeat
#pragma unroll
    for (int half = 0; half < 2; ++half) {
        if (half) __syncthreads();       // all reads of previous half done
#pragma unroll
        for (int it = 0; it < 9; ++it) {
            int i = it * 256 + t;        // 0..2303
            wlds[i ^ ((i >> 4) & 7)] = ((const uint4*)W1t)[(i >> 4) * 32 + half * 16 + (i & 15)];
        }
        __syncthreads();
#pragma unroll
        for (int ks = 0; ks < 4; ++ks) {
            union { uint4 u4; bf16x8 v; } A;
            float4 a0 = xa[2 * (half * 4 + ks)], a1 = xa[2 * (half * 4 + ks) + 1];
            A.u4.x = pk2(a0.x, a0.y); A.u4.y = pk2(a0.z, a0.w);
            A.u4.z = pk2(a1.x, a1.y); A.u4.w = pk2(a1.z, a1.w);
#pragma unroll
            for (int f = 0; f < 9; ++f) {
                union { uint4 u4; bf16x8 v; } B;
                B.u4 = wlds[(f * 256 + rb + ks * 4) ^ swz];
                acc[f] = __builtin_amdgcn_mfma_f32_16x16x32_bf16(A.v, B.v, acc[f], 0, 0, 0);
            }
        }
    }

    // store: C/D layout col=lane&15, row=(lane>>4)*4+reg; h1 as fp8 e4m3
    int col = lane & 15;
    int rbase = mbase + (lane >> 4) * 4;
#pragma unroll
    for (int f = 0; f < 8; ++f) {
        int w = 0;
        w = __builtin_amdgcn_cvt_pk_fp8_f32(acc[f][0], acc[f][1], w, false);
        w = __builtin_amdgcn_cvt_pk_fp8_f32(acc[f][2], acc[f][3], w, true);
#pragma unroll
        for (int i = 0; i < 4; ++i) {
            int rr = rbase + i;
            if (rr < NODES)
                h1f8[(size_t)rr * F1 + f * 16 + col] = (unsigned char)((w >> (8 * i)) & 0xff);
        }
    }
#pragma unroll
    for (int i = 0; i < 4; ++i) {
        int rr = rbase + i;
        if (rr < NODES) {
            float v = acc[8][i];
            if (col < 8) as1[(size_t)rr * NHEAD + col] = v;
            else ad1[(size_t)rr * NHEAD + (col - 8)] = v;
        }
    }
}

// ---------- MFMA GEMM2: out1b[N,128]bf16 @ W2e^T -> h2b bf16 + as2/ad2 ----------
__global__ __launch_bounds__(256) void gemm2m(const unsigned short* __restrict__ a,
                                              const unsigned short* __restrict__ W2e,
                                              unsigned short* __restrict__ h2b,
                                              float* __restrict__ as2,
                                              float* __restrict__ ad2) {
    __shared__ uint4 wlds[768];          // 48 rows x 16 uint4 = 12288 B
    int t = threadIdx.x;
    int wave = t >> 6, lane = t & 63;
    int mbase = blockIdx.x * 64 + wave * 16;
    int rowc = min(mbase + (lane & 15), NODES - 1);
    int kg = lane >> 4;              // 0..3
    const uint4* ar = (const uint4*)(a + (size_t)rowc * F1 + kg * 8);

    // preload all 4 A fragments (K=128)
    uint4 xa[4];
#pragma unroll
    for (int ks = 0; ks < 4; ++ks) xa[ks] = ar[ks * 4];
    __builtin_amdgcn_sched_barrier(0);

    // stage W2e, swizzled: uint4 idx i -> i ^ ((i>>4)&7)
#pragma unroll
    for (int it = 0; it < 3; ++it) {
        int i = it * 256 + t;
        wlds[i ^ ((i >> 4) & 7)] = ((const uint4*)W2e)[i];
    }
    __syncthreads();

    f32x4 acc[3];
#pragma unroll
    for (int f = 0; f < 3; ++f) acc[f] = (f32x4){0.f, 0.f, 0.f, 0.f};

    int r = lane & 15;
    int swz = r & 7;
    int rb = r * 16 + kg;                // uint4 idx within frag row-block (16/row)

#pragma unroll
    for (int ks = 0; ks < 4; ++ks) {
        union { uint4 u; bf16x8 v; } A;
        A.u = xa[ks];
#pragma unroll
        for (int f = 0; f < 3; ++f) {
            union { uint4 u; bf16x8 v; } B;
            B.u = wlds[(f * 256 + rb + ks * 4) ^ swz];
            acc[f] = __builtin_amdgcn_mfma_f32_16x16x32_bf16(A.v, B.v, acc[f], 0, 0, 0);
        }
    }

    int col = lane & 15;
    int rbase = mbase + (lane >> 4) * 4;
#pragma unroll
    for (int f = 0; f < 2; ++f) {
#pragma unroll
        for (int i = 0; i < 4; ++i) {
            int rr = rbase + i;
            if (rr < NODES) h2b[(size_t)rr * NC + f * 16 + col] = f2bf(acc[f][i]);
        }
    }
#pragma unroll
    for (int i = 0; i < 4; ++i) {
        int rr = rbase + i;
        if (rr < NODES) {
            float v = acc[2][i];
            int c = 32 + col;
            if (c < NC) h2b[(size_t)rr * NC + c] = f2bf(v);
            else if (c == NC) as2[rr] = v;
            else if (c == NC + 1) ad2[rr] = v;
        }
    }
}

// no-max softmax step, fp8 h-row (8 channels per lane)
#define PROC8F8(AV, HV)                                          \
    {                                                            \
        float l = (AV) + adv;                                    \
        l = l > 0.f ? l : 0.2f * l;                              \
        float p = __expf(l);                                     \
        den += p;                                                \
        f32x2 c0 = __builtin_amdgcn_cvt_pk_f32_fp8(HV.x, false); \
        f32x2 c1 = __builtin_amdgcn_cvt_pk_f32_fp8(HV.x, true);  \
        f32x2 c2 = __builtin_amdgcn_cvt_pk_f32_fp8(HV.y, false); \
        f32x2 c3 = __builtin_amdgcn_cvt_pk_f32_fp8(HV.y, true);  \
        acc[0] += p * c0.x; acc[1] += p * c0.y;                  \
        acc[2] += p * c1.x; acc[3] += p * c1.y;                  \
        acc[4] += p * c2.x; acc[5] += p * c2.y;                  \
        acc[6] += p * c3.x; acc[7] += p * c3.y;                  \
    }

// no-max softmax step, bf16 h-row (8 channels per lane)
#define PROC8(AV, HV)                                    \
    {                                                    \
        float l = (AV) + adv;                            \
        l = l > 0.f ? l : 0.2f * l;                      \
        float p = __expf(l);                             \
        den += p;                                        \
        acc[0] += p * bflo(HV.x); acc[1] += p * bfhi(HV.x); \
        acc[2] += p * bflo(HV.y); acc[3] += p * bfhi(HV.y); \
        acc[4] += p * bflo(HV.z); acc[5] += p * bfhi(HV.z); \
        acc[6] += p * bflo(HV.w); acc[7] += p * bfhi(HV.w); \
    }

// ---------- L1 gather: 16-lane group per dst (4 dst/wave), fp8 rows, depth-2 ----------
__global__ __launch_bounds__(256) void msg1(const int* __restrict__ rowPtr,
                                            const unsigned short* __restrict__ csr16,
                                            const float* __restrict__ as1,
                                            const float* __restrict__ ad1,
                                            const unsigned char* __restrict__ h1f8,
                                            const float* __restrict__ b1,
                                            unsigned short* __restrict__ out1b) {
    int t = threadIdx.x;
    int wid = t >> 6, lane = t & 63;
    int g = lane >> 4;                    // group 0..3 -> own dst
    int cl = lane & 15;                   // channel lane: ch 8*cl..8*cl+7
    int h = cl >> 1;                      // head
    int d = blockIdx.x * 16 + wid * 4 + g;   // grid exact: 3125*16 = 50000
    float adv = ad1[(size_t)d * NHEAD + h];
    int rs = rowPtr[d], re = rowPtr[d + 1];  // re > rs (self-loops)
    float den = 0.f;
    float acc[8];
#pragma unroll
    for (int k = 0; k < 8; ++k) acc[k] = 0.f;

    const char* as1c = (const char*)as1;
    unsigned hoff = (unsigned)(h << 2);
    unsigned coff = (unsigned)(cl << 3);

// internal index j_ avoids shadowing the caller's loop variable (R11 bug)
#define LD1(J, AV, HV)                                                \
    {                                                                 \
        int j_ = (J);                                                 \
        AV = -1e30f; HV = make_uint2(0u, 0u);                         \
        if (j_ < re) {                                                \
            unsigned ss = (unsigned)csr16[j_];                        \
            AV = *(const float*)(as1c + (ss << 5) + hoff);            \
            HV = *(const uint2*)(h1f8 + (ss << 7) + coff);            \
        }                                                             \
    }

    float av0, av1; uint2 hv0, hv1;
    LD1(rs, av0, hv0);
    LD1(rs + 1, av1, hv1);
    for (int j = rs; j < re; j += 2) {
        float ta, tb; uint2 ua, ub;
        LD1(j + 2, ta, ua);
        LD1(j + 3, tb, ub);
        PROC8F8(av0, hv0);
        PROC8F8(av1, hv1);
        av0 = ta; hv0 = ua; av1 = tb; hv1 = ub;
    }
#undef LD1

    float invd = 1.f / (den + 1e-16f);
    const float4* bp = (const float4*)(b1 + cl * 8);
    float4 ba = bp[0], bb = bp[1];
    float v[8];
    v[0] = acc[0] * invd + ba.x; v[1] = acc[1] * invd + ba.y;
    v[2] = acc[2] * invd + ba.z; v[3] = acc[3] * invd + ba.w;
    v[4] = acc[4] * invd + bb.x; v[5] = acc[5] * invd + bb.y;
    v[6] = acc[6] * invd + bb.z; v[7] = acc[7] * invd + bb.w;
#pragma unroll
    for (int k = 0; k < 8; ++k) {
        float ev = __expf(v[k]) - 1.f;          // ELU negative branch
        v[k] = v[k] > 0.f ? v[k] : ev;
    }
    uint4 o;
    o.x = pk2(v[0], v[1]); o.y = pk2(v[2], v[3]);
    o.z = pk2(v[4], v[5]); o.w = pk2(v[6], v[7]);
    *(uint4*)(out1b + (size_t)d * F1 + cl * 8) = o;
}

// ---------- L2 gather: 8-lane group per dst (8 dst/wave), depth-2 ----------
__global__ __launch_bounds__(256) void msg2(const int* __restrict__ rowPtr,
                                            const unsigned short* __restrict__ csr16,
                                            const float* __restrict__ as2,
                                            const float* __restrict__ ad2,
                                            const unsigned short* __restrict__ h2b,
                                            const float* __restrict__ b2,
                                            float* __restrict__ out) {
    int t = threadIdx.x;
    int wid = t >> 6, lane = t & 63;
    int g = lane >> 3;                    // group 0..7 -> own dst
    int cl = lane & 7;                    // channel lane; active cl<5 (8 ch each)
    int clc = cl < 5 ? cl : 4;
    bool act = cl < 5;
    int d0 = blockIdx.x * 32 + wid * 8 + g;
    int d = min(d0, NODES - 1);
    float adv = ad2[d];
    int rs = rowPtr[d], re = rowPtr[d + 1];
    if (!act) { rs = 0; re = 0; }         // inactive lanes: no loads, no loop
    float den = 0.f;
    float acc[8];
#pragma unroll
    for (int k = 0; k < 8; ++k) acc[k] = 0.f;

    const char* as2c = (const char*)as2;
    const char* h2c = (const char*)h2b;
    unsigned coff = (unsigned)(clc << 4);

#define LD2(J, AV, HV)                                                \
    {                                                                 \
        int j_ = (J);                                                 \
        AV = -1e30f; HV = make_uint4(0u, 0u, 0u, 0u);                 \
        if (j_ < re) {                                                \
            unsigned ss = (unsigned)csr16[j_];                        \
            AV = *(const float*)(as2c + (ss << 2));                   \
            HV = *(const uint4*)(h2c + ss * 80u + coff);              \
        }                                                             \
    }

    float av0, av1; uint4 hv0, hv1;
    LD2(rs, av0, hv0);
    LD2(rs + 1, av1, hv1);
    for (int j = rs; j < re; j += 2) {
        float ta, tb; uint4 ua, ub;
        LD2(j + 2, ta, ua);
        LD2(j + 3, tb, ub);
        PROC8(av0, hv0);
        PROC8(av1, hv1);
        av0 = ta; hv0 = ua; av1 = tb; hv1 = ub;
    }
#undef LD2

    float invd = 1.f / (den + 1e-16f);
    float v[8];
    float mk = -1e30f;
    if (act) {
        const float4* bp = (const float4*)(b2 + cl * 8);
        float4 ba = bp[0], bb = bp[1];
        v[0] = acc[0] * invd + ba.x; v[1] = acc[1] * invd + ba.y;
        v[2] = acc[2] * invd + ba.z; v[3] = acc[3] * invd + ba.w;
        v[4] = acc[4] * invd + bb.x; v[5] = acc[5] * invd + bb.y;
        v[6] = acc[6] * invd + bb.z; v[7] = acc[7] * invd + bb.w;
#pragma unroll
        for (int k = 0; k < 8; ++k) mk = fmaxf(mk, v[k]);
    }
    // reduce within the 8-lane group
    mk = fmaxf(mk, __shfl_xor(mk, 1, 64));
    mk = fmaxf(mk, __shfl_xor(mk, 2, 64));
    mk = fmaxf(mk, __shfl_xor(mk, 4, 64));
    float e = 0.f;
    if (act) {
#pragma unroll
        for (int k = 0; k < 8; ++k) e += __expf(v[k] - mk);
    }
    e += __shfl_xor(e, 1, 64);
    e += __shfl_xor(e, 2, 64);
    e += __shfl_xor(e, 4, 64);
    float lse = mk + logf(e);
    if (act && d0 < NODES) {
        float4 o0 = make_float4(v[0] - lse, v[1] - lse, v[2] - lse, v[3] - lse);
        float4 o1 = make_float4(v[4] - lse, v[5] - lse, v[6] - lse, v[7] - lse);
        float* po = out + (size_t)d0 * NC + cl * 8;
        *(float4*)po = o0;
        *(float4*)(po + 4) = o1;
    }
}

extern "C" void kernel_launch(void* const* d_in, const int* in_sizes, int n_in,
                              void* d_out, int out_size, void* d_ws, size_t ws_size,
                              hipStream_t stream) {
    const float* x       = (const float*)d_in[0];
    const unsigned* eidx = (const unsigned*)d_in[1];
    const float* W1      = (const float*)d_in[2];
    const float* atts1   = (const float*)d_in[3];
    const float* attd1   = (const float*)d_in[4];
    const float* b1      = (const float*)d_in[5];
    const float* W2      = (const float*)d_in[6];
    const float* atts2   = (const float*)d_in[7];
    const float* attd2   = (const float*)d_in[8];
    const float* b2      = (const float*)d_in[9];
    float* out = (float*)d_out;

    char* base = (char*)d_ws;
    size_t off = 0;
    auto takeB = [&](size_t bytes) {
        void* p = base + off;
        off = (off + bytes + 255) & ~(size_t)255;
        return p;
    };
    unsigned* flag = (unsigned*)takeB(256);
    int* cnt       = (int*)takeB((size_t)NODES * 4);
    int* fill      = (int*)takeB((size_t)NODES * 4);
    int* rowPtr    = (int*)takeB((size_t)(NODES + 64) * 4);
    int* blockSum  = (int*)takeB(SCAN_BLK * 4);
    int* blockOff  = (int*)takeB(SCAN_BLK * 4);
    unsigned short* csr16 = (unsigned short*)takeB((size_t)ETOT * 2 + 256);
    unsigned short* W1t  = (unsigned short*)takeB((size_t)144 * NF * 2);
    unsigned short* W2e  = (unsigned short*)takeB((size_t)48 * F1 * 2);
    unsigned char* h1f8  = (unsigned char*)takeB((size_t)NODES * F1);
    float* as1     = (float*)takeB((size_t)NODES * NHEAD * 4);
    float* ad1     = (float*)takeB((size_t)NODES * NHEAD * 4);
    unsigned short* out1b = (unsigned short*)takeB((size_t)(NODES + 64) * F1 * 2);
    unsigned short* h2b  = (unsigned short*)takeB((size_t)NODES * NC * 2 + 256);
    float* as2     = (float*)takeB((size_t)NODES * 4);
    float* ad2     = (float*)takeB((size_t)NODES * 4);

    hipMemsetAsync(flag, 0, 4, stream);
    hipMemsetAsync(cnt, 0, (size_t)NODES * 4, stream);
    hipMemsetAsync(fill, 0, (size_t)NODES * 4, stream);

    detect_k<<<1, 256, 0, stream>>>(eidx, flag);

    // CSR histogram + scan
    hist_k<<<(ETOT + 255) / 256, 256, 0, stream>>>(eidx, flag, cnt);
    scanA<<<SCAN_BLK, 256, 0, stream>>>(cnt, rowPtr, blockSum);
    scanB<<<1, 256, 0, stream>>>(blockSum, blockOff);
    scanC<<<SCAN_BLK, 256, 0, stream>>>(rowPtr, blockOff);

    // weight prep (both layers, one dispatch)
    prepW12<<<192, 256, 0, stream>>>(W1, atts1, attd1, W2, atts2, attd2, W1t, W2e);

    // fused: CSR scatter (ushort) + layer-1 MFMA GEMM (fp8 h1 out)
    scatter_gemm1<<<SG_BLOCKS, 256, 0, stream>>>(eidx, flag, rowPtr, fill, csr16,
                                                 x, W1t, h1f8, as1, ad1);

    // Layer-1 gather
    msg1<<<NODES / 16, 256, 0, stream>>>(rowPtr, csr16, as1, ad1, h1f8, b1, out1b);

    // Layer 2
    gemm2m<<<(NODES + 63) / 64, 256, 0, stream>>>(out1b, W2e, h2b, as2, ad2);
    msg2<<<(NODES + 31) / 32, 256, 0, stream>>>(rowPtr, csr16, as2, ad2, h2b, b2, out);
}

// Round 18
// 124.667 us; speedup vs baseline: 2.0553x; 1.3463x over previous
//
#include <hip/hip_runtime.h>
#include <math.h>

#define NODES 50000
#define NEDGE 800000
#define ETOT  (NEDGE + NODES)   // edges + self loops = 850000
#define NF    256
#define F1    128               // HEADS*NHID
#define NHEAD 8
#define NHID  16
#define NC    40
#define ELLCAP 64               // slots per dst; P(deg>63) ~ 1e-17 for Poisson(16)
// fused scatter+gemm1 grid: 3321 scatter blocks + 782 gemm blocks, 4:1 interleave
#define SG_BLOCKS 4103
#define SG_GEMMCUT 3910         // 782*5; gemm role at bid%5==4 below this

typedef __attribute__((ext_vector_type(8))) short bf16x8;
typedef __attribute__((ext_vector_type(4))) float f32x4;
typedef __attribute__((ext_vector_type(2))) float f32x2;

__device__ __forceinline__ float bflo(unsigned u) { return __uint_as_float(u << 16); }
__device__ __forceinline__ float bfhi(unsigned u) { return __uint_as_float(u & 0xffff0000u); }
__device__ __forceinline__ unsigned short f2bf(float f) {
    unsigned u = __float_as_uint(f);
    unsigned r = u + 0x7fffu + ((u >> 16) & 1u);   // RNE
    return (unsigned short)(r >> 16);
}
__device__ __forceinline__ unsigned pk2(float a, float b) {
    return (unsigned)f2bf(a) | ((unsigned)f2bf(b) << 16);
}

// ---------- edge index dtype detect ----------
__global__ void detect_k(const unsigned* __restrict__ u, unsigned* __restrict__ flag) {
    int t = threadIdx.x;              // 256 threads
    if (u[2 * t + 1] != 0u) atomicOr(flag, 1u);   // nonzero hi-word pattern => int32 data
}

// ---------- prep (merged): W1t144[144][256] + W2e[48][128], both bf16 ----------
__global__ void prepW12(const float* __restrict__ W1, const float* __restrict__ atts1,
                        const float* __restrict__ attd1,
                        const float* __restrict__ W2, const float* __restrict__ atts2,
                        const float* __restrict__ attd2,
                        unsigned short* __restrict__ W1t, unsigned short* __restrict__ W2e) {
    int b = blockIdx.x;
    int k = threadIdx.x;
    if (b < 144) {
        int n = b;            // 0..143, k 0..255
        float v;
        if (n < 128) {
            v = W1[(size_t)k * F1 + n];
        } else if (n < 136) {
            int h = n - 128; v = 0.f;
#pragma unroll
            for (int c = 0; c < 16; ++c) v += W1[(size_t)k * F1 + h * 16 + c] * atts1[h * 16 + c];
        } else {
            int h = n - 136; v = 0.f;
#pragma unroll
            for (int c = 0; c < 16; ++c) v += W1[(size_t)k * F1 + h * 16 + c] * attd1[h * 16 + c];
        }
        W1t[(size_t)n * NF + k] = f2bf(v);
    } else {
        int n = b - 144;      // 0..47, k valid 0..127
        if (k >= F1) return;
        float v = 0.f;
        if (n < NC) {
            v = W2[(size_t)k * NC + n];
        } else if (n == NC) {
#pragma unroll
            for (int c = 0; c < NC; ++c) v += W2[(size_t)k * NC + c] * atts2[c];
        } else if (n == NC + 1) {
#pragma unroll
            for (int c = 0; c < NC; ++c) v += W2[(size_t)k * NC + c] * attd2[c];
        }
        W2e[(size_t)n * F1 + k] = f2bf(v);
    }
}

// ---------- FUSED: ELL scatter + MFMA GEMM1 split-K LDS (fp8 h1) ----------
// ELL: csr16[d*64+pos], pos=atomicAdd(fill[d]) -- no rowPtr/hist/scan needed.
__global__ __launch_bounds__(256) void scatter_gemm1(
        const unsigned* __restrict__ u, const unsigned* __restrict__ flag,
        int* __restrict__ fill, unsigned short* __restrict__ csr16,
        const float* __restrict__ x, const unsigned short* __restrict__ W1t,
        unsigned char* __restrict__ h1f8, float* __restrict__ as1,
        float* __restrict__ ad1) {
    __shared__ uint4 wlds[2304];         // 144 rows x 16 uint4 = 36864 B
    int bid = blockIdx.x;
    int t = threadIdx.x;
    bool isGemm = (bid < SG_GEMMCUT) && ((bid % 5) == 4);
    if (!isGemm) {
        // ---- scatter role: 1 edge per thread, 2B ELL stores ----
        int si = bid - min(bid, SG_GEMMCUT) / 5;   // gemm blocks before bid
        int e = si * 256 + t;
        if (e >= ETOT) return;
        int s, d;
        if (e < NEDGE) {
            if (*flag) { s = (int)u[e]; d = (int)u[NEDGE + e]; }
            else       { s = (int)u[2 * e]; d = (int)u[2 * NEDGE + 2 * e]; }
        } else s = d = e - NEDGE;
        int pos = atomicAdd(&fill[d], 1);
        if (pos < ELLCAP) csr16[((size_t)d << 6) + pos] = (unsigned short)s;
        return;
    }
    // ---- gemm role ----
    int gi = bid / 5;
    int wave = t >> 6, lane = t & 63;
    int mbase = gi * 64 + wave * 16;
    int rowc = min(mbase + (lane & 15), NODES - 1);
    int kg = lane >> 4;              // 0..3
    const float4* xr = (const float4*)(x + (size_t)rowc * NF + kg * 8);

    // issue the full K-strip loads (16 independent dwordx4 in flight)
    float4 xa[16];
#pragma unroll
    for (int ks = 0; ks < 8; ++ks) {
        xa[2 * ks]     = xr[ks * 8];
        xa[2 * ks + 1] = xr[ks * 8 + 1];
    }
    __builtin_amdgcn_sched_barrier(0);   // pin x loads before staging

    f32x4 acc[9];
#pragma unroll
    for (int f = 0; f < 9; ++f) acc[f] = (f32x4){0.f, 0.f, 0.f, 0.f};

    int r = lane & 15;
    int swz = r & 7;
    int rb = r * 16 + kg;                // uint4 idx base in [row][16] half-layout

    // two K-halves: stage 36KB, run 4 MFMA steps, repeat
#pragma unroll
    for (int half = 0; half < 2; ++half) {
        if (half) __syncthreads();       // all reads of previous half done
#pragma unroll
        for (int it = 0; it < 9; ++it) {
            int i = it * 256 + t;        // 0..2303
            wlds[i ^ ((i >> 4) & 7)] = ((const uint4*)W1t)[(i >> 4) * 32 + half * 16 + (i & 15)];
        }
        __syncthreads();
#pragma unroll
        for (int ks = 0; ks < 4; ++ks) {
            union { uint4 u4; bf16x8 v; } A;
            float4 a0 = xa[2 * (half * 4 + ks)], a1 = xa[2 * (half * 4 + ks) + 1];
            A.u4.x = pk2(a0.x, a0.y); A.u4.y = pk2(a0.z, a0.w);
            A.u4.z = pk2(a1.x, a1.y); A.u4.w = pk2(a1.z, a1.w);
#pragma unroll
            for (int f = 0; f < 9; ++f) {
                union { uint4 u4; bf16x8 v; } B;
                B.u4 = wlds[(f * 256 + rb + ks * 4) ^ swz];
                acc[f] = __builtin_amdgcn_mfma_f32_16x16x32_bf16(A.v, B.v, acc[f], 0, 0, 0);
            }
        }
    }

    // store: C/D layout col=lane&15, row=(lane>>4)*4+reg; h1 as fp8 e4m3
    int col = lane & 15;
    int rbase = mbase + (lane >> 4) * 4;
#pragma unroll
    for (int f = 0; f < 8; ++f) {
        int w = 0;
        w = __builtin_amdgcn_cvt_pk_fp8_f32(acc[f][0], acc[f][1], w, false);
        w = __builtin_amdgcn_cvt_pk_fp8_f32(acc[f][2], acc[f][3], w, true);
#pragma unroll
        for (int i = 0; i < 4; ++i) {
            int rr = rbase + i;
            if (rr < NODES)
                h1f8[(size_t)rr * F1 + f * 16 + col] = (unsigned char)((w >> (8 * i)) & 0xff);
        }
    }
#pragma unroll
    for (int i = 0; i < 4; ++i) {
        int rr = rbase + i;
        if (rr < NODES) {
            float v = acc[8][i];
            if (col < 8) as1[(size_t)rr * NHEAD + col] = v;
            else ad1[(size_t)rr * NHEAD + (col - 8)] = v;
        }
    }
}

// no-max softmax step, fp8 h-row (8 channels per lane)
#define PROC8F8(AV, HV)                                          \
    {                                                            \
        float l = (AV) + adv;                                    \
        l = l > 0.f ? l : 0.2f * l;                              \
        float p = __expf(l);                                     \
        den += p;                                                \
        f32x2 c0 = __builtin_amdgcn_cvt_pk_f32_fp8(HV.x, false); \
        f32x2 c1 = __builtin_amdgcn_cvt_pk_f32_fp8(HV.x, true);  \
        f32x2 c2 = __builtin_amdgcn_cvt_pk_f32_fp8(HV.y, false); \
        f32x2 c3 = __builtin_amdgcn_cvt_pk_f32_fp8(HV.y, true);  \
        acc[0] += p * c0.x; acc[1] += p * c0.y;                  \
        acc[2] += p * c1.x; acc[3] += p * c1.y;                  \
        acc[4] += p * c2.x; acc[5] += p * c2.y;                  \
        acc[6] += p * c3.x; acc[7] += p * c3.y;                  \
    }

// no-max softmax step, bf16 h-row (8 channels per lane)
#define PROC8(AV, HV)                                    \
    {                                                    \
        float l = (AV) + adv;                            \
        l = l > 0.f ? l : 0.2f * l;                      \
        float p = __expf(l);                             \
        den += p;                                        \
        acc[0] += p * bflo(HV.x); acc[1] += p * bfhi(HV.x); \
        acc[2] += p * bflo(HV.y); acc[3] += p * bfhi(HV.y); \
        acc[4] += p * bflo(HV.z); acc[5] += p * bfhi(HV.z); \
        acc[6] += p * bflo(HV.w); acc[7] += p * bfhi(HV.w); \
    }

// ---------- L1 gather + fused GEMM2: block owns 16 dst (M=16 tile) ----------
// Phase 1: each 16-lane group gathers one dst row (fp8 h1, ELL edges), applies
// softmax-normalize + bias + ELU, writes the bf16 row into swizzled LDS.
// Phase 2: waves 0..2 run the 16x48x128 MFMA tile (W2e staged in LDS),
// producing h2b plus the fused as2/ad2 columns. out1 never touches HBM.
__global__ __launch_bounds__(256) void msg1g2(const int* __restrict__ fill,
                                              const unsigned short* __restrict__ csr16,
                                              const float* __restrict__ as1,
                                              const float* __restrict__ ad1,
                                              const unsigned char* __restrict__ h1f8,
                                              const float* __restrict__ b1,
                                              const unsigned short* __restrict__ W2e,
                                              unsigned short* __restrict__ h2b,
                                              float* __restrict__ as2,
                                              float* __restrict__ ad2) {
    __shared__ uint4 w2s[768];           // 48 x 16 uint4 = 12 KB, swizzled
    __shared__ uint4 o1s[256];           // 16 rows x 16 uint4 = 4 KB, swizzled
    int t = threadIdx.x;
    int wid = t >> 6, lane = t & 63;
    int g = lane >> 4;                    // group 0..3 -> own dst
    int cl = lane & 15;                   // channel lane: ch 8*cl..8*cl+7
    int h = cl >> 1;                      // head

    // stage W2e (swizzled identically to gemm2m)
#pragma unroll
    for (int it = 0; it < 3; ++it) {
        int i = it * 256 + t;
        w2s[i ^ ((i >> 4) & 7)] = ((const uint4*)W2e)[i];
    }

    int d = blockIdx.x * 16 + wid * 4 + g;   // grid exact: 3125*16 = 50000
    float adv = ad1[(size_t)d * NHEAD + h];
    int deg = fill[d];                        // >= 1 (self loop)
    size_t eb = (size_t)d << 6;               // ELL row base
    float den = 0.f;
    float acc[8];
#pragma unroll
    for (int k = 0; k < 8; ++k) acc[k] = 0.f;

    const char* as1c = (const char*)as1;
    unsigned hoff = (unsigned)(h << 2);
    unsigned coff = (unsigned)(cl << 3);

// internal index j_ avoids shadowing the caller's loop variable (R11 bug)
#define LD1(J, AV, HV)                                                \
    {                                                                 \
        int j_ = (J);                                                 \
        AV = -1e30f; HV = make_uint2(0u, 0u);                         \
        if (j_ < deg) {                                               \
            unsigned ss = (unsigned)csr16[eb + j_];                   \
            AV = *(const float*)(as1c + (ss << 5) + hoff);            \
            HV = *(const uint2*)(h1f8 + (ss << 7) + coff);            \
        }                                                             \
    }

    float av0, av1; uint2 hv0, hv1;
    LD1(0, av0, hv0);
    LD1(1, av1, hv1);
    for (int j = 0; j < deg; j += 2) {
        float ta, tb; uint2 ua, ub;
        LD1(j + 2, ta, ua);
        LD1(j + 3, tb, ub);
        PROC8F8(av0, hv0);
        PROC8F8(av1, hv1);
        av0 = ta; hv0 = ua; av1 = tb; hv1 = ub;
    }
#undef LD1

    float invd = 1.f / (den + 1e-16f);
    const float4* bp = (const float4*)(b1 + cl * 8);
    float4 ba = bp[0], bb = bp[1];
    float v[8];
    v[0] = acc[0] * invd + ba.x; v[1] = acc[1] * invd + ba.y;
    v[2] = acc[2] * invd + ba.z; v[3] = acc[3] * invd + ba.w;
    v[4] = acc[4] * invd + bb.x; v[5] = acc[5] * invd + bb.y;
    v[6] = acc[6] * invd + bb.z; v[7] = acc[7] * invd + bb.w;
#pragma unroll
    for (int k = 0; k < 8; ++k) {
        float ev = __expf(v[k]) - 1.f;          // ELU negative branch
        v[k] = v[k] > 0.f ? v[k] : ev;
    }
    uint4 o;
    o.x = pk2(v[0], v[1]); o.y = pk2(v[2], v[3]);
    o.z = pk2(v[4], v[5]); o.w = pk2(v[6], v[7]);
    int orow = wid * 4 + g;
    o1s[(orow * 16 + cl) ^ (orow & 7)] = o;
    __syncthreads();

    // Phase 2: GEMM tile f = wid (waves 0..2), M=16 block dst, N=16, K=128
    if (wid < 3) {
        int r = lane & 15;
        int kg = lane >> 4;
        int swz = r & 7;
        f32x4 c2 = (f32x4){0.f, 0.f, 0.f, 0.f};
#pragma unroll
        for (int ks = 0; ks < 4; ++ks) {
            union { uint4 u; bf16x8 vv; } A, B;
            A.u = o1s[(r * 16 + kg + ks * 4) ^ swz];
            B.u = w2s[(wid * 256 + r * 16 + kg + ks * 4) ^ swz];
            c2 = __builtin_amdgcn_mfma_f32_16x16x32_bf16(A.vv, B.vv, c2, 0, 0, 0);
        }
        int col = lane & 15;
        int rbase = blockIdx.x * 16 + (lane >> 4) * 4;
        if (wid < 2) {
#pragma unroll
            for (int i = 0; i < 4; ++i)
                h2b[(size_t)(rbase + i) * NC + wid * 16 + col] = f2bf(c2[i]);
        } else {
            int c = 32 + col;
#pragma unroll
            for (int i = 0; i < 4; ++i) {
                int rr = rbase + i;
                if (c < NC) h2b[(size_t)rr * NC + c] = f2bf(c2[i]);
                else if (c == NC) as2[rr] = c2[i];
                else if (c == NC + 1) ad2[rr] = c2[i];
            }
        }
    }
}

// ---------- L2 gather: 8-lane group per dst (8 dst/wave), ELL, depth-2 ----------
__global__ __launch_bounds__(256) void msg2(const int* __restrict__ fill,
                                            const unsigned short* __restrict__ csr16,
                                            const float* __restrict__ as2,
                                            const float* __restrict__ ad2,
                                            const unsigned short* __restrict__ h2b,
                                            const float* __restrict__ b2,
                                            float* __restrict__ out) {
    int t = threadIdx.x;
    int wid = t >> 6, lane = t & 63;
    int g = lane >> 3;                    // group 0..7 -> own dst
    int cl = lane & 7;                    // channel lane; active cl<5 (8 ch each)
    int clc = cl < 5 ? cl : 4;
    bool act = cl < 5;
    int d0 = blockIdx.x * 32 + wid * 8 + g;
    int d = min(d0, NODES - 1);
    float adv = ad2[d];
    int deg = act ? fill[d] : 0;          // inactive lanes: no loads, no loop
    size_t eb = (size_t)d << 6;
    float den = 0.f;
    float acc[8];
#pragma unroll
    for (int k = 0; k < 8; ++k) acc[k] = 0.f;

    const char* as2c = (const char*)as2;
    const char* h2c = (const char*)h2b;
    unsigned coff = (unsigned)(clc << 4);

#define LD2(J, AV, HV)                                                \
    {                                                                 \
        int j_ = (J);                                                 \
        AV = -1e30f; HV = make_uint4(0u, 0u, 0u, 0u);                 \
        if (j_ < deg) {                                               \
            unsigned ss = (unsigned)csr16[eb + j_];                   \
            AV = *(const float*)(as2c + (ss << 2));                   \
            HV = *(const uint4*)(h2c + ss * 80u + coff);              \
        }                                                             \
    }

    float av0, av1; uint4 hv0, hv1;
    LD2(0, av0, hv0);
    LD2(1, av1, hv1);
    for (int j = 0; j < deg; j += 2) {
        float ta, tb; uint4 ua, ub;
        LD2(j + 2, ta, ua);
        LD2(j + 3, tb, ub);
        PROC8(av0, hv0);
        PROC8(av1, hv1);
        av0 = ta; hv0 = ua; av1 = tb; hv1 = ub;
    }
#undef LD2

    float invd = 1.f / (den + 1e-16f);
    float v[8];
    float mk = -1e30f;
    if (act) {
        const float4* bp = (const float4*)(b2 + cl * 8);
        float4 ba = bp[0], bb = bp[1];
        v[0] = acc[0] * invd + ba.x; v[1] = acc[1] * invd + ba.y;
        v[2] = acc[2] * invd + ba.z; v[3] = acc[3] * invd + ba.w;
        v[4] = acc[4] * invd + bb.x; v[5] = acc[5] * invd + bb.y;
        v[6] = acc[6] * invd + bb.z; v[7] = acc[7] * invd + bb.w;
#pragma unroll
        for (int k = 0; k < 8; ++k) mk = fmaxf(mk, v[k]);
    }
    // reduce within the 8-lane group
    mk = fmaxf(mk, __shfl_xor(mk, 1, 64));
    mk = fmaxf(mk, __shfl_xor(mk, 2, 64));
    mk = fmaxf(mk, __shfl_xor(mk, 4, 64));
    float e = 0.f;
    if (act) {
#pragma unroll
        for (int k = 0; k < 8; ++k) e += __expf(v[k] - mk);
    }
    e += __shfl_xor(e, 1, 64);
    e += __shfl_xor(e, 2, 64);
    e += __shfl_xor(e, 4, 64);
    float lse = mk + logf(e);
    if (act && d0 < NODES) {
        float4 o0 = make_float4(v[0] - lse, v[1] - lse, v[2] - lse, v[3] - lse);
        float4 o1 = make_float4(v[4] - lse, v[5] - lse, v[6] - lse, v[7] - lse);
        float* po = out + (size_t)d0 * NC + cl * 8;
        *(float4*)po = o0;
        *(float4*)(po + 4) = o1;
    }
}

extern "C" void kernel_launch(void* const* d_in, const int* in_sizes, int n_in,
                              void* d_out, int out_size, void* d_ws, size_t ws_size,
                              hipStream_t stream) {
    const float* x       = (const float*)d_in[0];
    const unsigned* eidx = (const unsigned*)d_in[1];
    const float* W1      = (const float*)d_in[2];
    const float* atts1   = (const float*)d_in[3];
    const float* attd1   = (const float*)d_in[4];
    const float* b1      = (const float*)d_in[5];
    const float* W2      = (const float*)d_in[6];
    const float* atts2   = (const float*)d_in[7];
    const float* attd2   = (const float*)d_in[8];
    const float* b2      = (const float*)d_in[9];
    float* out = (float*)d_out;

    char* base = (char*)d_ws;
    size_t off = 0;
    auto takeB = [&](size_t bytes) {
        void* p = base + off;
        off = (off + bytes + 255) & ~(size_t)255;
        return p;
    };
    unsigned* flag = (unsigned*)takeB(256);
    int* fill      = (int*)takeB((size_t)NODES * 4);
    unsigned short* csr16 = (unsigned short*)takeB((size_t)NODES * ELLCAP * 2 + 256);
    unsigned short* W1t  = (unsigned short*)takeB((size_t)144 * NF * 2);
    unsigned short* W2e  = (unsigned short*)takeB((size_t)48 * F1 * 2);
    unsigned char* h1f8  = (unsigned char*)takeB((size_t)NODES * F1);
    float* as1     = (float*)takeB((size_t)NODES * NHEAD * 4);
    float* ad1     = (float*)takeB((size_t)NODES * NHEAD * 4);
    unsigned short* h2b  = (unsigned short*)takeB((size_t)NODES * NC * 2 + 256);
    float* as2     = (float*)takeB((size_t)NODES * 4);
    float* ad2     = (float*)takeB((size_t)NODES * 4);

    hipMemsetAsync(flag, 0, 4, stream);
    hipMemsetAsync(fill, 0, (size_t)NODES * 4, stream);

    detect_k<<<1, 256, 0, stream>>>(eidx, flag);

    // weight prep (both layers, one dispatch)
    prepW12<<<192, 256, 0, stream>>>(W1, atts1, attd1, W2, atts2, attd2, W1t, W2e);

    // fused: ELL scatter + layer-1 MFMA GEMM (fp8 h1 out)
    scatter_gemm1<<<SG_BLOCKS, 256, 0, stream>>>(eidx, flag, fill, csr16,
                                                 x, W1t, h1f8, as1, ad1);

    // Layer-1 gather + fused layer-2 projection (out1 stays on-chip)
    msg1g2<<<NODES / 16, 256, 0, stream>>>(fill, csr16, as1, ad1, h1f8, b1,
                                           W2e, h2b, as2, ad2);

    // Layer-2 gather + log_softmax
    msg2<<<(NODES + 31) / 32, 256, 0, stream>>>(fill, csr16, as2, ad2, h2b, b2, out);
}

// Round 19
// 124.490 us; speedup vs baseline: 2.0582x; 1.0014x over previous
//
#include <hip/hip_runtime.h>
#include <math.h>

#define NODES 50000
#define NEDGE 800000
#define ETOT  (NEDGE + NODES)   // edges + self loops = 850000
#define NF    256
#define F1    128               // HEADS*NHID
#define NHEAD 8
#define NHID  16
#define NC    40
#define ELLCAP 64               // slots per dst; P(deg>63) ~ 1e-17 for Poisson(16)
// fused scatter+gemm1: 104 windows of 40 blocks = 32 scatter (4 chunks x 8
// XCD residues) + 8 gemm. 416 chunks of 2048 edges cover ETOT.
#define SG_CHUNK 2048
#define SG_NWIN 104
#define SG_BLOCKS (SG_NWIN * 40)   // 4160
#define SG_GEMM 782

typedef __attribute__((ext_vector_type(8))) short bf16x8;
typedef __attribute__((ext_vector_type(4))) float f32x4;
typedef __attribute__((ext_vector_type(2))) float f32x2;

__device__ __forceinline__ float bflo(unsigned u) { return __uint_as_float(u << 16); }
__device__ __forceinline__ float bfhi(unsigned u) { return __uint_as_float(u & 0xffff0000u); }
__device__ __forceinline__ unsigned short f2bf(float f) {
    unsigned u = __float_as_uint(f);
    unsigned r = u + 0x7fffu + ((u >> 16) & 1u);   // RNE
    return (unsigned short)(r >> 16);
}
__device__ __forceinline__ unsigned pk2(float a, float b) {
    return (unsigned)f2bf(a) | ((unsigned)f2bf(b) << 16);
}

// ---------- edge index dtype detect ----------
__global__ void detect_k(const unsigned* __restrict__ u, unsigned* __restrict__ flag) {
    int t = threadIdx.x;              // 256 threads
    if (u[2 * t + 1] != 0u) atomicOr(flag, 1u);   // nonzero hi-word pattern => int32 data
}

// ---------- prep (merged): W1t144[144][256] + W2e[48][128], both bf16 ----------
__global__ void prepW12(const float* __restrict__ W1, const float* __restrict__ atts1,
                        const float* __restrict__ attd1,
                        const float* __restrict__ W2, const float* __restrict__ atts2,
                        const float* __restrict__ attd2,
                        unsigned short* __restrict__ W1t, unsigned short* __restrict__ W2e) {
    int b = blockIdx.x;
    int k = threadIdx.x;
    if (b < 144) {
        int n = b;            // 0..143, k 0..255
        float v;
        if (n < 128) {
            v = W1[(size_t)k * F1 + n];
        } else if (n < 136) {
            int h = n - 128; v = 0.f;
#pragma unroll
            for (int c = 0; c < 16; ++c) v += W1[(size_t)k * F1 + h * 16 + c] * atts1[h * 16 + c];
        } else {
            int h = n - 136; v = 0.f;
#pragma unroll
            for (int c = 0; c < 16; ++c) v += W1[(size_t)k * F1 + h * 16 + c] * attd1[h * 16 + c];
        }
        W1t[(size_t)n * NF + k] = f2bf(v);
    } else {
        int n = b - 144;      // 0..47, k valid 0..127
        if (k >= F1) return;
        float v = 0.f;
        if (n < NC) {
            v = W2[(size_t)k * NC + n];
        } else if (n == NC) {
#pragma unroll
            for (int c = 0; c < NC; ++c) v += W2[(size_t)k * NC + c] * atts2[c];
        } else if (n == NC + 1) {
#pragma unroll
            for (int c = 0; c < NC; ++c) v += W2[(size_t)k * NC + c] * attd2[c];
        }
        W2e[(size_t)n * F1 + k] = f2bf(v);
    }
}

// ---------- FUSED: XCD-affine ELL scatter + MFMA GEMM1 split-K LDS (fp8 h1) ----------
// Scatter tasks: (chunk, residue) pairs; a block commits only edges whose
// dst & 7 == blockIdx & 7 (presumed XCD id). All writes to a csr16 row then
// come from one XCD -> each dirty line written once instead of up to 8x.
// Extra dst re-reads are L3-served. Correct regardless of the real block->XCD map.
__global__ __launch_bounds__(256) void scatter_gemm1(
        const unsigned* __restrict__ u, const unsigned* __restrict__ flag,
        int* __restrict__ fill, unsigned short* __restrict__ csr16,
        const float* __restrict__ x, const unsigned short* __restrict__ W1t,
        unsigned char* __restrict__ h1f8, float* __restrict__ as1,
        float* __restrict__ ad1) {
    __shared__ uint4 wlds[2304];         // 144 rows x 16 uint4 = 36864 B
    int bid = blockIdx.x;
    int t = threadIdx.x;
    int w = bid / 40, i = bid % 40;
    if (i < 32) {
        // ---- scatter role: chunk of 2048 edges, commit residue (bid&7) ----
        int chunk = w * 4 + (i >> 3);
        int residue = bid & 7;           // == i & 7 since 40w % 8 == 0
        int ebase = chunk * SG_CHUNK;
        bool isi32 = (*flag) != 0;
#pragma unroll
        for (int q = 0; q < 8; ++q) {
            int e = ebase + q * 256 + t;
            if (e < ETOT) {
                int s, d;
                if (e < NEDGE) {
                    d = isi32 ? (int)u[NEDGE + e] : (int)u[2 * NEDGE + 2 * e];
                } else {
                    d = e - NEDGE;
                }
                if ((d & 7) == residue) {
                    if (e < NEDGE) s = isi32 ? (int)u[e] : (int)u[2 * e];
                    else s = d;
                    int pos = atomicAdd(&fill[d], 1);
                    if (pos < ELLCAP) csr16[((size_t)d << 6) + pos] = (unsigned short)s;
                }
            }
        }
        return;
    }
    // ---- gemm role ----
    int gi = w * 8 + (i - 32);
    if (gi >= SG_GEMM) return;
    int wave = t >> 6, lane = t & 63;
    int mbase = gi * 64 + wave * 16;
    int rowc = min(mbase + (lane & 15), NODES - 1);
    int kg = lane >> 4;              // 0..3
    const float4* xr = (const float4*)(x + (size_t)rowc * NF + kg * 8);

    // issue the full K-strip loads (16 independent dwordx4 in flight)
    float4 xa[16];
#pragma unroll
    for (int ks = 0; ks < 8; ++ks) {
        xa[2 * ks]     = xr[ks * 8];
        xa[2 * ks + 1] = xr[ks * 8 + 1];
    }
    __builtin_amdgcn_sched_barrier(0);   // pin x loads before staging

    f32x4 acc[9];
#pragma unroll
    for (int f = 0; f < 9; ++f) acc[f] = (f32x4){0.f, 0.f, 0.f, 0.f};

    int r = lane & 15;
    int swz = r & 7;
    int rb = r * 16 + kg;                // uint4 idx base in [row][16] half-layout

    // two K-halves: stage 36KB, run 4 MFMA steps, repeat
#pragma unroll
    for (int half = 0; half < 2; ++half) {
        if (half) __syncthreads();       // all reads of previous half done
#pragma unroll
        for (int it = 0; it < 9; ++it) {
            int idx = it * 256 + t;      // 0..2303
            wlds[idx ^ ((idx >> 4) & 7)] =
                ((const uint4*)W1t)[(idx >> 4) * 32 + half * 16 + (idx & 15)];
        }
        __syncthreads();
#pragma unroll
        for (int ks = 0; ks < 4; ++ks) {
            union { uint4 u4; bf16x8 v; } A;
            float4 a0 = xa[2 * (half * 4 + ks)], a1 = xa[2 * (half * 4 + ks) + 1];
            A.u4.x = pk2(a0.x, a0.y); A.u4.y = pk2(a0.z, a0.w);
            A.u4.z = pk2(a1.x, a1.y); A.u4.w = pk2(a1.z, a1.w);
#pragma unroll
            for (int f = 0; f < 9; ++f) {
                union { uint4 u4; bf16x8 v; } B;
                B.u4 = wlds[(f * 256 + rb + ks * 4) ^ swz];
                acc[f] = __builtin_amdgcn_mfma_f32_16x16x32_bf16(A.v, B.v, acc[f], 0, 0, 0);
            }
        }
    }

    // store: C/D layout col=lane&15, row=(lane>>4)*4+reg; h1 as fp8 e4m3
    int col = lane & 15;
    int rbase = mbase + (lane >> 4) * 4;
#pragma unroll
    for (int f = 0; f < 8; ++f) {
        int wv = 0;
        wv = __builtin_amdgcn_cvt_pk_fp8_f32(acc[f][0], acc[f][1], wv, false);
        wv = __builtin_amdgcn_cvt_pk_fp8_f32(acc[f][2], acc[f][3], wv, true);
#pragma unroll
        for (int ii = 0; ii < 4; ++ii) {
            int rr = rbase + ii;
            if (rr < NODES)
                h1f8[(size_t)rr * F1 + f * 16 + col] = (unsigned char)((wv >> (8 * ii)) & 0xff);
        }
    }
#pragma unroll
    for (int ii = 0; ii < 4; ++ii) {
        int rr = rbase + ii;
        if (rr < NODES) {
            float v = acc[8][ii];
            if (col < 8) as1[(size_t)rr * NHEAD + col] = v;
            else ad1[(size_t)rr * NHEAD + (col - 8)] = v;
        }
    }
}

// no-max softmax step, fp8 h-row (8 channels per lane)
#define PROC8F8(AV, HV)                                          \
    {                                                            \
        float l = (AV) + adv;                                    \
        l = l > 0.f ? l : 0.2f * l;                              \
        float p = __expf(l);                                     \
        den += p;                                                \
        f32x2 c0 = __builtin_amdgcn_cvt_pk_f32_fp8(HV.x, false); \
        f32x2 c1 = __builtin_amdgcn_cvt_pk_f32_fp8(HV.x, true);  \
        f32x2 c2 = __builtin_amdgcn_cvt_pk_f32_fp8(HV.y, false); \
        f32x2 c3 = __builtin_amdgcn_cvt_pk_f32_fp8(HV.y, true);  \
        acc[0] += p * c0.x; acc[1] += p * c0.y;                  \
        acc[2] += p * c1.x; acc[3] += p * c1.y;                  \
        acc[4] += p * c2.x; acc[5] += p * c2.y;                  \
        acc[6] += p * c3.x; acc[7] += p * c3.y;                  \
    }

// no-max softmax step, bf16 h-row (8 channels per lane)
#define PROC8(AV, HV)                                    \
    {                                                    \
        float l = (AV) + adv;                            \
        l = l > 0.f ? l : 0.2f * l;                      \
        float p = __expf(l);                             \
        den += p;                                        \
        acc[0] += p * bflo(HV.x); acc[1] += p * bfhi(HV.x); \
        acc[2] += p * bflo(HV.y); acc[3] += p * bfhi(HV.y); \
        acc[4] += p * bflo(HV.z); acc[5] += p * bfhi(HV.z); \
        acc[6] += p * bflo(HV.w); acc[7] += p * bfhi(HV.w); \
    }

// ---------- L1 gather + fused GEMM2: block owns 16 dst (M=16 tile) ----------
__global__ __launch_bounds__(256) void msg1g2(const int* __restrict__ fill,
                                              const unsigned short* __restrict__ csr16,
                                              const float* __restrict__ as1,
                                              const float* __restrict__ ad1,
                                              const unsigned char* __restrict__ h1f8,
                                              const float* __restrict__ b1,
                                              const unsigned short* __restrict__ W2e,
                                              unsigned short* __restrict__ h2b,
                                              float* __restrict__ as2,
                                              float* __restrict__ ad2) {
    __shared__ uint4 w2s[768];           // 48 x 16 uint4 = 12 KB, swizzled
    __shared__ uint4 o1s[256];           // 16 rows x 16 uint4 = 4 KB, swizzled
    int t = threadIdx.x;
    int wid = t >> 6, lane = t & 63;
    int g = lane >> 4;                    // group 0..3 -> own dst
    int cl = lane & 15;                   // channel lane: ch 8*cl..8*cl+7
    int h = cl >> 1;                      // head

    // stage W2e (swizzled identically to gemm2m)
#pragma unroll
    for (int it = 0; it < 3; ++it) {
        int i = it * 256 + t;
        w2s[i ^ ((i >> 4) & 7)] = ((const uint4*)W2e)[i];
    }

    int d = blockIdx.x * 16 + wid * 4 + g;   // grid exact: 3125*16 = 50000
    float adv = ad1[(size_t)d * NHEAD + h];
    int deg = fill[d];                        // >= 1 (self loop)
    size_t eb = (size_t)d << 6;               // ELL row base
    float den = 0.f;
    float acc[8];
#pragma unroll
    for (int k = 0; k < 8; ++k) acc[k] = 0.f;

    const char* as1c = (const char*)as1;
    unsigned hoff = (unsigned)(h << 2);
    unsigned coff = (unsigned)(cl << 3);

// internal index j_ avoids shadowing the caller's loop variable (R11 bug)
#define LD1(J, AV, HV)                                                \
    {                                                                 \
        int j_ = (J);                                                 \
        AV = -1e30f; HV = make_uint2(0u, 0u);                         \
        if (j_ < deg) {                                               \
            unsigned ss = (unsigned)csr16[eb + j_];                   \
            AV = *(const float*)(as1c + (ss << 5) + hoff);            \
            HV = *(const uint2*)(h1f8 + (ss << 7) + coff);            \
        }                                                             \
    }

    float av0, av1; uint2 hv0, hv1;
    LD1(0, av0, hv0);
    LD1(1, av1, hv1);
    for (int j = 0; j < deg; j += 2) {
        float ta, tb; uint2 ua, ub;
        LD1(j + 2, ta, ua);
        LD1(j + 3, tb, ub);
        PROC8F8(av0, hv0);
        PROC8F8(av1, hv1);
        av0 = ta; hv0 = ua; av1 = tb; hv1 = ub;
    }
#undef LD1

    float invd = 1.f / (den + 1e-16f);
    const float4* bp = (const float4*)(b1 + cl * 8);
    float4 ba = bp[0], bb = bp[1];
    float v[8];
    v[0] = acc[0] * invd + ba.x; v[1] = acc[1] * invd + ba.y;
    v[2] = acc[2] * invd + ba.z; v[3] = acc[3] * invd + ba.w;
    v[4] = acc[4] * invd + bb.x; v[5] = acc[5] * invd + bb.y;
    v[6] = acc[6] * invd + bb.z; v[7] = acc[7] * invd + bb.w;
#pragma unroll
    for (int k = 0; k < 8; ++k) {
        float ev = __expf(v[k]) - 1.f;          // ELU negative branch
        v[k] = v[k] > 0.f ? v[k] : ev;
    }
    uint4 o;
    o.x = pk2(v[0], v[1]); o.y = pk2(v[2], v[3]);
    o.z = pk2(v[4], v[5]); o.w = pk2(v[6], v[7]);
    int orow = wid * 4 + g;
    o1s[(orow * 16 + cl) ^ (orow & 7)] = o;
    __syncthreads();

    // Phase 2: GEMM tile f = wid (waves 0..2), M=16 block dst, N=16, K=128
    if (wid < 3) {
        int r = lane & 15;
        int kg = lane >> 4;
        int swz = r & 7;
        f32x4 c2 = (f32x4){0.f, 0.f, 0.f, 0.f};
#pragma unroll
        for (int ks = 0; ks < 4; ++ks) {
            union { uint4 u; bf16x8 vv; } A, B;
            A.u = o1s[(r * 16 + kg + ks * 4) ^ swz];
            B.u = w2s[(wid * 256 + r * 16 + kg + ks * 4) ^ swz];
            c2 = __builtin_amdgcn_mfma_f32_16x16x32_bf16(A.vv, B.vv, c2, 0, 0, 0);
        }
        int col = lane & 15;
        int rbase = blockIdx.x * 16 + (lane >> 4) * 4;
        if (wid < 2) {
#pragma unroll
            for (int i = 0; i < 4; ++i)
                h2b[(size_t)(rbase + i) * NC + wid * 16 + col] = f2bf(c2[i]);
        } else {
            int c = 32 + col;
#pragma unroll
            for (int i = 0; i < 4; ++i) {
                int rr = rbase + i;
                if (c < NC) h2b[(size_t)rr * NC + c] = f2bf(c2[i]);
                else if (c == NC) as2[rr] = c2[i];
                else if (c == NC + 1) ad2[rr] = c2[i];
            }
        }
    }
}

// ---------- L2 gather: 8-lane group per dst (8 dst/wave), ELL, depth-2 ----------
__global__ __launch_bounds__(256) void msg2(const int* __restrict__ fill,
                                            const unsigned short* __restrict__ csr16,
                                            const float* __restrict__ as2,
                                            const float* __restrict__ ad2,
                                            const unsigned short* __restrict__ h2b,
                                            const float* __restrict__ b2,
                                            float* __restrict__ out) {
    int t = threadIdx.x;
    int wid = t >> 6, lane = t & 63;
    int g = lane >> 3;                    // group 0..7 -> own dst
    int cl = lane & 7;                    // channel lane; active cl<5 (8 ch each)
    int clc = cl < 5 ? cl : 4;
    bool act = cl < 5;
    int d0 = blockIdx.x * 32 + wid * 8 + g;
    int d = min(d0, NODES - 1);
    float adv = ad2[d];
    int deg = act ? fill[d] : 0;          // inactive lanes: no loads, no loop
    size_t eb = (size_t)d << 6;
    float den = 0.f;
    float acc[8];
#pragma unroll
    for (int k = 0; k < 8; ++k) acc[k] = 0.f;

    const char* as2c = (const char*)as2;
    const char* h2c = (const char*)h2b;
    unsigned coff = (unsigned)(clc << 4);

#define LD2(J, AV, HV)                                                \
    {                                                                 \
        int j_ = (J);                                                 \
        AV = -1e30f; HV = make_uint4(0u, 0u, 0u, 0u);                 \
        if (j_ < deg) {                                               \
            unsigned ss = (unsigned)csr16[eb + j_];                   \
            AV = *(const float*)(as2c + (ss << 2));                   \
            HV = *(const uint4*)(h2c + ss * 80u + coff);              \
        }                                                             \
    }

    float av0, av1; uint4 hv0, hv1;
    LD2(0, av0, hv0);
    LD2(1, av1, hv1);
    for (int j = 0; j < deg; j += 2) {
        float ta, tb; uint4 ua, ub;
        LD2(j + 2, ta, ua);
        LD2(j + 3, tb, ub);
        PROC8(av0, hv0);
        PROC8(av1, hv1);
        av0 = ta; hv0 = ua; av1 = tb; hv1 = ub;
    }
#undef LD2

    float invd = 1.f / (den + 1e-16f);
    float v[8];
    float mk = -1e30f;
    if (act) {
        const float4* bp = (const float4*)(b2 + cl * 8);
        float4 ba = bp[0], bb = bp[1];
        v[0] = acc[0] * invd + ba.x; v[1] = acc[1] * invd + ba.y;
        v[2] = acc[2] * invd + ba.z; v[3] = acc[3] * invd + ba.w;
        v[4] = acc[4] * invd + bb.x; v[5] = acc[5] * invd + bb.y;
        v[6] = acc[6] * invd + bb.z; v[7] = acc[7] * invd + bb.w;
#pragma unroll
        for (int k = 0; k < 8; ++k) mk = fmaxf(mk, v[k]);
    }
    // reduce within the 8-lane group
    mk = fmaxf(mk, __shfl_xor(mk, 1, 64));
    mk = fmaxf(mk, __shfl_xor(mk, 2, 64));
    mk = fmaxf(mk, __shfl_xor(mk, 4, 64));
    float e = 0.f;
    if (act) {
#pragma unroll
        for (int k = 0; k < 8; ++k) e += __expf(v[k] - mk);
    }
    e += __shfl_xor(e, 1, 64);
    e += __shfl_xor(e, 2, 64);
    e += __shfl_xor(e, 4, 64);
    float lse = mk + logf(e);
    if (act && d0 < NODES) {
        float4 o0 = make_float4(v[0] - lse, v[1] - lse, v[2] - lse, v[3] - lse);
        float4 o1 = make_float4(v[4] - lse, v[5] - lse, v[6] - lse, v[7] - lse);
        float* po = out + (size_t)d0 * NC + cl * 8;
        *(float4*)po = o0;
        *(float4*)(po + 4) = o1;
    }
}

extern "C" void kernel_launch(void* const* d_in, const int* in_sizes, int n_in,
                              void* d_out, int out_size, void* d_ws, size_t ws_size,
                              hipStream_t stream) {
    const float* x       = (const float*)d_in[0];
    const unsigned* eidx = (const unsigned*)d_in[1];
    const float* W1      = (const float*)d_in[2];
    const float* atts1   = (const float*)d_in[3];
    const float* attd1   = (const float*)d_in[4];
    const float* b1      = (const float*)d_in[5];
    const float* W2      = (const float*)d_in[6];
    const float* atts2   = (const float*)d_in[7];
    const float* attd2   = (const float*)d_in[8];
    const float* b2      = (const float*)d_in[9];
    float* out = (float*)d_out;

    char* base = (char*)d_ws;
    size_t off = 0;
    auto takeB = [&](size_t bytes) {
        void* p = base + off;
        off = (off + bytes + 255) & ~(size_t)255;
        return p;
    };
    unsigned* flag = (unsigned*)takeB(256);
    int* fill      = (int*)takeB((size_t)NODES * 4);
    unsigned short* csr16 = (unsigned short*)takeB((size_t)NODES * ELLCAP * 2 + 256);
    unsigned short* W1t  = (unsigned short*)takeB((size_t)144 * NF * 2);
    unsigned short* W2e  = (unsigned short*)takeB((size_t)48 * F1 * 2);
    unsigned char* h1f8  = (unsigned char*)takeB((size_t)NODES * F1);
    float* as1     = (float*)takeB((size_t)NODES * NHEAD * 4);
    float* ad1     = (float*)takeB((size_t)NODES * NHEAD * 4);
    unsigned short* h2b  = (unsigned short*)takeB((size_t)NODES * NC * 2 + 256);
    float* as2     = (float*)takeB((size_t)NODES * 4);
    float* ad2     = (float*)takeB((size_t)NODES * 4);

    hipMemsetAsync(flag, 0, 4, stream);
    hipMemsetAsync(fill, 0, (size_t)NODES * 4, stream);

    detect_k<<<1, 256, 0, stream>>>(eidx, flag);

    // weight prep (both layers, one dispatch)
    prepW12<<<192, 256, 0, stream>>>(W1, atts1, attd1, W2, atts2, attd2, W1t, W2e);

    // fused: XCD-affine ELL scatter + layer-1 MFMA GEMM (fp8 h1 out)
    scatter_gemm1<<<SG_BLOCKS, 256, 0, stream>>>(eidx, flag, fill, csr16,
                                                 x, W1t, h1f8, as1, ad1);

    // Layer-1 gather + fused layer-2 projection (out1 stays on-chip)
    msg1g2<<<NODES / 16, 256, 0, stream>>>(fill, csr16, as1, ad1, h1f8, b1,
                                           W2e, h2b, as2, ad2);

    // Layer-2 gather + log_softmax
    msg2<<<(NODES + 31) / 32, 256, 0, stream>>>(fill, csr16, as2, ad2, h2b, b2, out);
}

// Round 20
// 120.390 us; speedup vs baseline: 2.1283x; 1.0341x over previous
//
#include <hip/hip_runtime.h>
#include <math.h>

#define NODES 50000
#define NEDGE 800000
#define ETOT  (NEDGE + NODES)   // edges + self loops = 850000
#define NF    256
#define F1    128               // HEADS*NHID
#define NHEAD 8
#define NHID  16
#define NC    40
#define ELLCAP 64               // slots per dst; P(deg>63) ~ 1e-17 for Poisson(16)
// fused scatter+gemm1 grid: 3321 scatter blocks + 782 gemm blocks, 4:1 interleave
#define SG_BLOCKS 4103
#define SG_GEMMCUT 3910         // 782*5; gemm role at bid%5==4 below this

typedef __attribute__((ext_vector_type(8))) short bf16x8;
typedef __attribute__((ext_vector_type(4))) float f32x4;
typedef __attribute__((ext_vector_type(2))) float f32x2;

__device__ __forceinline__ float bflo(unsigned u) { return __uint_as_float(u << 16); }
__device__ __forceinline__ float bfhi(unsigned u) { return __uint_as_float(u & 0xffff0000u); }
__device__ __forceinline__ unsigned short f2bf(float f) {
    unsigned u = __float_as_uint(f);
    unsigned r = u + 0x7fffu + ((u >> 16) & 1u);   // RNE
    return (unsigned short)(r >> 16);
}
__device__ __forceinline__ unsigned pk2(float a, float b) {
    return (unsigned)f2bf(a) | ((unsigned)f2bf(b) << 16);
}
__device__ __forceinline__ unsigned char f2fp8(float v) {
    return (unsigned char)(__builtin_amdgcn_cvt_pk_fp8_f32(v, v, 0, false) & 0xff);
}

// ---------- edge index dtype detect ----------
__global__ void detect_k(const unsigned* __restrict__ u, unsigned* __restrict__ flag) {
    int t = threadIdx.x;              // 256 threads
    if (u[2 * t + 1] != 0u) atomicOr(flag, 1u);   // nonzero hi-word pattern => int32 data
}

// ---------- prep (merged): W1t144[144][256] + W2e[48][128], both bf16 ----------
__global__ void prepW12(const float* __restrict__ W1, const float* __restrict__ atts1,
                        const float* __restrict__ attd1,
                        const float* __restrict__ W2, const float* __restrict__ atts2,
                        const float* __restrict__ attd2,
                        unsigned short* __restrict__ W1t, unsigned short* __restrict__ W2e) {
    int b = blockIdx.x;
    int k = threadIdx.x;
    if (b < 144) {
        int n = b;            // 0..143, k 0..255
        float v;
        if (n < 128) {
            v = W1[(size_t)k * F1 + n];
        } else if (n < 136) {
            int h = n - 128; v = 0.f;
#pragma unroll
            for (int c = 0; c < 16; ++c) v += W1[(size_t)k * F1 + h * 16 + c] * atts1[h * 16 + c];
        } else {
            int h = n - 136; v = 0.f;
#pragma unroll
            for (int c = 0; c < 16; ++c) v += W1[(size_t)k * F1 + h * 16 + c] * attd1[h * 16 + c];
        }
        W1t[(size_t)n * NF + k] = f2bf(v);
    } else {
        int n = b - 144;      // 0..47, k valid 0..127
        if (k >= F1) return;
        float v = 0.f;
        if (n < NC) {
            v = W2[(size_t)k * NC + n];
        } else if (n == NC) {
#pragma unroll
            for (int c = 0; c < NC; ++c) v += W2[(size_t)k * NC + c] * atts2[c];
        } else if (n == NC + 1) {
#pragma unroll
            for (int c = 0; c < NC; ++c) v += W2[(size_t)k * NC + c] * attd2[c];
        }
        W2e[(size_t)n * F1 + k] = f2bf(v);
    }
}

// ---------- FUSED: ELL scatter + MFMA GEMM1 split-K LDS (fp8 h1) ----------
__global__ __launch_bounds__(256) void scatter_gemm1(
        const unsigned* __restrict__ u, const unsigned* __restrict__ flag,
        int* __restrict__ fill, unsigned short* __restrict__ csr16,
        const float* __restrict__ x, const unsigned short* __restrict__ W1t,
        unsigned char* __restrict__ h1f8, float* __restrict__ as1,
        float* __restrict__ ad1) {
    __shared__ uint4 wlds[2304];         // 144 rows x 16 uint4 = 36864 B
    int bid = blockIdx.x;
    int t = threadIdx.x;
    bool isGemm = (bid < SG_GEMMCUT) && ((bid % 5) == 4);
    if (!isGemm) {
        // ---- scatter role: 1 edge per thread, 2B ELL stores ----
        int si = bid - min(bid, SG_GEMMCUT) / 5;   // gemm blocks before bid
        int e = si * 256 + t;
        if (e >= ETOT) return;
        int s, d;
        if (e < NEDGE) {
            if (*flag) { s = (int)u[e]; d = (int)u[NEDGE + e]; }
            else       { s = (int)u[2 * e]; d = (int)u[2 * NEDGE + 2 * e]; }
        } else s = d = e - NEDGE;
        int pos = atomicAdd(&fill[d], 1);
        if (pos < ELLCAP) csr16[((size_t)d << 6) + pos] = (unsigned short)s;
        return;
    }
    // ---- gemm role ----
    int gi = bid / 5;
    int wave = t >> 6, lane = t & 63;
    int mbase = gi * 64 + wave * 16;
    int rowc = min(mbase + (lane & 15), NODES - 1);
    int kg = lane >> 4;              // 0..3
    const float4* xr = (const float4*)(x + (size_t)rowc * NF + kg * 8);

    // issue the full K-strip loads (16 independent dwordx4 in flight)
    float4 xa[16];
#pragma unroll
    for (int ks = 0; ks < 8; ++ks) {
        xa[2 * ks]     = xr[ks * 8];
        xa[2 * ks + 1] = xr[ks * 8 + 1];
    }
    __builtin_amdgcn_sched_barrier(0);   // pin x loads before staging

    f32x4 acc[9];
#pragma unroll
    for (int f = 0; f < 9; ++f) acc[f] = (f32x4){0.f, 0.f, 0.f, 0.f};

    int r = lane & 15;
    int swz = r & 7;
    int rb = r * 16 + kg;                // uint4 idx base in [row][16] half-layout

    // two K-halves: stage 36KB, run 4 MFMA steps, repeat
#pragma unroll
    for (int half = 0; half < 2; ++half) {
        if (half) __syncthreads();       // all reads of previous half done
#pragma unroll
        for (int it = 0; it < 9; ++it) {
            int idx = it * 256 + t;      // 0..2303
            wlds[idx ^ ((idx >> 4) & 7)] =
                ((const uint4*)W1t)[(idx >> 4) * 32 + half * 16 + (idx & 15)];
        }
        __syncthreads();
#pragma unroll
        for (int ks = 0; ks < 4; ++ks) {
            union { uint4 u4; bf16x8 v; } A;
            float4 a0 = xa[2 * (half * 4 + ks)], a1 = xa[2 * (half * 4 + ks) + 1];
            A.u4.x = pk2(a0.x, a0.y); A.u4.y = pk2(a0.z, a0.w);
            A.u4.z = pk2(a1.x, a1.y); A.u4.w = pk2(a1.z, a1.w);
#pragma unroll
            for (int f = 0; f < 9; ++f) {
                union { uint4 u4; bf16x8 v; } B;
                B.u4 = wlds[(f * 256 + rb + ks * 4) ^ swz];
                acc[f] = __builtin_amdgcn_mfma_f32_16x16x32_bf16(A.v, B.v, acc[f], 0, 0, 0);
            }
        }
    }

    // store: C/D layout col=lane&15, row=(lane>>4)*4+reg; h1 as fp8 e4m3
    int col = lane & 15;
    int rbase = mbase + (lane >> 4) * 4;
#pragma unroll
    for (int f = 0; f < 8; ++f) {
        int wv = 0;
        wv = __builtin_amdgcn_cvt_pk_fp8_f32(acc[f][0], acc[f][1], wv, false);
        wv = __builtin_amdgcn_cvt_pk_fp8_f32(acc[f][2], acc[f][3], wv, true);
#pragma unroll
        for (int ii = 0; ii < 4; ++ii) {
            int rr = rbase + ii;
            if (rr < NODES)
                h1f8[(size_t)rr * F1 + f * 16 + col] = (unsigned char)((wv >> (8 * ii)) & 0xff);
        }
    }
#pragma unroll
    for (int ii = 0; ii < 4; ++ii) {
        int rr = rbase + ii;
        if (rr < NODES) {
            float v = acc[8][ii];
            if (col < 8) as1[(size_t)rr * NHEAD + col] = v;
            else ad1[(size_t)rr * NHEAD + (col - 8)] = v;
        }
    }
}

// no-max softmax step, fp8 h-row (8 channels per lane)
#define PROC8F8(AV, HV)                                          \
    {                                                            \
        float l = (AV) + adv;                                    \
        l = l > 0.f ? l : 0.2f * l;                              \
        float p = __expf(l);                                     \
        den += p;                                                \
        f32x2 c0 = __builtin_amdgcn_cvt_pk_f32_fp8(HV.x, false); \
        f32x2 c1 = __builtin_amdgcn_cvt_pk_f32_fp8(HV.x, true);  \
        f32x2 c2 = __builtin_amdgcn_cvt_pk_f32_fp8(HV.y, false); \
        f32x2 c3 = __builtin_amdgcn_cvt_pk_f32_fp8(HV.y, true);  \
        acc[0] += p * c0.x; acc[1] += p * c0.y;                  \
        acc[2] += p * c1.x; acc[3] += p * c1.y;                  \
        acc[4] += p * c2.x; acc[5] += p * c2.y;                  \
        acc[6] += p * c3.x; acc[7] += p * c3.y;                  \
    }

// ---------- L1 gather + fused GEMM2: block owns 16 dst (M=16 tile) ----------
// Phase 1: each 16-lane group gathers one dst row (fp8 h1, ELL edges), applies
// softmax-normalize + bias + ELU, writes the bf16 row into swizzled LDS.
// Phase 2: waves 0..2 run the 16x48x128 MFMA tile (W2e staged in LDS),
// producing fp8 h2 plus the fused as2/ad2 columns. out1 never touches HBM.
__global__ __launch_bounds__(256) void msg1g2(const int* __restrict__ fill,
                                              const unsigned short* __restrict__ csr16,
                                              const float* __restrict__ as1,
                                              const float* __restrict__ ad1,
                                              const unsigned char* __restrict__ h1f8,
                                              const float* __restrict__ b1,
                                              const unsigned short* __restrict__ W2e,
                                              unsigned char* __restrict__ h2f8,
                                              float* __restrict__ as2,
                                              float* __restrict__ ad2) {
    __shared__ uint4 w2s[768];           // 48 x 16 uint4 = 12 KB, swizzled
    __shared__ uint4 o1s[256];           // 16 rows x 16 uint4 = 4 KB, swizzled
    int t = threadIdx.x;
    int wid = t >> 6, lane = t & 63;
    int g = lane >> 4;                    // group 0..3 -> own dst
    int cl = lane & 15;                   // channel lane: ch 8*cl..8*cl+7
    int h = cl >> 1;                      // head

    // stage W2e (swizzled identically to gemm2m)
#pragma unroll
    for (int it = 0; it < 3; ++it) {
        int i = it * 256 + t;
        w2s[i ^ ((i >> 4) & 7)] = ((const uint4*)W2e)[i];
    }

    int d = blockIdx.x * 16 + wid * 4 + g;   // grid exact: 3125*16 = 50000
    float adv = ad1[(size_t)d * NHEAD + h];
    int deg = fill[d];                        // >= 1 (self loop)
    size_t eb = (size_t)d << 6;               // ELL row base
    float den = 0.f;
    float acc[8];
#pragma unroll
    for (int k = 0; k < 8; ++k) acc[k] = 0.f;

    const char* as1c = (const char*)as1;
    unsigned hoff = (unsigned)(h << 2);
    unsigned coff = (unsigned)(cl << 3);

// internal index j_ avoids shadowing the caller's loop variable (R11 bug)
#define LD1(J, AV, HV)                                                \
    {                                                                 \
        int j_ = (J);                                                 \
        AV = -1e30f; HV = make_uint2(0u, 0u);                         \
        if (j_ < deg) {                                               \
            unsigned ss = (unsigned)csr16[eb + j_];                   \
            AV = *(const float*)(as1c + (ss << 5) + hoff);            \
            HV = *(const uint2*)(h1f8 + (ss << 7) + coff);            \
        }                                                             \
    }

    float av0, av1; uint2 hv0, hv1;
    LD1(0, av0, hv0);
    LD1(1, av1, hv1);
    for (int j = 0; j < deg; j += 2) {
        float ta, tb; uint2 ua, ub;
        LD1(j + 2, ta, ua);
        LD1(j + 3, tb, ub);
        PROC8F8(av0, hv0);
        PROC8F8(av1, hv1);
        av0 = ta; hv0 = ua; av1 = tb; hv1 = ub;
    }
#undef LD1

    float invd = 1.f / (den + 1e-16f);
    const float4* bp = (const float4*)(b1 + cl * 8);
    float4 ba = bp[0], bb = bp[1];
    float v[8];
    v[0] = acc[0] * invd + ba.x; v[1] = acc[1] * invd + ba.y;
    v[2] = acc[2] * invd + ba.z; v[3] = acc[3] * invd + ba.w;
    v[4] = acc[4] * invd + bb.x; v[5] = acc[5] * invd + bb.y;
    v[6] = acc[6] * invd + bb.z; v[7] = acc[7] * invd + bb.w;
#pragma unroll
    for (int k = 0; k < 8; ++k) {
        float ev = __expf(v[k]) - 1.f;          // ELU negative branch
        v[k] = v[k] > 0.f ? v[k] : ev;
    }
    uint4 o;
    o.x = pk2(v[0], v[1]); o.y = pk2(v[2], v[3]);
    o.z = pk2(v[4], v[5]); o.w = pk2(v[6], v[7]);
    int orow = wid * 4 + g;
    o1s[(orow * 16 + cl) ^ (orow & 7)] = o;
    __syncthreads();

    // Phase 2: GEMM tile f = wid (waves 0..2), M=16 block dst, N=16, K=128
    if (wid < 3) {
        int r = lane & 15;
        int kg = lane >> 4;
        int swz = r & 7;
        f32x4 c2 = (f32x4){0.f, 0.f, 0.f, 0.f};
#pragma unroll
        for (int ks = 0; ks < 4; ++ks) {
            union { uint4 u; bf16x8 vv; } A, B;
            A.u = o1s[(r * 16 + kg + ks * 4) ^ swz];
            B.u = w2s[(wid * 256 + r * 16 + kg + ks * 4) ^ swz];
            c2 = __builtin_amdgcn_mfma_f32_16x16x32_bf16(A.vv, B.vv, c2, 0, 0, 0);
        }
        int col = lane & 15;
        int rbase = blockIdx.x * 16 + (lane >> 4) * 4;
        if (wid < 2) {
#pragma unroll
            for (int i = 0; i < 4; ++i)
                h2f8[(size_t)(rbase + i) * NC + wid * 16 + col] = f2fp8(c2[i]);
        } else {
            int c = 32 + col;
#pragma unroll
            for (int i = 0; i < 4; ++i) {
                int rr = rbase + i;
                if (c < NC) h2f8[(size_t)rr * NC + c] = f2fp8(c2[i]);
                else if (c == NC) as2[rr] = c2[i];
                else if (c == NC + 1) ad2[rr] = c2[i];
            }
        }
    }
}

// ---------- L2 gather: 8-lane group per dst (8 dst/wave), ELL, fp8 h2, depth-2 ----------
__global__ __launch_bounds__(256) void msg2(const int* __restrict__ fill,
                                            const unsigned short* __restrict__ csr16,
                                            const float* __restrict__ as2,
                                            const float* __restrict__ ad2,
                                            const unsigned char* __restrict__ h2f8,
                                            const float* __restrict__ b2,
                                            float* __restrict__ out) {
    int t = threadIdx.x;
    int wid = t >> 6, lane = t & 63;
    int g = lane >> 3;                    // group 0..7 -> own dst
    int cl = lane & 7;                    // channel lane; active cl<5 (8 ch each)
    int clc = cl < 5 ? cl : 4;
    bool act = cl < 5;
    int d0 = blockIdx.x * 32 + wid * 8 + g;
    int d = min(d0, NODES - 1);
    float adv = ad2[d];
    int deg = act ? fill[d] : 0;          // inactive lanes: no loads, no loop
    size_t eb = (size_t)d << 6;
    float den = 0.f;
    float acc[8];
#pragma unroll
    for (int k = 0; k < 8; ++k) acc[k] = 0.f;

    const char* as2c = (const char*)as2;
    unsigned coff = (unsigned)(clc << 3);

#define LD2(J, AV, HV)                                                \
    {                                                                 \
        int j_ = (J);                                                 \
        AV = -1e30f; HV = make_uint2(0u, 0u);                         \
        if (j_ < deg) {                                               \
            unsigned ss = (unsigned)csr16[eb + j_];                   \
            AV = *(const float*)(as2c + (ss << 2));                   \
            HV = *(const uint2*)(h2f8 + ss * 40u + coff);             \
        }                                                             \
    }

    float av0, av1; uint2 hv0, hv1;
    LD2(0, av0, hv0);
    LD2(1, av1, hv1);
    for (int j = 0; j < deg; j += 2) {
        float ta, tb; uint2 ua, ub;
        LD2(j + 2, ta, ua);
        LD2(j + 3, tb, ub);
        PROC8F8(av0, hv0);
        PROC8F8(av1, hv1);
        av0 = ta; hv0 = ua; av1 = tb; hv1 = ub;
    }
#undef LD2

    float invd = 1.f / (den + 1e-16f);
    float v[8];
    float mk = -1e30f;
    if (act) {
        const float4* bp = (const float4*)(b2 + cl * 8);
        float4 ba = bp[0], bb = bp[1];
        v[0] = acc[0] * invd + ba.x; v[1] = acc[1] * invd + ba.y;
        v[2] = acc[2] * invd + ba.z; v[3] = acc[3] * invd + ba.w;
        v[4] = acc[4] * invd + bb.x; v[5] = acc[5] * invd + bb.y;
        v[6] = acc[6] * invd + bb.z; v[7] = acc[7] * invd + bb.w;
#pragma unroll
        for (int k = 0; k < 8; ++k) mk = fmaxf(mk, v[k]);
    }
    // reduce within the 8-lane group
    mk = fmaxf(mk, __shfl_xor(mk, 1, 64));
    mk = fmaxf(mk, __shfl_xor(mk, 2, 64));
    mk = fmaxf(mk, __shfl_xor(mk, 4, 64));
    float e = 0.f;
    if (act) {
#pragma unroll
        for (int k = 0; k < 8; ++k) e += __expf(v[k] - mk);
    }
    e += __shfl_xor(e, 1, 64);
    e += __shfl_xor(e, 2, 64);
    e += __shfl_xor(e, 4, 64);
    float lse = mk + logf(e);
    if (act && d0 < NODES) {
        float4 o0 = make_float4(v[0] - lse, v[1] - lse, v[2] - lse, v[3] - lse);
        float4 o1 = make_float4(v[4] - lse, v[5] - lse, v[6] - lse, v[7] - lse);
        float* po = out + (size_t)d0 * NC + cl * 8;
        *(float4*)po = o0;
        *(float4*)(po + 4) = o1;
    }
}

extern "C" void kernel_launch(void* const* d_in, const int* in_sizes, int n_in,
                              void* d_out, int out_size, void* d_ws, size_t ws_size,
                              hipStream_t stream) {
    const float* x       = (const float*)d_in[0];
    const unsigned* eidx = (const unsigned*)d_in[1];
    const float* W1      = (const float*)d_in[2];
    const float* atts1   = (const float*)d_in[3];
    const float* attd1   = (const float*)d_in[4];
    const float* b1      = (const float*)d_in[5];
    const float* W2      = (const float*)d_in[6];
    const float* atts2   = (const float*)d_in[7];
    const float* attd2   = (const float*)d_in[8];
    const float* b2      = (const float*)d_in[9];
    float* out = (float*)d_out;

    char* base = (char*)d_ws;
    size_t off = 0;
    auto takeB = [&](size_t bytes) {
        void* p = base + off;
        off = (off + bytes + 255) & ~(size_t)255;
        return p;
    };
    unsigned* flag = (unsigned*)takeB(256);
    int* fill      = (int*)takeB((size_t)NODES * 4);
    unsigned short* csr16 = (unsigned short*)takeB((size_t)NODES * ELLCAP * 2 + 256);
    unsigned short* W1t  = (unsigned short*)takeB((size_t)144 * NF * 2);
    unsigned short* W2e  = (unsigned short*)takeB((size_t)48 * F1 * 2);
    unsigned char* h1f8  = (unsigned char*)takeB((size_t)NODES * F1);
    float* as1     = (float*)takeB((size_t)NODES * NHEAD * 4);
    float* ad1     = (float*)takeB((size_t)NODES * NHEAD * 4);
    unsigned char* h2f8  = (unsigned char*)takeB((size_t)NODES * NC + 256);
    float* as2     = (float*)takeB((size_t)NODES * 4);
    float* ad2     = (float*)takeB((size_t)NODES * 4);

    hipMemsetAsync(flag, 0, 4, stream);
    hipMemsetAsync(fill, 0, (size_t)NODES * 4, stream);

    detect_k<<<1, 256, 0, stream>>>(eidx, flag);

    // weight prep (both layers, one dispatch)
    prepW12<<<192, 256, 0, stream>>>(W1, atts1, attd1, W2, atts2, attd2, W1t, W2e);

    // fused: ELL scatter + layer-1 MFMA GEMM (fp8 h1 out)
    scatter_gemm1<<<SG_BLOCKS, 256, 0, stream>>>(eidx, flag, fill, csr16,
                                                 x, W1t, h1f8, as1, ad1);

    // Layer-1 gather + fused layer-2 projection (out1 stays on-chip)
    msg1g2<<<NODES / 16, 256, 0, stream>>>(fill, csr16, as1, ad1, h1f8, b1,
                                           W2e, h2f8, as2, ad2);

    // Layer-2 gather + log_softmax
    msg2<<<(NODES + 31) / 32, 256, 0, stream>>>(fill, csr16, as2, ad2, h2f8, b2, out);
}

// Round 21
// 114.853 us; speedup vs baseline: 2.2309x; 1.0482x over previous
//
#include <hip/hip_runtime.h>
#include <math.h>

#define NODES 50000
#define NEDGE 800000
#define ETOT  (NEDGE + NODES)   // edges + self loops = 850000
#define NF    256
#define F1    128               // HEADS*NHID
#define NHEAD 8
#define NHID  16
#define NC    40
#define ELLCAP 64               // slots per dst; P(deg>63) ~ 1e-17 for Poisson(16)
// fused scatter+gemm1 grid: 3321 scatter blocks + 782 gemm blocks, 4:1 interleave
#define SG_BLOCKS 4103
#define SG_GEMMCUT 3910         // 782*5; gemm role at bid%5==4 below this

typedef __attribute__((ext_vector_type(8))) short bf16x8;
typedef __attribute__((ext_vector_type(4))) float f32x4;
typedef __attribute__((ext_vector_type(2))) float f32x2;

__device__ __forceinline__ float bflo(unsigned u) { return __uint_as_float(u << 16); }
__device__ __forceinline__ float bfhi(unsigned u) { return __uint_as_float(u & 0xffff0000u); }
__device__ __forceinline__ unsigned short f2bf(float f) {
    unsigned u = __float_as_uint(f);
    unsigned r = u + 0x7fffu + ((u >> 16) & 1u);   // RNE
    return (unsigned short)(r >> 16);
}
__device__ __forceinline__ unsigned pk2(float a, float b) {
    return (unsigned)f2bf(a) | ((unsigned)f2bf(b) << 16);
}
__device__ __forceinline__ unsigned char f2fp8(float v) {
    return (unsigned char)(__builtin_amdgcn_cvt_pk_fp8_f32(v, v, 0, false) & 0xff);
}

// ---------- prep (merged): W1t144[144][256] + W2e[48][128], both bf16 ----------
__global__ void prepW12(const float* __restrict__ W1, const float* __restrict__ atts1,
                        const float* __restrict__ attd1,
                        const float* __restrict__ W2, const float* __restrict__ atts2,
                        const float* __restrict__ attd2,
                        unsigned short* __restrict__ W1t, unsigned short* __restrict__ W2e) {
    int b = blockIdx.x;
    int k = threadIdx.x;
    if (b < 144) {
        int n = b;            // 0..143, k 0..255
        float v;
        if (n < 128) {
            v = W1[(size_t)k * F1 + n];
        } else if (n < 136) {
            int h = n - 128; v = 0.f;
#pragma unroll
            for (int c = 0; c < 16; ++c) v += W1[(size_t)k * F1 + h * 16 + c] * atts1[h * 16 + c];
        } else {
            int h = n - 136; v = 0.f;
#pragma unroll
            for (int c = 0; c < 16; ++c) v += W1[(size_t)k * F1 + h * 16 + c] * attd1[h * 16 + c];
        }
        W1t[(size_t)n * NF + k] = f2bf(v);
    } else {
        int n = b - 144;      // 0..47, k valid 0..127
        if (k >= F1) return;
        float v = 0.f;
        if (n < NC) {
            v = W2[(size_t)k * NC + n];
        } else if (n == NC) {
#pragma unroll
            for (int c = 0; c < NC; ++c) v += W2[(size_t)k * NC + c] * atts2[c];
        } else if (n == NC + 1) {
#pragma unroll
            for (int c = 0; c < NC; ++c) v += W2[(size_t)k * NC + c] * attd2[c];
        }
        W2e[(size_t)n * F1 + k] = f2bf(v);
    }
}

// ---------- FUSED: ELL scatter (self-detecting dtype) + MFMA GEMM1 ----------
// Gemm role stages W1t in FOUR 18.4KB K-quarters -> static LDS 18432 B ->
// 8 blocks/CU residency for BOTH roles (scatter concurrency doubles vs 36.9KB).
__global__ __launch_bounds__(256) void scatter_gemm1(
        const unsigned* __restrict__ u,
        int* __restrict__ fill, unsigned short* __restrict__ csr16,
        const float* __restrict__ x, const unsigned short* __restrict__ W1t,
        unsigned char* __restrict__ h1f8, float* __restrict__ as1,
        float* __restrict__ ad1) {
    __shared__ uint4 wlds[1152];         // 144 rows x 8 uint4 = 18432 B
    int bid = blockIdx.x;
    int t = threadIdx.x;
    bool isGemm = (bid < SG_GEMMCUT) && ((bid % 5) == 4);
    if (!isGemm) {
        // ---- scatter role: 1 edge per thread, 2B ELL stores ----
        // self-detect edge dtype: int64 data has zero hi-words at odd slots;
        // int32 data has random node ids there (P(all 64 == 0) ~ 0).
        unsigned hw = u[2 * (t & 63) + 1];
        bool isi32 = __ballot(hw != 0) != 0;
        int si = bid - min(bid, SG_GEMMCUT) / 5;   // gemm blocks before bid
        int e = si * 256 + t;
        if (e >= ETOT) return;
        int s, d;
        if (e < NEDGE) {
            if (isi32) { s = (int)u[e]; d = (int)u[NEDGE + e]; }
            else       { s = (int)u[2 * e]; d = (int)u[2 * NEDGE + 2 * e]; }
        } else s = d = e - NEDGE;
        int pos = atomicAdd(&fill[d], 1);
        if (pos < ELLCAP) csr16[((size_t)d << 6) + pos] = (unsigned short)s;
        return;
    }
    // ---- gemm role ----
    int gi = bid / 5;
    int wave = t >> 6, lane = t & 63;
    int mbase = gi * 64 + wave * 16;
    int rowc = min(mbase + (lane & 15), NODES - 1);
    int kg = lane >> 4;              // 0..3
    const float4* xr = (const float4*)(x + (size_t)rowc * NF + kg * 8);

    // issue the full K-strip loads (16 independent dwordx4 in flight)
    float4 xa[16];
#pragma unroll
    for (int ks = 0; ks < 8; ++ks) {
        xa[2 * ks]     = xr[ks * 8];
        xa[2 * ks + 1] = xr[ks * 8 + 1];
    }
    __builtin_amdgcn_sched_barrier(0);   // pin x loads before staging

    f32x4 acc[9];
#pragma unroll
    for (int f = 0; f < 9; ++f) acc[f] = (f32x4){0.f, 0.f, 0.f, 0.f};

    int r = lane & 15;
    int rsw = r & 7;

    // four K-quarters: stage 18.4KB ([144][8] uint4, XOR-swizzled), 2 MFMA steps
#pragma unroll
    for (int q = 0; q < 4; ++q) {
        if (q) __syncthreads();          // all reads of previous quarter done
#pragma unroll
        for (int it = 0; it < 5; ++it) {
            int i = it * 256 + t;
            if (i < 1152) {
                int row = i >> 3, s = i & 7;
                wlds[row * 8 + (s ^ (row & 7))] = ((const uint4*)W1t)[row * 32 + q * 8 + s];
            }
        }
        __syncthreads();
#pragma unroll
        for (int ks2 = 0; ks2 < 2; ++ks2) {
            int ks = q * 2 + ks2;
            union { uint4 u4; bf16x8 v; } A;
            float4 a0 = xa[2 * ks], a1 = xa[2 * ks + 1];
            A.u4.x = pk2(a0.x, a0.y); A.u4.y = pk2(a0.z, a0.w);
            A.u4.z = pk2(a1.x, a1.y); A.u4.w = pk2(a1.z, a1.w);
#pragma unroll
            for (int f = 0; f < 9; ++f) {
                union { uint4 u4; bf16x8 v; } B;
                B.u4 = wlds[f * 128 + r * 8 + ((ks2 * 4 + kg) ^ rsw)];
                acc[f] = __builtin_amdgcn_mfma_f32_16x16x32_bf16(A.v, B.v, acc[f], 0, 0, 0);
            }
        }
    }

    // store: C/D layout col=lane&15, row=(lane>>4)*4+reg; h1 as fp8 e4m3
    int col = lane & 15;
    int rbase = mbase + (lane >> 4) * 4;
#pragma unroll
    for (int f = 0; f < 8; ++f) {
        int wv = 0;
        wv = __builtin_amdgcn_cvt_pk_fp8_f32(acc[f][0], acc[f][1], wv, false);
        wv = __builtin_amdgcn_cvt_pk_fp8_f32(acc[f][2], acc[f][3], wv, true);
#pragma unroll
        for (int ii = 0; ii < 4; ++ii) {
            int rr = rbase + ii;
            if (rr < NODES)
                h1f8[(size_t)rr * F1 + f * 16 + col] = (unsigned char)((wv >> (8 * ii)) & 0xff);
        }
    }
#pragma unroll
    for (int ii = 0; ii < 4; ++ii) {
        int rr = rbase + ii;
        if (rr < NODES) {
            float v = acc[8][ii];
            if (col < 8) as1[(size_t)rr * NHEAD + col] = v;
            else ad1[(size_t)rr * NHEAD + (col - 8)] = v;
        }
    }
}

// no-max softmax step, fp8 h-row (8 channels per lane)
#define PROC8F8(AV, HV)                                          \
    {                                                            \
        float l = (AV) + adv;                                    \
        l = l > 0.f ? l : 0.2f * l;                              \
        float p = __expf(l);                                     \
        den += p;                                                \
        f32x2 c0 = __builtin_amdgcn_cvt_pk_f32_fp8(HV.x, false); \
        f32x2 c1 = __builtin_amdgcn_cvt_pk_f32_fp8(HV.x, true);  \
        f32x2 c2 = __builtin_amdgcn_cvt_pk_f32_fp8(HV.y, false); \
        f32x2 c3 = __builtin_amdgcn_cvt_pk_f32_fp8(HV.y, true);  \
        acc[0] += p * c0.x; acc[1] += p * c0.y;                  \
        acc[2] += p * c1.x; acc[3] += p * c1.y;                  \
        acc[4] += p * c2.x; acc[5] += p * c2.y;                  \
        acc[6] += p * c3.x; acc[7] += p * c3.y;                  \
    }

// ---------- L1 gather + fused GEMM2: block owns 16 dst (M=16 tile) ----------
__global__ __launch_bounds__(256) void msg1g2(const int* __restrict__ fill,
                                              const unsigned short* __restrict__ csr16,
                                              const float* __restrict__ as1,
                                              const float* __restrict__ ad1,
                                              const unsigned char* __restrict__ h1f8,
                                              const float* __restrict__ b1,
                                              const unsigned short* __restrict__ W2e,
                                              unsigned char* __restrict__ h2f8,
                                              float* __restrict__ as2,
                                              float* __restrict__ ad2) {
    __shared__ uint4 w2s[768];           // 48 x 16 uint4 = 12 KB, swizzled
    __shared__ uint4 o1s[256];           // 16 rows x 16 uint4 = 4 KB, swizzled
    int t = threadIdx.x;
    int wid = t >> 6, lane = t & 63;
    int g = lane >> 4;                    // group 0..3 -> own dst
    int cl = lane & 15;                   // channel lane: ch 8*cl..8*cl+7
    int h = cl >> 1;                      // head

    // stage W2e (swizzled identically to gemm2m)
#pragma unroll
    for (int it = 0; it < 3; ++it) {
        int i = it * 256 + t;
        w2s[i ^ ((i >> 4) & 7)] = ((const uint4*)W2e)[i];
    }

    int d = blockIdx.x * 16 + wid * 4 + g;   // grid exact: 3125*16 = 50000
    float adv = ad1[(size_t)d * NHEAD + h];
    int deg = fill[d];                        // >= 1 (self loop)
    size_t eb = (size_t)d << 6;               // ELL row base
    float den = 0.f;
    float acc[8];
#pragma unroll
    for (int k = 0; k < 8; ++k) acc[k] = 0.f;

    const char* as1c = (const char*)as1;
    unsigned hoff = (unsigned)(h << 2);
    unsigned coff = (unsigned)(cl << 3);

// internal index j_ avoids shadowing the caller's loop variable (R11 bug)
#define LD1(J, AV, HV)                                                \
    {                                                                 \
        int j_ = (J);                                                 \
        AV = -1e30f; HV = make_uint2(0u, 0u);                         \
        if (j_ < deg) {                                               \
            unsigned ss = (unsigned)csr16[eb + j_];                   \
            AV = *(const float*)(as1c + (ss << 5) + hoff);            \
            HV = *(const uint2*)(h1f8 + (ss << 7) + coff);            \
        }                                                             \
    }

    float av0, av1; uint2 hv0, hv1;
    LD1(0, av0, hv0);
    LD1(1, av1, hv1);
    for (int j = 0; j < deg; j += 2) {
        float ta, tb; uint2 ua, ub;
        LD1(j + 2, ta, ua);
        LD1(j + 3, tb, ub);
        PROC8F8(av0, hv0);
        PROC8F8(av1, hv1);
        av0 = ta; hv0 = ua; av1 = tb; hv1 = ub;
    }
#undef LD1

    float invd = 1.f / (den + 1e-16f);
    const float4* bp = (const float4*)(b1 + cl * 8);
    float4 ba = bp[0], bb = bp[1];
    float v[8];
    v[0] = acc[0] * invd + ba.x; v[1] = acc[1] * invd + ba.y;
    v[2] = acc[2] * invd + ba.z; v[3] = acc[3] * invd + ba.w;
    v[4] = acc[4] * invd + bb.x; v[5] = acc[5] * invd + bb.y;
    v[6] = acc[6] * invd + bb.z; v[7] = acc[7] * invd + bb.w;
#pragma unroll
    for (int k = 0; k < 8; ++k) {
        float ev = __expf(v[k]) - 1.f;          // ELU negative branch
        v[k] = v[k] > 0.f ? v[k] : ev;
    }
    uint4 o;
    o.x = pk2(v[0], v[1]); o.y = pk2(v[2], v[3]);
    o.z = pk2(v[4], v[5]); o.w = pk2(v[6], v[7]);
    int orow = wid * 4 + g;
    o1s[(orow * 16 + cl) ^ (orow & 7)] = o;
    __syncthreads();

    // Phase 2: GEMM tile f = wid (waves 0..2), M=16 block dst, N=16, K=128
    if (wid < 3) {
        int r = lane & 15;
        int kg = lane >> 4;
        int swz = r & 7;
        f32x4 c2 = (f32x4){0.f, 0.f, 0.f, 0.f};
#pragma unroll
        for (int ks = 0; ks < 4; ++ks) {
            union { uint4 u; bf16x8 vv; } A, B;
            A.u = o1s[(r * 16 + kg + ks * 4) ^ swz];
            B.u = w2s[(wid * 256 + r * 16 + kg + ks * 4) ^ swz];
            c2 = __builtin_amdgcn_mfma_f32_16x16x32_bf16(A.vv, B.vv, c2, 0, 0, 0);
        }
        int col = lane & 15;
        int rbase = blockIdx.x * 16 + (lane >> 4) * 4;
        if (wid < 2) {
#pragma unroll
            for (int i = 0; i < 4; ++i)
                h2f8[(size_t)(rbase + i) * NC + wid * 16 + col] = f2fp8(c2[i]);
        } else {
            int c = 32 + col;
#pragma unroll
            for (int i = 0; i < 4; ++i) {
                int rr = rbase + i;
                if (c < NC) h2f8[(size_t)rr * NC + c] = f2fp8(c2[i]);
                else if (c == NC) as2[rr] = c2[i];
                else if (c == NC + 1) ad2[rr] = c2[i];
            }
        }
    }
}

// ---------- L2 gather: 8-lane group per dst (8 dst/wave), ELL, fp8 h2, depth-2 ----------
__global__ __launch_bounds__(256) void msg2(const int* __restrict__ fill,
                                            const unsigned short* __restrict__ csr16,
                                            const float* __restrict__ as2,
                                            const float* __restrict__ ad2,
                                            const unsigned char* __restrict__ h2f8,
                                            const float* __restrict__ b2,
                                            float* __restrict__ out) {
    int t = threadIdx.x;
    int wid = t >> 6, lane = t & 63;
    int g = lane >> 3;                    // group 0..7 -> own dst
    int cl = lane & 7;                    // channel lane; active cl<5 (8 ch each)
    int clc = cl < 5 ? cl : 4;
    bool act = cl < 5;
    int d0 = blockIdx.x * 32 + wid * 8 + g;
    int d = min(d0, NODES - 1);
    float adv = ad2[d];
    int deg = act ? fill[d] : 0;          // inactive lanes: no loads, no loop
    size_t eb = (size_t)d << 6;
    float den = 0.f;
    float acc[8];
#pragma unroll
    for (int k = 0; k < 8; ++k) acc[k] = 0.f;

    const char* as2c = (const char*)as2;
    unsigned coff = (unsigned)(clc << 3);

#define LD2(J, AV, HV)                                                \
    {                                                                 \
        int j_ = (J);                                                 \
        AV = -1e30f; HV = make_uint2(0u, 0u);                         \
        if (j_ < deg) {                                               \
            unsigned ss = (unsigned)csr16[eb + j_];                   \
            AV = *(const float*)(as2c + (ss << 2));                   \
            HV = *(const uint2*)(h2f8 + ss * 40u + coff);             \
        }                                                             \
    }

    float av0, av1; uint2 hv0, hv1;
    LD2(0, av0, hv0);
    LD2(1, av1, hv1);
    for (int j = 0; j < deg; j += 2) {
        float ta, tb; uint2 ua, ub;
        LD2(j + 2, ta, ua);
        LD2(j + 3, tb, ub);
        PROC8F8(av0, hv0);
        PROC8F8(av1, hv1);
        av0 = ta; hv0 = ua; av1 = tb; hv1 = ub;
    }
#undef LD2

    float invd = 1.f / (den + 1e-16f);
    float v[8];
    float mk = -1e30f;
    if (act) {
        const float4* bp = (const float4*)(b2 + cl * 8);
        float4 ba = bp[0], bb = bp[1];
        v[0] = acc[0] * invd + ba.x; v[1] = acc[1] * invd + ba.y;
        v[2] = acc[2] * invd + ba.z; v[3] = acc[3] * invd + ba.w;
        v[4] = acc[4] * invd + bb.x; v[5] = acc[5] * invd + bb.y;
        v[6] = acc[6] * invd + bb.z; v[7] = acc[7] * invd + bb.w;
#pragma unroll
        for (int k = 0; k < 8; ++k) mk = fmaxf(mk, v[k]);
    }
    // reduce within the 8-lane group
    mk = fmaxf(mk, __shfl_xor(mk, 1, 64));
    mk = fmaxf(mk, __shfl_xor(mk, 2, 64));
    mk = fmaxf(mk, __shfl_xor(mk, 4, 64));
    float e = 0.f;
    if (act) {
#pragma unroll
        for (int k = 0; k < 8; ++k) e += __expf(v[k] - mk);
    }
    e += __shfl_xor(e, 1, 64);
    e += __shfl_xor(e, 2, 64);
    e += __shfl_xor(e, 4, 64);
    float lse = mk + logf(e);
    if (act && d0 < NODES) {
        float4 o0 = make_float4(v[0] - lse, v[1] - lse, v[2] - lse, v[3] - lse);
        float4 o1 = make_float4(v[4] - lse, v[5] - lse, v[6] - lse, v[7] - lse);
        float* po = out + (size_t)d0 * NC + cl * 8;
        *(float4*)po = o0;
        *(float4*)(po + 4) = o1;
    }
}

extern "C" void kernel_launch(void* const* d_in, const int* in_sizes, int n_in,
                              void* d_out, int out_size, void* d_ws, size_t ws_size,
                              hipStream_t stream) {
    const float* x       = (const float*)d_in[0];
    const unsigned* eidx = (const unsigned*)d_in[1];
    const float* W1      = (const float*)d_in[2];
    const float* atts1   = (const float*)d_in[3];
    const float* attd1   = (const float*)d_in[4];
    const float* b1      = (const float*)d_in[5];
    const float* W2      = (const float*)d_in[6];
    const float* atts2   = (const float*)d_in[7];
    const float* attd2   = (const float*)d_in[8];
    const float* b2      = (const float*)d_in[9];
    float* out = (float*)d_out;

    char* base = (char*)d_ws;
    size_t off = 0;
    auto takeB = [&](size_t bytes) {
        void* p = base + off;
        off = (off + bytes + 255) & ~(size_t)255;
        return p;
    };
    int* fill      = (int*)takeB((size_t)NODES * 4);
    unsigned short* csr16 = (unsigned short*)takeB((size_t)NODES * ELLCAP * 2 + 256);
    unsigned short* W1t  = (unsigned short*)takeB((size_t)144 * NF * 2);
    unsigned short* W2e  = (unsigned short*)takeB((size_t)48 * F1 * 2);
    unsigned char* h1f8  = (unsigned char*)takeB((size_t)NODES * F1);
    float* as1     = (float*)takeB((size_t)NODES * NHEAD * 4);
    float* ad1     = (float*)takeB((size_t)NODES * NHEAD * 4);
    unsigned char* h2f8  = (unsigned char*)takeB((size_t)NODES * NC + 256);
    float* as2     = (float*)takeB((size_t)NODES * 4);
    float* ad2     = (float*)takeB((size_t)NODES * 4);

    hipMemsetAsync(fill, 0, (size_t)NODES * 4, stream);

    // weight prep (both layers, one dispatch)
    prepW12<<<192, 256, 0, stream>>>(W1, atts1, attd1, W2, atts2, attd2, W1t, W2e);

    // fused: ELL scatter (self-detecting) + layer-1 MFMA GEMM (fp8 h1 out)
    scatter_gemm1<<<SG_BLOCKS, 256, 0, stream>>>(eidx, fill, csr16,
                                                 x, W1t, h1f8, as1, ad1);

    // Layer-1 gather + fused layer-2 projection (out1 stays on-chip)
    msg1g2<<<NODES / 16, 256, 0, stream>>>(fill, csr16, as1, ad1, h1f8, b1,
                                           W2e, h2f8, as2, ad2);

    // Layer-2 gather + log_softmax
    msg2<<<(NODES + 31) / 32, 256, 0, stream>>>(fill, csr16, as2, ad2, h2f8, b2, out);
}